// Round 21
// baseline (160.476 us; speedup 1.0000x reference)
//
#include <hip/hip_runtime.h>
#include <math.h>

// ---------------- problem constants ----------------
#define MM 2048             // B*N keypoints
#define HOImg 512
#define GG 1024             // HG*WG
#define NCTRL 64
#define NPAR 132            // NPARAM*2

#define BN_S 0.9999950000374997f   // 1/sqrt(1+1e-5)

typedef __bf16 bf16x8 __attribute__((ext_vector_type(8)));
typedef float  f32x4  __attribute__((ext_vector_type(4)));

__device__ __forceinline__ unsigned short f2b(float v){
    unsigned u = __float_as_uint(v);
    unsigned r = (u + 0x7FFFu + ((u>>16)&1u)) >> 16;
    return (unsigned short)r;
}
__device__ __forceinline__ float b2f(unsigned short s){
    return __uint_as_float(((unsigned)s)<<16);
}

// ===== prep_xb: x (4,64,128,128) f32 -> xp bf16 [4][130][130][64] =====
__global__ __launch_bounds__(256) void prep_xb_k(const float* __restrict__ x,
    short* __restrict__ XH)
{
    __shared__ float sT[64][65];
    const int xt = blockIdx.x, yo = blockIdx.y, b = blockIdx.z;
    const int tid = threadIdx.x;
    const int x0 = xt*64;

    if (yo == 0 || yo == 129){
        for (int e = tid; e < 4160; e += 256){      // half of 130*64
            int idx = xt*4160 + e;
            size_t o = (((size_t)b*130 + yo)*130 + idx/64)*64 + (idx&63);
            XH[o] = 0;
        }
        return;
    }
    const int ys = yo - 1;
    for (int e = tid; e < 64*64; e += 256) {
        int ci = e >> 6, xl = e & 63;
        sT[ci][xl] = x[(((size_t)b*64 + ci)*128 + ys)*128 + x0 + xl];
    }
    if (tid < 64){
        size_t o = (((size_t)b*130 + yo)*130 + (xt?129:0))*64 + tid;
        XH[o] = 0;
    }
    __syncthreads();
    for (int e = tid; e < 64*64; e += 256) {
        int xl = e >> 6, ci = e & 63;
        size_t o = (((size_t)b*130 + yo)*130 + (x0+xl+1))*64 + ci;
        XH[o] = (short)f2b(sT[ci][xl]);
    }
}

// ===== prep_misc: B1 (0..127), B2 (128..255), Tab (256..260) =====
__global__ __launch_bounds__(256) void prep_misc_k(const float* __restrict__ w1,
    const float* __restrict__ w2, short* __restrict__ B1H,
    short* __restrict__ B2H, float* __restrict__ Tab)
{
    int bid = blockIdx.x;
    if (bid < 128){
        int co = bid;
        for (int e = threadIdx.x; e < 576; e += 256){
            int kp = e >> 6, ci = e & 63;
            int ky = kp/3, kx = kp - (kp/3)*3;
            float v = w1[((co*66 + ci)*3 + ky)*3 + kx];
            B1H[co*576+e] = (short)f2b(v);
        }
    } else if (bid < 256){
        int co = bid - 128;
        for (int e = threadIdx.x; e < 1152; e += 256){
            int kp = e >> 7, ci = e & 127;
            int ky = kp/3, kx = kp - (kp/3)*3;
            float v = w2[((co*128 + ci)*3 + ky)*3 + kx];
            B2H[co*1152+e] = (short)f2b(v);
        }
    } else {
        int i = (bid-256)*256 + threadIdx.x;
        if (i < 1152){
            int co = i/9, comb = i - (i/9)*9;
            int py = comb/3, px = comb - py*3;
            float w64[3][3], w65[3][3];
            #pragma unroll
            for (int ky=0;ky<3;ky++)
                #pragma unroll
                for (int kx=0;kx<3;kx++){
                    w64[ky][kx] = w1[((co*66 + 64)*3 + ky)*3 + kx];
                    w65[ky][kx] = w1[((co*66 + 65)*3 + ky)*3 + kx];
                }
            const int ky0 = (py==0)?1:0, ky1 = (py==2)?1:2;
            const int kx0 = (px==0)?1:0, kx1 = (px==2)?1:2;
            const float s = 2.f/127.f;
            float A = 0.f, Bc = 0.f, Cc = 0.f;
            for (int kx=kx0; kx<=kx1; ++kx){
                float wy = 0.f;
                for (int ky=ky0; ky<=ky1; ++ky) wy += w64[ky][kx];
                A  += wy * (-1.f + (float)(kx-1)*s);
                Bc += wy * s;
            }
            for (int ky=ky0; ky<=ky1; ++ky){
                float wx = 0.f;
                for (int kx=kx0; kx<=kx1; ++kx) wx += w65[ky][kx];
                A  += wx * (-1.f + (float)(ky-1)*s);
                Cc += wx * s;
            }
            float* d = Tab + ((size_t)comb*128 + co)*3;
            d[0] = A; d[1] = Bc; d[2] = Cc;
        }
    }
}

// ===== SPARSE conv1+conv2+interp: one block = 4 keypoints =====
__global__ __launch_bounds__(256, 2) void spconv_k(
    const short* __restrict__ XP, const short* __restrict__ B1,
    const short* __restrict__ B2, const float* __restrict__ Tab,
    const int* __restrict__ kp, float* __restrict__ th0g)
{
    __shared__ __align__(16) short xL[10368];      // 4kp x 36(pos) x 72(ch pad)
    __shared__ __align__(16) short hL[8768];       // 4kp x (16pos x 136 + 16 pad)
    __shared__ int   sPY[4], sPX[4], sCY[4][2], sCX[4][2], sB[4];
    __shared__ float sWT[4][4];
    const int bid = blockIdx.x;
    const int tid = threadIdx.x;
    const int wv = tid>>6, lane = tid&63;
    const int l15 = lane&15, lg = lane>>4;

    if (tid < 4){
        int m = bid*4 + tid;
        sB[tid] = m >> 9;
        float ix = (float)kp[m*2+0]/511.f*125.f;
        float iy = (float)kp[m*2+1]/511.f*125.f;
        float x0f = floorf(ix), y0f = floorf(iy);
        float wx = ix-x0f, wy = iy-y0f;
        int X0 = (int)x0f, Y0 = (int)y0f;
        bool vx1 = (x0f+1.f <= 125.f), vy1 = (y0f+1.f <= 125.f);
        int X1 = vx1 ? X0+1 : 125;
        int Y1 = vy1 ? Y0+1 : 125;
        int pX0 = min(X0,124), pY0 = min(Y0,124);
        sPX[tid]=pX0; sPY[tid]=pY0;
        sCX[tid][0]=X0-pX0; sCX[tid][1]=X1-pX0;
        sCY[tid][0]=Y0-pY0; sCY[tid][1]=Y1-pY0;
        sWT[tid][0] = (1.f-wx)*(1.f-wy);
        sWT[tid][1] = vx1 ? wx*(1.f-wy) : 0.f;
        sWT[tid][2] = vy1 ? (1.f-wx)*wy : 0.f;
        sWT[tid][3] = (vx1&&vy1) ? wx*wy : 0.f;
    }
    __syncthreads();

    // stage 4 xp patches (6x6 pos x 64ch) -> xL, ch padded to 72
    for (int e = tid; e < 1152; e += 256){
        int pair = e >> 3, seg = e & 7;
        int ki = pair/36, rem = pair - ki*36;
        int row = rem/6, col = rem - row*6;
        const short* src = XP + (((size_t)sB[ki]*130 + sPY[ki]+row)*130
                                 + sPX[ki]+col)*64 + seg*8;
        int4 v = *(const int4*)src;
        *(int4*)&xL[(ki*36 + rem)*72 + seg*8] = v;
    }
    __syncthreads();

    // ---- conv1 ----
    f32x4 a1[4][2];
    #pragma unroll
    for (int i=0;i<4;i++){ a1[i][0]=(f32x4)(0.f); a1[i][1]=(f32x4)(0.f); }
    {
        const int py = l15>>2, px = l15&3;
        for (int cc=0; cc<2; ++cc){
            #pragma unroll
            for (int k9=0;k9<9;k9++){
                const int ky = k9/3, kx = k9 - (k9/3)*3;
                bf16x8 A[4], Bv[2];
                #pragma unroll
                for (int mt=0;mt<4;mt++)
                    A[mt] = *(const bf16x8*)&xL[(mt*36 + (py+ky)*6 + (px+kx))*72
                                                + cc*32 + lg*8];
                const int ko = k9*64 + cc*32;
                Bv[0] = *(const bf16x8*)(B1 + (wv*32 +     l15)*576 + ko + lg*8);
                Bv[1] = *(const bf16x8*)(B1 + (wv*32 + 16 + l15)*576 + ko + lg*8);
                #pragma unroll
                for (int mt=0;mt<4;mt++){
                    a1[mt][0] = __builtin_amdgcn_mfma_f32_16x16x32_bf16(A[mt], Bv[0], a1[mt][0],0,0,0);
                    a1[mt][1] = __builtin_amdgcn_mfma_f32_16x16x32_bf16(A[mt], Bv[1], a1[mt][1],0,0,0);
                }
            }
        }
    }
    // epilogue conv1 -> hL (bf16), Tab affine + BN + relu
    #pragma unroll
    for (int mt=0;mt<4;mt++){
        const int pY0 = sPY[mt], pX0 = sPX[mt];
        #pragma unroll
        for (int reg=0;reg<4;reg++){
            const int p = lg*4 + reg;
            const int py = p>>2, px = p&3;
            const int hy = pY0+py, hx = pX0+px;
            const int pyb = (hy==0)?0:((hy==127)?2:1);
            const int pxb = (hx==0)?0:((hx==127)?2:1);
            #pragma unroll
            for (int nt=0;nt<2;nt++){
                const int co = wv*32 + nt*16 + l15;
                const float* t3 = Tab + ((size_t)(pyb*3+pxb)*128 + co)*3;
                float a = a1[mt][nt][reg];
                a += t3[0] + t3[1]*(float)hx + t3[2]*(float)hy;
                float v = fmaxf(a*BN_S, 0.f);
                hL[mt*2192 + p*136 + co] = (short)f2b(v);
            }
        }
    }
    __syncthreads();

    // ---- conv2: M=16 (4kp x 4 corners) ----
    f32x4 a2[2];
    a2[0]=(f32x4)(0.f); a2[1]=(f32x4)(0.f);
    {
        const int ki = l15>>2, c = l15&3, cy = c>>1, cx = c&1;
        const int hbase = ki*2192 + (sCY[ki][cy]*4 + sCX[ki][cx])*136;
        for (int cc=0; cc<4; ++cc){
            #pragma unroll
            for (int k9=0;k9<9;k9++){
                const int ky = k9/3, kx = k9 - (k9/3)*3;
                bf16x8 A = *(const bf16x8*)&hL[hbase + (ky*4+kx)*136 + cc*32 + lg*8];
                const int ko = k9*128 + cc*32;
                bf16x8 Bv0 = *(const bf16x8*)(B2 + (wv*32 +     l15)*1152 + ko + lg*8);
                bf16x8 Bv1 = *(const bf16x8*)(B2 + (wv*32 + 16 + l15)*1152 + ko + lg*8);
                a2[0] = __builtin_amdgcn_mfma_f32_16x16x32_bf16(A, Bv0, a2[0],0,0,0);
                a2[1] = __builtin_amdgcn_mfma_f32_16x16x32_bf16(A, Bv1, a2[1],0,0,0);
            }
        }
    }
    // interp epilogue: Theta = relu(BN_S * conv2) per corner, THEN weight.
    {
        const float* w4 = sWT[lg];
        #pragma unroll
        for (int nt=0;nt<2;nt++){
            float c0 = fmaxf(a2[nt][0]*BN_S, 0.f);
            float c1 = fmaxf(a2[nt][1]*BN_S, 0.f);
            float c2 = fmaxf(a2[nt][2]*BN_S, 0.f);
            float c3 = fmaxf(a2[nt][3]*BN_S, 0.f);
            float r = ((c0*w4[0] + c1*w4[1]) + c2*w4[2]) + c3*w4[3];
            th0g[(size_t)(bid*4+lg)*128 + wv*32 + nt*16 + l15] = r;
        }
    }
}

// ===== constants: shuffle-based reduce (1 block, 1024 thr) =====
__global__ __launch_bounds__(1024) void consts_red_k(float* __restrict__ cbuf,
    float* __restrict__ pgn, float* __restrict__ ctrl)
{
    __shared__ float part[16][4];
    __shared__ float res[4];
    int g = threadIdx.x;
    int i = g >> 5, j = g & 31;
    float xs = (j + 0.5f)*(2.0f/32.0f) - 1.0f;
    float ys = (i + 0.5f)*(2.0f/32.0f) - 1.0f;
    float norm = (xs + 1.0f)*0.5f;
    float r_ = 1.0f + norm*31.0f;
    float r_s = (r_ - 1.0f)/31.0f*2.0f*32.0f/512.0f;
    float t_s = (ys + 1.0f)*3.14159265358979323846f;
    float bx = r_s*cosf(t_s);
    float by = r_s*sinf(t_s);

    float mnx=bx, mxx=bx, mny=by, mxy=by;
    #pragma unroll
    for (int s=1; s<64; s<<=1){
        mnx = fminf(mnx, __shfl_xor(mnx, s));
        mxx = fmaxf(mxx, __shfl_xor(mxx, s));
        mny = fminf(mny, __shfl_xor(mny, s));
        mxy = fmaxf(mxy, __shfl_xor(mxy, s));
    }
    int wv = g>>6, ln = g&63;
    if (ln == 0){ part[wv][0]=mnx; part[wv][1]=mxx; part[wv][2]=mny; part[wv][3]=mxy; }
    __syncthreads();
    if (g < 4){
        float v = part[0][g];
        for (int t=1;t<16;t++) v = (g&1) ? fmaxf(v, part[t][g]) : fminf(v, part[t][g]);
        res[g] = v;
    }
    __syncthreads();
    float minx=res[0], maxx=res[1], miny=res[2], maxy=res[3];
    float ptpx = maxx-minx, ptpy = maxy-miny;
    if (g == 0){ cbuf[0]=minx; cbuf[1]=miny; cbuf[2]=ptpx; cbuf[3]=ptpy; }

    float pgx = (bx - minx)/(ptpx + 1e-8f)*0.3f + 0.35f;
    float pgy = (by - miny)/(ptpy + 1e-8f)*0.3f + 0.35f;
    pgn[2*g]   = pgx;
    pgn[2*g+1] = pgy;
    if ((i&3)==0 && (j&3)==0){ int t = (i>>2)*8 + (j>>2); ctrl[t*2]=pgx; ctrl[t*2+1]=pgy; }
}

// ===== Ug fill: bf16 U+ matrix [1024 g][96 k] =====
__global__ __launch_bounds__(256) void ug_fill_k(const float* __restrict__ pgn,
    const float* __restrict__ ctrl, unsigned short* __restrict__ Ug)
{
    __shared__ float sc[64][2];
    int g = blockIdx.x*256 + threadIdx.x;
    for (int e = threadIdx.x; e < 128; e += 256) sc[e>>1][e&1] = ctrl[e];
    __syncthreads();
    float px = pgn[2*g], py = pgn[2*g+1];
    float gg2 = px*px + py*py;
    unsigned int* dst = (unsigned int*)(Ug + (size_t)g*96);
    #pragma unroll
    for (int t=0;t<64;t+=2){
        float cx0=sc[t][0],   cy0=sc[t][1];
        float cx1=sc[t+1][0], cy1=sc[t+1][1];
        float r20 = fmaxf(gg2 + (cx0*cx0+cy0*cy0) - 2.f*(px*cx0+py*cy0), 0.f);
        float r21 = fmaxf(gg2 + (cx1*cx1+cy1*cy1) - 2.f*(px*cx1+py*cy1), 0.f);
        float u0 = r20*logf(sqrtf(r20+1e-12f)+1e-6f);
        float u1 = r21*logf(sqrtf(r21+1e-12f)+1e-6f);
        dst[t>>1] = (unsigned)f2b(u0) | ((unsigned)f2b(u1)<<16);
    }
    dst[32] = (unsigned)f2b(1.f) | ((unsigned)f2b(px)<<16);
    dst[33] = (unsigned)f2b(py);               // hi half = 0
    #pragma unroll
    for (int t=34;t<48;t++) dst[t] = 0u;
}

// ===== fused MLP+TPS: row-major weights staged through LDS (coalesced) =====
__global__ __launch_bounds__(256) void mlp_tps_k(const float* __restrict__ th0g,
    const float* __restrict__ l1w, const float* __restrict__ l1b,
    const float* __restrict__ l2w, const float* __restrict__ l2b,
    const float* __restrict__ l3w, const float* __restrict__ l3b,
    const unsigned short* __restrict__ Ug, float* __restrict__ bxy)
{
    __shared__ float th0[8][128];
    __shared__ float th1[8][256];
    __shared__ float th2[8][256];
    __shared__ float sth[8][132];
    __shared__ float sWb[256][33];          // 32-K-row weight tile, +1 pad
    __shared__ __align__(16) unsigned short sW[16][96];
    const int m0 = blockIdx.x*8;
    const int tid = threadIdx.x;

    #pragma unroll
    for (int it=0; it<4; ++it){
        int e = tid + it*256;
        th0[e>>7][e&127] = th0g[(size_t)(m0 + (e>>7))*128 + (e&127)];
    }
    __syncthreads();
    // ---- lin1: K=128, 4 LDS-staged chunks of 32 ----
    {
        const int o = tid;
        float acc[8] = {0,0,0,0,0,0,0,0};
        for (int c0=0;c0<128;c0+=32){
            __syncthreads();
            for (int e=tid; e<8192; e+=256){
                int oo = e>>5, ic = e&31;
                sWb[oo][ic] = l1w[oo*128 + c0 + ic];
            }
            __syncthreads();
            #pragma unroll
            for (int ic=0; ic<32; ic++){
                float wv = sWb[o][ic];
                int i = c0 + ic;
                #pragma unroll
                for (int j=0;j<8;j++) acc[j] += th0[j][i]*wv;
            }
        }
        float bv = l1b[o];
        #pragma unroll
        for (int j=0;j<8;j++) th1[j][o] = fmaxf((acc[j]+bv)*BN_S, 0.f);
    }
    __syncthreads();
    // ---- lin2: K=256, 8 LDS-staged chunks of 32 ----
    {
        const int o = tid;
        float acc[8] = {0,0,0,0,0,0,0,0};
        for (int c0=0;c0<256;c0+=32){
            __syncthreads();
            for (int e=tid; e<8192; e+=256){
                int oo = e>>5, ic = e&31;
                sWb[oo][ic] = l2w[oo*256 + c0 + ic];
            }
            __syncthreads();
            #pragma unroll
            for (int ic=0; ic<32; ic++){
                float wv = sWb[o][ic];
                int i = c0 + ic;
                #pragma unroll
                for (int j=0;j<8;j++) acc[j] += th1[j][i]*wv;
            }
        }
        float bv = l2b[o];
        #pragma unroll
        for (int j=0;j<8;j++) th2[j][o] = fmaxf(acc[j]+bv, 0.f);
    }
    __syncthreads();
    // ---- lin3: K=256, 8 LDS-staged chunks (132 rows); tanh -> theta ----
    {
        float acc[8] = {0,0,0,0,0,0,0,0};
        for (int c0=0;c0<256;c0+=32){
            __syncthreads();
            for (int e=tid; e<4224; e+=256){
                int oo = e>>5, ic = e&31;
                sWb[oo][ic] = l3w[oo*256 + c0 + ic];
            }
            __syncthreads();
            if (tid < NPAR){
                #pragma unroll
                for (int ic=0; ic<32; ic++){
                    float wv = sWb[tid][ic];
                    int i = c0 + ic;
                    #pragma unroll
                    for (int j=0;j<8;j++) acc[j] += th2[j][i]*wv;
                }
            }
        }
        if (tid < NPAR){
            float bv = l3b[tid];
            #pragma unroll
            for (int j=0;j<8;j++) sth[j][tid] = tanhf(acc[j]+bv);
        }
    }
    __syncthreads();
    // ---- W+ prep ----
    if (tid < 16){
        int kpi = tid>>1, c = tid&1;
        float s = 0.f;
        for (int p=0;p<63;p++){ float w = sth[kpi][2*p+c]; s += w; sW[tid][1+p] = f2b(w); }
        sW[tid][0]  = f2b(-s);
        sW[tid][64] = f2b(sth[kpi][126+c]);
        sW[tid][65] = f2b(sth[kpi][128+c]);
        sW[tid][66] = f2b(sth[kpi][130+c]);
        for (int p=67;p<96;p++) sW[tid][p] = 0;
    }
    __syncthreads();
    // ---- TPS MFMA: bxy = Ug(1024x96) @ W+(96x16cols) ----
    const int wv = tid>>6, lane = tid&63;
    const int l15 = lane&15, lg = lane>>4;
    bf16x8 Bf[3];
    #pragma unroll
    for (int ks=0;ks<3;ks++) Bf[ks] = *(const bf16x8*)&sW[l15][ks*32 + lg*8];
    const int gbase = wv*256;
    const int kpg = m0 + (l15>>1), c = l15&1;
    #pragma unroll
    for (int mf=0; mf<16; ++mf){
        f32x4 acc2 = (f32x4)(0.f);
        const unsigned short* ap = Ug + (size_t)(gbase + mf*16 + l15)*96 + lg*8;
        #pragma unroll
        for (int ks=0;ks<3;ks++){
            bf16x8 Af = *(const bf16x8*)(ap + ks*32);
            acc2 = __builtin_amdgcn_mfma_f32_16x16x32_bf16(Af, Bf[ks], acc2,0,0,0);
        }
        float* dst = bxy + ((size_t)kpg*2 + c)*1024 + gbase + mf*16 + lg*4;
        #pragma unroll
        for (int r=0;r<4;r++) dst[r] = acc2[r];
    }
}

// ===== sample: pure gather, one (keypoint, channel) per block ==============
__global__ __launch_bounds__(256) void sample3_k(const int* __restrict__ kp,
    const float* __restrict__ bxy, const float* __restrict__ pgn,
    const float* __restrict__ cbuf, const float* __restrict__ imgs,
    float* __restrict__ out)
{
    const int bid = blockIdx.x;
    const int m = ((bid & 7) << 8) | (bid >> 3);   // bijective: 2048 = 8*256
    const int ch = blockIdx.y;
    const int tid = threadIdx.x;
    const int b = m >> 9;
    const float vminx = cbuf[0] + ((float)kp[m*2+0]/512.f*2.f - 1.f);
    const float vminy = cbuf[1] + ((float)kp[m*2+1]/512.f*2.f - 1.f);
    const float ptpx = cbuf[2], ptpy = cbuf[3];
    const int g0 = tid*4;
    f32x4 zbx = *(const f32x4*)&bxy[((size_t)m*2+0)*1024 + g0];
    f32x4 zby = *(const f32x4*)&bxy[((size_t)m*2+1)*1024 + g0];
    f32x4 pga = *(const f32x4*)&pgn[2*g0];
    f32x4 pgb = *(const f32x4*)&pgn[2*g0+4];
    float px[4] = {pga[0], pga[2], pgb[0], pgb[2]};
    float py[4] = {pga[1], pga[3], pgb[1], pgb[3]};
    const float* ic = imgs + ((size_t)b*3 + ch)*HOImg*HOImg;
    f32x4 o;
    #pragma unroll
    for (int i=0;i<4;i++){
        float wnx = px[i] + zbx[i];
        float wny = py[i] + zby[i];
        float wxr = (wnx - 0.35f)/0.3f*ptpx + vminx;
        float wyr = (wny - 0.35f)/0.3f*ptpy + vminy;
        float ix = ((wxr + 1.f)*512.f - 1.f)*0.5f;
        float iy = ((wyr + 1.f)*512.f - 1.f)*0.5f;
        float x0f = floorf(ix), y0f = floorf(iy);
        float fx = ix-x0f, fy = iy-y0f;
        float w00=(1.f-fx)*(1.f-fy), w10=fx*(1.f-fy), w01=(1.f-fx)*fy, w11=fx*fy;
        bool vx0 = (x0f>=0.f)&&(x0f<=511.f), vx1 = (x0f+1.f>=0.f)&&(x0f+1.f<=511.f);
        bool vy0 = (y0f>=0.f)&&(y0f<=511.f), vy1 = (y0f+1.f>=0.f)&&(y0f+1.f<=511.f);
        float m00 = (vx0&&vy0)?w00:0.f;
        float m10 = (vx1&&vy0)?w10:0.f;
        float m01 = (vx0&&vy1)?w01:0.f;
        float m11 = (vx1&&vy1)?w11:0.f;
        int X0 = (int)fminf(fmaxf(x0f,0.f),511.f);
        int X1 = (int)fminf(fmaxf(x0f+1.f,0.f),511.f);
        int Y0 = (int)fminf(fmaxf(y0f,0.f),511.f);
        int Y1 = (int)fminf(fmaxf(y0f+1.f,0.f),511.f);
        int i00 = Y0*HOImg+X0, i10 = Y0*HOImg+X1, i01 = Y1*HOImg+X0, i11 = Y1*HOImg+X1;
        o[i] = ic[i00]*m00 + ic[i10]*m10 + ic[i01]*m01 + ic[i11]*m11;
    }
    *(f32x4*)&out[((size_t)(m*3+ch))*GG + g0] = o;
}

// ============================ launcher =======================================
extern "C" void kernel_launch(void* const* d_in, const int* in_sizes, int n_in,
                              void* d_out, int out_size, void* d_ws, size_t ws_size,
                              hipStream_t stream)
{
    const float* x    = (const float*)d_in[0];
    const float* imgs = (const float*)d_in[1];
    const int*   kp   = (const int*)d_in[2];
    const float* c1w  = (const float*)d_in[3];
    const float* c2w  = (const float*)d_in[4];
    const float* l1w  = (const float*)d_in[5];
    const float* l1b  = (const float*)d_in[6];
    const float* l2w  = (const float*)d_in[7];
    const float* l2b  = (const float*)d_in[8];
    const float* l3w  = (const float*)d_in[9];
    const float* l3b  = (const float*)d_in[10];
    float* out = (float*)d_out;

    // ---- workspace layout (alias-audited; nothing aliases) ----
    // [0, 8.66MB)     xp bf16
    // [32.51, 33.56)  th0g
    // [49.55, 50.07)  B1, B2
    // [50.07, ...)    Ug, pgn, cbuf, ctrl, Tab, bxy
    char* W = (char*)d_ws;
    short* xph   = (short*)(W + 0);
    constexpr size_t OFF_HH = 32514048;
    float* th0g = (float*)(W + OFF_HH);                // 1,048,576 B
    constexpr size_t OFF_B = OFF_HH + 17039360;        // 49,553,408
    short* B1 = (short*)(W + OFF_B);                   // 147,456
    short* B2 = (short*)(W + OFF_B + 221184);          // 294,912
    constexpr size_t OFF_C = OFF_B + 516096;           // 50,069,504
    unsigned short* Ug = (unsigned short*)(W + OFF_C);          // 196,608
    float* pgn  = (float*)(W + OFF_C + 196608);                 // 8,192
    float* cbuf = (float*)(W + OFF_C + 204800);                 // 256
    float* ctrl = (float*)(W + OFF_C + 205056);                 // 512
    float* Tab  = (float*)(W + OFF_C + 205568);                 // 13,824
    float* bxy  = (float*)(W + OFF_C + 219392);                 // 16,777,216

    hipLaunchKernelGGL(prep_xb_k, dim3(2,130,4), dim3(256), 0, stream, x, xph);
    hipLaunchKernelGGL(prep_misc_k, dim3(261), dim3(256), 0, stream,
                       c1w, c2w, B1, B2, Tab);
    hipLaunchKernelGGL(consts_red_k, dim3(1), dim3(1024), 0, stream, cbuf, pgn, ctrl);
    hipLaunchKernelGGL(ug_fill_k, dim3(4), dim3(256), 0, stream, pgn, ctrl, Ug);

    hipLaunchKernelGGL(spconv_k, dim3(MM/4), dim3(256), 0, stream,
                       xph, B1, B2, Tab, kp, th0g);

    hipLaunchKernelGGL(mlp_tps_k, dim3(MM/8), dim3(256), 0, stream,
                       th0g, l1w, l1b, l2w, l2b, l3w, l3b, Ug, bxy);
    hipLaunchKernelGGL(sample3_k, dim3(MM, 3), dim3(256), 0, stream,
                       kp, bxy, pgn, cbuf, imgs, out);
}

// Round 22
// 120.865 us; speedup vs baseline: 1.3277x; 1.3277x over previous
//
#include <hip/hip_runtime.h>
#include <math.h>

// ---------------- problem constants ----------------
#define MM 2048             // B*N keypoints
#define HOImg 512
#define GG 1024             // HG*WG
#define NCTRL 64
#define NPAR 132            // NPARAM*2

#define BN_S 0.9999950000374997f   // 1/sqrt(1+1e-5)

typedef __bf16 bf16x8 __attribute__((ext_vector_type(8)));
typedef float  f32x4  __attribute__((ext_vector_type(4)));

__device__ __forceinline__ unsigned short f2b(float v){
    unsigned u = __float_as_uint(v);
    unsigned r = (u + 0x7FFFu + ((u>>16)&1u)) >> 16;
    return (unsigned short)r;
}
__device__ __forceinline__ float b2f(unsigned short s){
    return __uint_as_float(((unsigned)s)<<16);
}

// ===== prep_xb: x (4,64,128,128) f32 -> xp bf16 [4][130][130][64] =====
__global__ __launch_bounds__(256) void prep_xb_k(const float* __restrict__ x,
    short* __restrict__ XH)
{
    __shared__ float sT[64][65];
    const int xt = blockIdx.x, yo = blockIdx.y, b = blockIdx.z;
    const int tid = threadIdx.x;
    const int x0 = xt*64;

    if (yo == 0 || yo == 129){
        for (int e = tid; e < 4160; e += 256){      // half of 130*64
            int idx = xt*4160 + e;
            size_t o = (((size_t)b*130 + yo)*130 + idx/64)*64 + (idx&63);
            XH[o] = 0;
        }
        return;
    }
    const int ys = yo - 1;
    for (int e = tid; e < 64*64; e += 256) {
        int ci = e >> 6, xl = e & 63;
        sT[ci][xl] = x[(((size_t)b*64 + ci)*128 + ys)*128 + x0 + xl];
    }
    if (tid < 64){
        size_t o = (((size_t)b*130 + yo)*130 + (xt?129:0))*64 + tid;
        XH[o] = 0;
    }
    __syncthreads();
    for (int e = tid; e < 64*64; e += 256) {
        int xl = e >> 6, ci = e & 63;
        size_t o = (((size_t)b*130 + yo)*130 + (x0+xl+1))*64 + ci;
        XH[o] = (short)f2b(sT[ci][xl]);
    }
}

// ===== prep_misc: B1 (0..127), B2 (128..255), Tab (256..260),
//       W1 split (261..388), W2 split (389..644), W3 split (645..788) =====
__global__ __launch_bounds__(256) void prep_misc_k(const float* __restrict__ w1,
    const float* __restrict__ w2, const float* __restrict__ l1w,
    const float* __restrict__ l2w, const float* __restrict__ l3w,
    short* __restrict__ B1H, short* __restrict__ B2H, float* __restrict__ Tab,
    unsigned short* __restrict__ W1h, unsigned short* __restrict__ W1l,
    unsigned short* __restrict__ W2h, unsigned short* __restrict__ W2l,
    unsigned short* __restrict__ W3h, unsigned short* __restrict__ W3l)
{
    int bid = blockIdx.x;
    if (bid < 128){
        int co = bid;
        for (int e = threadIdx.x; e < 576; e += 256){
            int kp = e >> 6, ci = e & 63;
            int ky = kp/3, kx = kp - (kp/3)*3;
            float v = w1[((co*66 + ci)*3 + ky)*3 + kx];
            B1H[co*576+e] = (short)f2b(v);
        }
    } else if (bid < 256){
        int co = bid - 128;
        for (int e = threadIdx.x; e < 1152; e += 256){
            int kp = e >> 7, ci = e & 127;
            int ky = kp/3, kx = kp - (kp/3)*3;
            float v = w2[((co*128 + ci)*3 + ky)*3 + kx];
            B2H[co*1152+e] = (short)f2b(v);
        }
    } else if (bid < 261){
        int i = (bid-256)*256 + threadIdx.x;
        if (i < 1152){
            int co = i/9, comb = i - (i/9)*9;
            int py = comb/3, px = comb - py*3;
            float w64[3][3], w65[3][3];
            #pragma unroll
            for (int ky=0;ky<3;ky++)
                #pragma unroll
                for (int kx=0;kx<3;kx++){
                    w64[ky][kx] = w1[((co*66 + 64)*3 + ky)*3 + kx];
                    w65[ky][kx] = w1[((co*66 + 65)*3 + ky)*3 + kx];
                }
            const int ky0 = (py==0)?1:0, ky1 = (py==2)?1:2;
            const int kx0 = (px==0)?1:0, kx1 = (px==2)?1:2;
            const float s = 2.f/127.f;
            float A = 0.f, Bc = 0.f, Cc = 0.f;
            for (int kx=kx0; kx<=kx1; ++kx){
                float wy = 0.f;
                for (int ky=ky0; ky<=ky1; ++ky) wy += w64[ky][kx];
                A  += wy * (-1.f + (float)(kx-1)*s);
                Bc += wy * s;
            }
            for (int ky=ky0; ky<=ky1; ++ky){
                float wx = 0.f;
                for (int kx=kx0; kx<=kx1; ++kx) wx += w65[ky][kx];
                A  += wx * (-1.f + (float)(ky-1)*s);
                Cc += wx * s;
            }
            float* d = Tab + ((size_t)comb*128 + co)*3;
            d[0] = A; d[1] = Bc; d[2] = Cc;
        }
    } else if (bid < 389){
        int e = (bid-261)*256 + threadIdx.x;    // 32768 = 256o x 128k
        float v = l1w[e];
        unsigned short hi = f2b(v);
        W1h[e] = hi; W1l[e] = f2b(v - b2f(hi));
    } else if (bid < 645){
        int e = (bid-389)*256 + threadIdx.x;    // 65536 = 256o x 256k
        float v = l2w[e];
        unsigned short hi = f2b(v);
        W2h[e] = hi; W2l[e] = f2b(v - b2f(hi));
    } else {
        int e = (bid-645)*256 + threadIdx.x;    // 36864 = 144o x 256k
        int o = e >> 8, k = e & 255;
        float v = (o < 132) ? l3w[o*256 + k] : 0.f;
        unsigned short hi = f2b(v);
        W3h[e] = hi; W3l[e] = f2b(v - b2f(hi));
    }
}

// ===== SPARSE conv1+conv2+interp: one block = 4 keypoints =====
__global__ __launch_bounds__(256, 2) void spconv_k(
    const short* __restrict__ XP, const short* __restrict__ B1,
    const short* __restrict__ B2, const float* __restrict__ Tab,
    const int* __restrict__ kp, float* __restrict__ th0g)
{
    __shared__ __align__(16) short xL[10368];      // 4kp x 36(pos) x 72(ch pad)
    __shared__ __align__(16) short hL[8768];       // 4kp x (16pos x 136 + 16 pad)
    __shared__ int   sPY[4], sPX[4], sCY[4][2], sCX[4][2], sB[4];
    __shared__ float sWT[4][4];
    const int bid = blockIdx.x;
    const int tid = threadIdx.x;
    const int wv = tid>>6, lane = tid&63;
    const int l15 = lane&15, lg = lane>>4;

    if (tid < 4){
        int m = bid*4 + tid;
        sB[tid] = m >> 9;
        float ix = (float)kp[m*2+0]/511.f*125.f;
        float iy = (float)kp[m*2+1]/511.f*125.f;
        float x0f = floorf(ix), y0f = floorf(iy);
        float wx = ix-x0f, wy = iy-y0f;
        int X0 = (int)x0f, Y0 = (int)y0f;
        bool vx1 = (x0f+1.f <= 125.f), vy1 = (y0f+1.f <= 125.f);
        int X1 = vx1 ? X0+1 : 125;
        int Y1 = vy1 ? Y0+1 : 125;
        int pX0 = min(X0,124), pY0 = min(Y0,124);
        sPX[tid]=pX0; sPY[tid]=pY0;
        sCX[tid][0]=X0-pX0; sCX[tid][1]=X1-pX0;
        sCY[tid][0]=Y0-pY0; sCY[tid][1]=Y1-pY0;
        sWT[tid][0] = (1.f-wx)*(1.f-wy);
        sWT[tid][1] = vx1 ? wx*(1.f-wy) : 0.f;
        sWT[tid][2] = vy1 ? (1.f-wx)*wy : 0.f;
        sWT[tid][3] = (vx1&&vy1) ? wx*wy : 0.f;
    }
    __syncthreads();

    // stage 4 xp patches (6x6 pos x 64ch) -> xL, ch padded to 72
    for (int e = tid; e < 1152; e += 256){
        int pair = e >> 3, seg = e & 7;
        int ki = pair/36, rem = pair - ki*36;
        int row = rem/6, col = rem - row*6;
        const short* src = XP + (((size_t)sB[ki]*130 + sPY[ki]+row)*130
                                 + sPX[ki]+col)*64 + seg*8;
        int4 v = *(const int4*)src;
        *(int4*)&xL[(ki*36 + rem)*72 + seg*8] = v;
    }
    __syncthreads();

    // ---- conv1 ----
    f32x4 a1[4][2];
    #pragma unroll
    for (int i=0;i<4;i++){ a1[i][0]=(f32x4)(0.f); a1[i][1]=(f32x4)(0.f); }
    {
        const int py = l15>>2, px = l15&3;
        for (int cc=0; cc<2; ++cc){
            #pragma unroll
            for (int k9=0;k9<9;k9++){
                const int ky = k9/3, kx = k9 - (k9/3)*3;
                bf16x8 A[4], Bv[2];
                #pragma unroll
                for (int mt=0;mt<4;mt++)
                    A[mt] = *(const bf16x8*)&xL[(mt*36 + (py+ky)*6 + (px+kx))*72
                                                + cc*32 + lg*8];
                const int ko = k9*64 + cc*32;
                Bv[0] = *(const bf16x8*)(B1 + (wv*32 +     l15)*576 + ko + lg*8);
                Bv[1] = *(const bf16x8*)(B1 + (wv*32 + 16 + l15)*576 + ko + lg*8);
                #pragma unroll
                for (int mt=0;mt<4;mt++){
                    a1[mt][0] = __builtin_amdgcn_mfma_f32_16x16x32_bf16(A[mt], Bv[0], a1[mt][0],0,0,0);
                    a1[mt][1] = __builtin_amdgcn_mfma_f32_16x16x32_bf16(A[mt], Bv[1], a1[mt][1],0,0,0);
                }
            }
        }
    }
    // epilogue conv1 -> hL (bf16), Tab affine + BN + relu
    #pragma unroll
    for (int mt=0;mt<4;mt++){
        const int pY0 = sPY[mt], pX0 = sPX[mt];
        #pragma unroll
        for (int reg=0;reg<4;reg++){
            const int p = lg*4 + reg;
            const int py = p>>2, px = p&3;
            const int hy = pY0+py, hx = pX0+px;
            const int pyb = (hy==0)?0:((hy==127)?2:1);
            const int pxb = (hx==0)?0:((hx==127)?2:1);
            #pragma unroll
            for (int nt=0;nt<2;nt++){
                const int co = wv*32 + nt*16 + l15;
                const float* t3 = Tab + ((size_t)(pyb*3+pxb)*128 + co)*3;
                float a = a1[mt][nt][reg];
                a += t3[0] + t3[1]*(float)hx + t3[2]*(float)hy;
                float v = fmaxf(a*BN_S, 0.f);
                hL[mt*2192 + p*136 + co] = (short)f2b(v);
            }
        }
    }
    __syncthreads();

    // ---- conv2: M=16 (4kp x 4 corners) ----
    f32x4 a2[2];
    a2[0]=(f32x4)(0.f); a2[1]=(f32x4)(0.f);
    {
        const int ki = l15>>2, c = l15&3, cy = c>>1, cx = c&1;
        const int hbase = ki*2192 + (sCY[ki][cy]*4 + sCX[ki][cx])*136;
        for (int cc=0; cc<4; ++cc){
            #pragma unroll
            for (int k9=0;k9<9;k9++){
                const int ky = k9/3, kx = k9 - (k9/3)*3;
                bf16x8 A = *(const bf16x8*)&hL[hbase + (ky*4+kx)*136 + cc*32 + lg*8];
                const int ko = k9*128 + cc*32;
                bf16x8 Bv0 = *(const bf16x8*)(B2 + (wv*32 +     l15)*1152 + ko + lg*8);
                bf16x8 Bv1 = *(const bf16x8*)(B2 + (wv*32 + 16 + l15)*1152 + ko + lg*8);
                a2[0] = __builtin_amdgcn_mfma_f32_16x16x32_bf16(A, Bv0, a2[0],0,0,0);
                a2[1] = __builtin_amdgcn_mfma_f32_16x16x32_bf16(A, Bv1, a2[1],0,0,0);
            }
        }
    }
    // interp epilogue: Theta = relu(BN_S * conv2) per corner, THEN weight.
    {
        const float* w4 = sWT[lg];
        #pragma unroll
        for (int nt=0;nt<2;nt++){
            float c0 = fmaxf(a2[nt][0]*BN_S, 0.f);
            float c1 = fmaxf(a2[nt][1]*BN_S, 0.f);
            float c2 = fmaxf(a2[nt][2]*BN_S, 0.f);
            float c3 = fmaxf(a2[nt][3]*BN_S, 0.f);
            float r = ((c0*w4[0] + c1*w4[1]) + c2*w4[2]) + c3*w4[3];
            th0g[(size_t)(bid*4+lg)*128 + wv*32 + nt*16 + l15] = r;
        }
    }
}

// ===== constants: shuffle-based reduce (1 block, 1024 thr) =====
__global__ __launch_bounds__(1024) void consts_red_k(float* __restrict__ cbuf,
    float* __restrict__ pgn, float* __restrict__ ctrl)
{
    __shared__ float part[16][4];
    __shared__ float res[4];
    int g = threadIdx.x;
    int i = g >> 5, j = g & 31;
    float xs = (j + 0.5f)*(2.0f/32.0f) - 1.0f;
    float ys = (i + 0.5f)*(2.0f/32.0f) - 1.0f;
    float norm = (xs + 1.0f)*0.5f;
    float r_ = 1.0f + norm*31.0f;
    float r_s = (r_ - 1.0f)/31.0f*2.0f*32.0f/512.0f;
    float t_s = (ys + 1.0f)*3.14159265358979323846f;
    float bx = r_s*cosf(t_s);
    float by = r_s*sinf(t_s);

    float mnx=bx, mxx=bx, mny=by, mxy=by;
    #pragma unroll
    for (int s=1; s<64; s<<=1){
        mnx = fminf(mnx, __shfl_xor(mnx, s));
        mxx = fmaxf(mxx, __shfl_xor(mxx, s));
        mny = fminf(mny, __shfl_xor(mny, s));
        mxy = fmaxf(mxy, __shfl_xor(mxy, s));
    }
    int wv = g>>6, ln = g&63;
    if (ln == 0){ part[wv][0]=mnx; part[wv][1]=mxx; part[wv][2]=mny; part[wv][3]=mxy; }
    __syncthreads();
    if (g < 4){
        float v = part[0][g];
        for (int t=1;t<16;t++) v = (g&1) ? fmaxf(v, part[t][g]) : fminf(v, part[t][g]);
        res[g] = v;
    }
    __syncthreads();
    float minx=res[0], maxx=res[1], miny=res[2], maxy=res[3];
    float ptpx = maxx-minx, ptpy = maxy-miny;
    if (g == 0){ cbuf[0]=minx; cbuf[1]=miny; cbuf[2]=ptpx; cbuf[3]=ptpy; }

    float pgx = (bx - minx)/(ptpx + 1e-8f)*0.3f + 0.35f;
    float pgy = (by - miny)/(ptpy + 1e-8f)*0.3f + 0.35f;
    pgn[2*g]   = pgx;
    pgn[2*g+1] = pgy;
    if ((i&3)==0 && (j&3)==0){ int t = (i>>2)*8 + (j>>2); ctrl[t*2]=pgx; ctrl[t*2+1]=pgy; }
}

// ===== Ug fill: bf16 U+ matrix [1024 g][96 k] =====
__global__ __launch_bounds__(256) void ug_fill_k(const float* __restrict__ pgn,
    const float* __restrict__ ctrl, unsigned short* __restrict__ Ug)
{
    __shared__ float sc[64][2];
    int g = blockIdx.x*256 + threadIdx.x;
    for (int e = threadIdx.x; e < 128; e += 256) sc[e>>1][e&1] = ctrl[e];
    __syncthreads();
    float px = pgn[2*g], py = pgn[2*g+1];
    float gg2 = px*px + py*py;
    unsigned int* dst = (unsigned int*)(Ug + (size_t)g*96);
    #pragma unroll
    for (int t=0;t<64;t+=2){
        float cx0=sc[t][0],   cy0=sc[t][1];
        float cx1=sc[t+1][0], cy1=sc[t+1][1];
        float r20 = fmaxf(gg2 + (cx0*cx0+cy0*cy0) - 2.f*(px*cx0+py*cy0), 0.f);
        float r21 = fmaxf(gg2 + (cx1*cx1+cy1*cy1) - 2.f*(px*cx1+py*cy1), 0.f);
        float u0 = r20*logf(sqrtf(r20+1e-12f)+1e-6f);
        float u1 = r21*logf(sqrtf(r21+1e-12f)+1e-6f);
        dst[t>>1] = (unsigned)f2b(u0) | ((unsigned)f2b(u1)<<16);
    }
    dst[32] = (unsigned)f2b(1.f) | ((unsigned)f2b(px)<<16);
    dst[33] = (unsigned)f2b(py);               // hi half = 0
    #pragma unroll
    for (int t=34;t<48;t++) dst[t] = 0u;
}

// ===== fused MLP+TPS: all linear layers as split-bf16 MFMA GEMMs =====
// M=16 (8 kp + 8 zero rows), A row=l15, k=lg*8; C row=lg*4+reg, col=l15
// (spconv's proven fragment idiom). Weights pre-split hi/lo in [o][k] layout.
__global__ __launch_bounds__(256) void mlp_tps_k(const float* __restrict__ th0g,
    const unsigned short* __restrict__ W1h, const unsigned short* __restrict__ W1l,
    const unsigned short* __restrict__ W2h, const unsigned short* __restrict__ W2l,
    const unsigned short* __restrict__ W3h, const unsigned short* __restrict__ W3l,
    const float* __restrict__ l1b, const float* __restrict__ l2b,
    const float* __restrict__ l3b,
    const unsigned short* __restrict__ Ug, float* __restrict__ bxy)
{
    __shared__ unsigned short th0h[16][136], th0l[16][136];
    __shared__ unsigned short th1h[16][264], th1l[16][264];
    __shared__ unsigned short th2h[16][264], th2l[16][264];
    __shared__ float sth[8][132];
    __shared__ __align__(16) unsigned short sW[16][96];
    const int m0 = blockIdx.x*8;
    const int tid = threadIdx.x;
    const int wv = tid>>6, lane = tid&63;
    const int l15 = lane&15, lg = lane>>4;

    // th0 (8 kp x 128) -> split hi/lo LDS; rows 8..15 zero
    for (int e = tid; e < 2048; e += 256){
        int r = e >> 7, k = e & 127;
        float v = (r < 8) ? th0g[(size_t)(m0 + r)*128 + k] : 0.f;
        unsigned short hi = f2b(v);
        th0h[r][k] = hi; th0l[r][k] = f2b(v - b2f(hi));
    }
    __syncthreads();

    // ---- lin1: N=256 (4 frags/wave), K=128 (4 chunks), 3-pass split ----
    {
        f32x4 acc[4];
        #pragma unroll
        for (int nt=0;nt<4;nt++) acc[nt] = (f32x4)(0.f);
        for (int kc=0; kc<4; ++kc){
            bf16x8 Ah = *(const bf16x8*)&th0h[l15][kc*32 + lg*8];
            bf16x8 Al = *(const bf16x8*)&th0l[l15][kc*32 + lg*8];
            #pragma unroll
            for (int nt=0;nt<4;nt++){
                const int o = (wv*4+nt)*16 + l15;
                bf16x8 Bh = *(const bf16x8*)(W1h + (size_t)o*128 + kc*32 + lg*8);
                bf16x8 Bl = *(const bf16x8*)(W1l + (size_t)o*128 + kc*32 + lg*8);
                acc[nt] = __builtin_amdgcn_mfma_f32_16x16x32_bf16(Ah, Bh, acc[nt],0,0,0);
                acc[nt] = __builtin_amdgcn_mfma_f32_16x16x32_bf16(Ah, Bl, acc[nt],0,0,0);
                acc[nt] = __builtin_amdgcn_mfma_f32_16x16x32_bf16(Al, Bh, acc[nt],0,0,0);
            }
        }
        #pragma unroll
        for (int nt=0;nt<4;nt++){
            const int o = (wv*4+nt)*16 + l15;
            float bv = l1b[o];
            #pragma unroll
            for (int reg=0;reg<4;reg++){
                int r = lg*4+reg;
                float v = fmaxf((acc[nt][reg]+bv)*BN_S, 0.f);
                unsigned short hi = f2b(v);
                th1h[r][o] = hi; th1l[r][o] = f2b(v - b2f(hi));
            }
        }
    }
    __syncthreads();

    // ---- lin2: N=256, K=256 (8 chunks) ----
    {
        f32x4 acc[4];
        #pragma unroll
        for (int nt=0;nt<4;nt++) acc[nt] = (f32x4)(0.f);
        for (int kc=0; kc<8; ++kc){
            bf16x8 Ah = *(const bf16x8*)&th1h[l15][kc*32 + lg*8];
            bf16x8 Al = *(const bf16x8*)&th1l[l15][kc*32 + lg*8];
            #pragma unroll
            for (int nt=0;nt<4;nt++){
                const int o = (wv*4+nt)*16 + l15;
                bf16x8 Bh = *(const bf16x8*)(W2h + (size_t)o*256 + kc*32 + lg*8);
                bf16x8 Bl = *(const bf16x8*)(W2l + (size_t)o*256 + kc*32 + lg*8);
                acc[nt] = __builtin_amdgcn_mfma_f32_16x16x32_bf16(Ah, Bh, acc[nt],0,0,0);
                acc[nt] = __builtin_amdgcn_mfma_f32_16x16x32_bf16(Ah, Bl, acc[nt],0,0,0);
                acc[nt] = __builtin_amdgcn_mfma_f32_16x16x32_bf16(Al, Bh, acc[nt],0,0,0);
            }
        }
        #pragma unroll
        for (int nt=0;nt<4;nt++){
            const int o = (wv*4+nt)*16 + l15;
            float bv = l2b[o];
            #pragma unroll
            for (int reg=0;reg<4;reg++){
                int r = lg*4+reg;
                float v = fmaxf(acc[nt][reg]+bv, 0.f);
                unsigned short hi = f2b(v);
                th2h[r][o] = hi; th2l[r][o] = f2b(v - b2f(hi));
            }
        }
    }
    __syncthreads();

    // ---- lin3: N=144 (9 frags: waves {2,2,2,3}), K=256; tanh -> sth ----
    {
        f32x4 acc[3];
        #pragma unroll
        for (int t=0;t<3;t++) acc[t] = (f32x4)(0.f);
        const int nfr = (wv<3) ? 2 : 3;
        for (int kc=0; kc<8; ++kc){
            bf16x8 Ah = *(const bf16x8*)&th2h[l15][kc*32 + lg*8];
            bf16x8 Al = *(const bf16x8*)&th2l[l15][kc*32 + lg*8];
            for (int t=0;t<3;t++){
                if (t >= nfr) break;
                const int fr = (wv<3) ? (wv*2+t) : (6+t);
                const int o = fr*16 + l15;
                bf16x8 Bh = *(const bf16x8*)(W3h + (size_t)o*256 + kc*32 + lg*8);
                bf16x8 Bl = *(const bf16x8*)(W3l + (size_t)o*256 + kc*32 + lg*8);
                acc[t] = __builtin_amdgcn_mfma_f32_16x16x32_bf16(Ah, Bh, acc[t],0,0,0);
                acc[t] = __builtin_amdgcn_mfma_f32_16x16x32_bf16(Ah, Bl, acc[t],0,0,0);
                acc[t] = __builtin_amdgcn_mfma_f32_16x16x32_bf16(Al, Bh, acc[t],0,0,0);
            }
        }
        for (int t=0;t<3;t++){
            if (t >= nfr) break;
            const int fr = (wv<3) ? (wv*2+t) : (6+t);
            const int o = fr*16 + l15;
            if (o < NPAR){
                float bv = l3b[o];
                #pragma unroll
                for (int reg=0;reg<4;reg++){
                    int r = lg*4+reg;
                    if (r < 8) sth[r][o] = tanhf(acc[t][reg]+bv);
                }
            }
        }
    }
    __syncthreads();

    // ---- W+ prep ----
    if (tid < 16){
        int kpi = tid>>1, c = tid&1;
        float s = 0.f;
        for (int p=0;p<63;p++){ float w = sth[kpi][2*p+c]; s += w; sW[tid][1+p] = f2b(w); }
        sW[tid][0]  = f2b(-s);
        sW[tid][64] = f2b(sth[kpi][126+c]);
        sW[tid][65] = f2b(sth[kpi][128+c]);
        sW[tid][66] = f2b(sth[kpi][130+c]);
        for (int p=67;p<96;p++) sW[tid][p] = 0;
    }
    __syncthreads();
    // ---- TPS MFMA: bxy = Ug(1024x96) @ W+(96x16cols) ----
    bf16x8 Bf[3];
    #pragma unroll
    for (int ks=0;ks<3;ks++) Bf[ks] = *(const bf16x8*)&sW[l15][ks*32 + lg*8];
    const int gbase = wv*256;
    const int kpg = m0 + (l15>>1), c = l15&1;
    #pragma unroll
    for (int mf=0; mf<16; ++mf){
        f32x4 acc2 = (f32x4)(0.f);
        const unsigned short* ap = Ug + (size_t)(gbase + mf*16 + l15)*96 + lg*8;
        #pragma unroll
        for (int ks=0;ks<3;ks++){
            bf16x8 Af = *(const bf16x8*)(ap + ks*32);
            acc2 = __builtin_amdgcn_mfma_f32_16x16x32_bf16(Af, Bf[ks], acc2,0,0,0);
        }
        float* dst = bxy + ((size_t)kpg*2 + c)*1024 + gbase + mf*16 + lg*4;
        #pragma unroll
        for (int r=0;r<4;r++) dst[r] = acc2[r];
    }
}

// ===== sample: pure gather, one (keypoint, channel) per block ==============
__global__ __launch_bounds__(256) void sample3_k(const int* __restrict__ kp,
    const float* __restrict__ bxy, const float* __restrict__ pgn,
    const float* __restrict__ cbuf, const float* __restrict__ imgs,
    float* __restrict__ out)
{
    const int bid = blockIdx.x;
    const int m = ((bid & 7) << 8) | (bid >> 3);   // bijective: 2048 = 8*256
    const int ch = blockIdx.y;
    const int tid = threadIdx.x;
    const int b = m >> 9;
    const float vminx = cbuf[0] + ((float)kp[m*2+0]/512.f*2.f - 1.f);
    const float vminy = cbuf[1] + ((float)kp[m*2+1]/512.f*2.f - 1.f);
    const float ptpx = cbuf[2], ptpy = cbuf[3];
    const int g0 = tid*4;
    f32x4 zbx = *(const f32x4*)&bxy[((size_t)m*2+0)*1024 + g0];
    f32x4 zby = *(const f32x4*)&bxy[((size_t)m*2+1)*1024 + g0];
    f32x4 pga = *(const f32x4*)&pgn[2*g0];
    f32x4 pgb = *(const f32x4*)&pgn[2*g0+4];
    float px[4] = {pga[0], pga[2], pgb[0], pgb[2]};
    float py[4] = {pga[1], pga[3], pgb[1], pgb[3]};
    const float* ic = imgs + ((size_t)b*3 + ch)*HOImg*HOImg;
    f32x4 o;
    #pragma unroll
    for (int i=0;i<4;i++){
        float wnx = px[i] + zbx[i];
        float wny = py[i] + zby[i];
        float wxr = (wnx - 0.35f)/0.3f*ptpx + vminx;
        float wyr = (wny - 0.35f)/0.3f*ptpy + vminy;
        float ix = ((wxr + 1.f)*512.f - 1.f)*0.5f;
        float iy = ((wyr + 1.f)*512.f - 1.f)*0.5f;
        float x0f = floorf(ix), y0f = floorf(iy);
        float fx = ix-x0f, fy = iy-y0f;
        float w00=(1.f-fx)*(1.f-fy), w10=fx*(1.f-fy), w01=(1.f-fx)*fy, w11=fx*fy;
        bool vx0 = (x0f>=0.f)&&(x0f<=511.f), vx1 = (x0f+1.f>=0.f)&&(x0f+1.f<=511.f);
        bool vy0 = (y0f>=0.f)&&(y0f<=511.f), vy1 = (y0f+1.f>=0.f)&&(y0f+1.f<=511.f);
        float m00 = (vx0&&vy0)?w00:0.f;
        float m10 = (vx1&&vy0)?w10:0.f;
        float m01 = (vx0&&vy1)?w01:0.f;
        float m11 = (vx1&&vy1)?w11:0.f;
        int X0 = (int)fminf(fmaxf(x0f,0.f),511.f);
        int X1 = (int)fminf(fmaxf(x0f+1.f,0.f),511.f);
        int Y0 = (int)fminf(fmaxf(y0f,0.f),511.f);
        int Y1 = (int)fminf(fmaxf(y0f+1.f,0.f),511.f);
        int i00 = Y0*HOImg+X0, i10 = Y0*HOImg+X1, i01 = Y1*HOImg+X0, i11 = Y1*HOImg+X1;
        o[i] = ic[i00]*m00 + ic[i10]*m10 + ic[i01]*m01 + ic[i11]*m11;
    }
    *(f32x4*)&out[((size_t)(m*3+ch))*GG + g0] = o;
}

// ============================ launcher =======================================
extern "C" void kernel_launch(void* const* d_in, const int* in_sizes, int n_in,
                              void* d_out, int out_size, void* d_ws, size_t ws_size,
                              hipStream_t stream)
{
    const float* x    = (const float*)d_in[0];
    const float* imgs = (const float*)d_in[1];
    const int*   kp   = (const int*)d_in[2];
    const float* c1w  = (const float*)d_in[3];
    const float* c2w  = (const float*)d_in[4];
    const float* l1w  = (const float*)d_in[5];
    const float* l1b  = (const float*)d_in[6];
    const float* l2w  = (const float*)d_in[7];
    const float* l2b  = (const float*)d_in[8];
    const float* l3w  = (const float*)d_in[9];
    const float* l3b  = (const float*)d_in[10];
    float* out = (float*)d_out;

    // ---- workspace layout (alias-audited; nothing aliases) ----
    // [0, 8.66MB)     xp bf16
    // [32.51, 33.56)  th0g
    // [49.55, 50.07)  B1, B2
    // [50.07, 67.61)  Ug, pgn, cbuf, ctrl, Tab, W1h/l, W2h/l, W3h/l, bxy
    char* W = (char*)d_ws;
    short* xph   = (short*)(W + 0);
    constexpr size_t OFF_HH = 32514048;
    float* th0g = (float*)(W + OFF_HH);                // 1,048,576 B
    constexpr size_t OFF_B = OFF_HH + 17039360;        // 49,553,408
    short* B1 = (short*)(W + OFF_B);                   // 147,456
    short* B2 = (short*)(W + OFF_B + 221184);          // 294,912
    constexpr size_t OFF_C = OFF_B + 516096;           // 50,069,504
    unsigned short* Ug  = (unsigned short*)(W + OFF_C);           // 196,608
    float* pgn  = (float*)(W + OFF_C + 196608);                   // 8,192
    float* cbuf = (float*)(W + OFF_C + 204800);                   // 256
    float* ctrl = (float*)(W + OFF_C + 205056);                   // 512
    float* Tab  = (float*)(W + OFF_C + 205568);                   // 13,824
    unsigned short* W1h = (unsigned short*)(W + OFF_C + 219392);  // 65,536
    unsigned short* W1l = (unsigned short*)(W + OFF_C + 284928);  // 65,536
    unsigned short* W2h = (unsigned short*)(W + OFF_C + 350464);  // 131,072
    unsigned short* W2l = (unsigned short*)(W + OFF_C + 481536);  // 131,072
    unsigned short* W3h = (unsigned short*)(W + OFF_C + 612608);  // 73,728
    unsigned short* W3l = (unsigned short*)(W + OFF_C + 686336);  // 73,728
    float* bxy = (float*)(W + OFF_C + 760064);                    // 16,777,216

    hipLaunchKernelGGL(prep_xb_k, dim3(2,130,4), dim3(256), 0, stream, x, xph);
    hipLaunchKernelGGL(prep_misc_k, dim3(789), dim3(256), 0, stream,
                       c1w, c2w, l1w, l2w, l3w, B1, B2, Tab,
                       W1h, W1l, W2h, W2l, W3h, W3l);
    hipLaunchKernelGGL(consts_red_k, dim3(1), dim3(1024), 0, stream, cbuf, pgn, ctrl);
    hipLaunchKernelGGL(ug_fill_k, dim3(4), dim3(256), 0, stream, pgn, ctrl, Ug);

    hipLaunchKernelGGL(spconv_k, dim3(MM/4), dim3(256), 0, stream,
                       xph, B1, B2, Tab, kp, th0g);

    hipLaunchKernelGGL(mlp_tps_k, dim3(MM/8), dim3(256), 0, stream,
                       th0g, W1h, W1l, W2h, W2l, W3h, W3l,
                       l1b, l2b, l3b, Ug, bxy);
    hipLaunchKernelGGL(sample3_k, dim3(MM, 3), dim3(256), 0, stream,
                       kp, bxy, pgn, cbuf, imgs, out);
}

// Round 23
// 119.679 us; speedup vs baseline: 1.3409x; 1.0099x over previous
//
#include <hip/hip_runtime.h>
#include <math.h>

// ---------------- problem constants ----------------
#define MM 2048             // B*N keypoints
#define HOImg 512
#define GG 1024             // HG*WG
#define NCTRL 64
#define NPAR 132            // NPARAM*2

#define BN_S 0.9999950000374997f   // 1/sqrt(1+1e-5)

typedef __bf16 bf16x8 __attribute__((ext_vector_type(8)));
typedef float  f32x4  __attribute__((ext_vector_type(4)));

__device__ __forceinline__ unsigned short f2b(float v){
    unsigned u = __float_as_uint(v);
    unsigned r = (u + 0x7FFFu + ((u>>16)&1u)) >> 16;
    return (unsigned short)r;
}
__device__ __forceinline__ float b2f(unsigned short s){
    return __uint_as_float(((unsigned)s)<<16);
}

// ===== prep_xb: x (4,64,128,128) f32 -> xp bf16 [4][130][130][64] =====
__global__ __launch_bounds__(256) void prep_xb_k(const float* __restrict__ x,
    short* __restrict__ XH)
{
    __shared__ float sT[64][65];
    const int xt = blockIdx.x, yo = blockIdx.y, b = blockIdx.z;
    const int tid = threadIdx.x;
    const int x0 = xt*64;

    if (yo == 0 || yo == 129){
        for (int e = tid; e < 4160; e += 256){      // half of 130*64
            int idx = xt*4160 + e;
            size_t o = (((size_t)b*130 + yo)*130 + idx/64)*64 + (idx&63);
            XH[o] = 0;
        }
        return;
    }
    const int ys = yo - 1;
    for (int e = tid; e < 64*64; e += 256) {
        int ci = e >> 6, xl = e & 63;
        sT[ci][xl] = x[(((size_t)b*64 + ci)*128 + ys)*128 + x0 + xl];
    }
    if (tid < 64){
        size_t o = (((size_t)b*130 + yo)*130 + (xt?129:0))*64 + tid;
        XH[o] = 0;
    }
    __syncthreads();
    for (int e = tid; e < 64*64; e += 256) {
        int xl = e >> 6, ci = e & 63;
        size_t o = (((size_t)b*130 + yo)*130 + (x0+xl+1))*64 + ci;
        XH[o] = (short)f2b(sT[ci][xl]);
    }
}

// ===== prep_img: imgs (4,3,512,512) -> imgT [b][y][x][4] f32 (dedicated) =====
__global__ __launch_bounds__(256) void prep_img_k(const float* __restrict__ imgs,
    float* __restrict__ imgT)
{
    const int x = blockIdx.x*256 + threadIdx.x;
    const int y = blockIdx.y, b = blockIdx.z;
    const size_t ib = ((size_t)b*3*HOImg + y)*HOImg + x;
    f32x4 v;
    v[0] = imgs[ib];
    v[1] = imgs[ib + (size_t)HOImg*HOImg];
    v[2] = imgs[ib + (size_t)2*HOImg*HOImg];
    v[3] = 0.f;
    *(f32x4*)&imgT[(((size_t)b*HOImg + y)*HOImg + x)*4] = v;
}

// ===== prep_misc: B1 (0..127), B2 (128..255), Tab (256..260),
//       W1 split (261..388), W2 split (389..644), W3 split (645..788) =====
__global__ __launch_bounds__(256) void prep_misc_k(const float* __restrict__ w1,
    const float* __restrict__ w2, const float* __restrict__ l1w,
    const float* __restrict__ l2w, const float* __restrict__ l3w,
    short* __restrict__ B1H, short* __restrict__ B2H, float* __restrict__ Tab,
    unsigned short* __restrict__ W1h, unsigned short* __restrict__ W1l,
    unsigned short* __restrict__ W2h, unsigned short* __restrict__ W2l,
    unsigned short* __restrict__ W3h, unsigned short* __restrict__ W3l)
{
    int bid = blockIdx.x;
    if (bid < 128){
        int co = bid;
        for (int e = threadIdx.x; e < 576; e += 256){
            int kp = e >> 6, ci = e & 63;
            int ky = kp/3, kx = kp - (kp/3)*3;
            float v = w1[((co*66 + ci)*3 + ky)*3 + kx];
            B1H[co*576+e] = (short)f2b(v);
        }
    } else if (bid < 256){
        int co = bid - 128;
        for (int e = threadIdx.x; e < 1152; e += 256){
            int kp = e >> 7, ci = e & 127;
            int ky = kp/3, kx = kp - (kp/3)*3;
            float v = w2[((co*128 + ci)*3 + ky)*3 + kx];
            B2H[co*1152+e] = (short)f2b(v);
        }
    } else if (bid < 261){
        int i = (bid-256)*256 + threadIdx.x;
        if (i < 1152){
            int co = i/9, comb = i - (i/9)*9;
            int py = comb/3, px = comb - py*3;
            float w64[3][3], w65[3][3];
            #pragma unroll
            for (int ky=0;ky<3;ky++)
                #pragma unroll
                for (int kx=0;kx<3;kx++){
                    w64[ky][kx] = w1[((co*66 + 64)*3 + ky)*3 + kx];
                    w65[ky][kx] = w1[((co*66 + 65)*3 + ky)*3 + kx];
                }
            const int ky0 = (py==0)?1:0, ky1 = (py==2)?1:2;
            const int kx0 = (px==0)?1:0, kx1 = (px==2)?1:2;
            const float s = 2.f/127.f;
            float A = 0.f, Bc = 0.f, Cc = 0.f;
            for (int kx=kx0; kx<=kx1; ++kx){
                float wy = 0.f;
                for (int ky=ky0; ky<=ky1; ++ky) wy += w64[ky][kx];
                A  += wy * (-1.f + (float)(kx-1)*s);
                Bc += wy * s;
            }
            for (int ky=ky0; ky<=ky1; ++ky){
                float wx = 0.f;
                for (int kx=kx0; kx<=kx1; ++kx) wx += w65[ky][kx];
                A  += wx * (-1.f + (float)(ky-1)*s);
                Cc += wx * s;
            }
            float* d = Tab + ((size_t)comb*128 + co)*3;
            d[0] = A; d[1] = Bc; d[2] = Cc;
        }
    } else if (bid < 389){
        int e = (bid-261)*256 + threadIdx.x;    // 32768 = 256o x 128k
        float v = l1w[e];
        unsigned short hi = f2b(v);
        W1h[e] = hi; W1l[e] = f2b(v - b2f(hi));
    } else if (bid < 645){
        int e = (bid-389)*256 + threadIdx.x;    // 65536 = 256o x 256k
        float v = l2w[e];
        unsigned short hi = f2b(v);
        W2h[e] = hi; W2l[e] = f2b(v - b2f(hi));
    } else {
        int e = (bid-645)*256 + threadIdx.x;    // 36864 = 144o x 256k
        int o = e >> 8, k = e & 255;
        float v = (o < 132) ? l3w[o*256 + k] : 0.f;
        unsigned short hi = f2b(v);
        W3h[e] = hi; W3l[e] = f2b(v - b2f(hi));
    }
}

// ===== SPARSE conv1+conv2+interp: one block = 4 keypoints =====
__global__ __launch_bounds__(256, 2) void spconv_k(
    const short* __restrict__ XP, const short* __restrict__ B1,
    const short* __restrict__ B2, const float* __restrict__ Tab,
    const int* __restrict__ kp, float* __restrict__ th0g)
{
    __shared__ __align__(16) short xL[10368];      // 4kp x 36(pos) x 72(ch pad)
    __shared__ __align__(16) short hL[8768];       // 4kp x (16pos x 136 + 16 pad)
    __shared__ int   sPY[4], sPX[4], sCY[4][2], sCX[4][2], sB[4];
    __shared__ float sWT[4][4];
    const int bid = blockIdx.x;
    const int tid = threadIdx.x;
    const int wv = tid>>6, lane = tid&63;
    const int l15 = lane&15, lg = lane>>4;

    if (tid < 4){
        int m = bid*4 + tid;
        sB[tid] = m >> 9;
        float ix = (float)kp[m*2+0]/511.f*125.f;
        float iy = (float)kp[m*2+1]/511.f*125.f;
        float x0f = floorf(ix), y0f = floorf(iy);
        float wx = ix-x0f, wy = iy-y0f;
        int X0 = (int)x0f, Y0 = (int)y0f;
        bool vx1 = (x0f+1.f <= 125.f), vy1 = (y0f+1.f <= 125.f);
        int X1 = vx1 ? X0+1 : 125;
        int Y1 = vy1 ? Y0+1 : 125;
        int pX0 = min(X0,124), pY0 = min(Y0,124);
        sPX[tid]=pX0; sPY[tid]=pY0;
        sCX[tid][0]=X0-pX0; sCX[tid][1]=X1-pX0;
        sCY[tid][0]=Y0-pY0; sCY[tid][1]=Y1-pY0;
        sWT[tid][0] = (1.f-wx)*(1.f-wy);
        sWT[tid][1] = vx1 ? wx*(1.f-wy) : 0.f;
        sWT[tid][2] = vy1 ? (1.f-wx)*wy : 0.f;
        sWT[tid][3] = (vx1&&vy1) ? wx*wy : 0.f;
    }
    __syncthreads();

    // stage 4 xp patches (6x6 pos x 64ch) -> xL, ch padded to 72
    for (int e = tid; e < 1152; e += 256){
        int pair = e >> 3, seg = e & 7;
        int ki = pair/36, rem = pair - ki*36;
        int row = rem/6, col = rem - row*6;
        const short* src = XP + (((size_t)sB[ki]*130 + sPY[ki]+row)*130
                                 + sPX[ki]+col)*64 + seg*8;
        int4 v = *(const int4*)src;
        *(int4*)&xL[(ki*36 + rem)*72 + seg*8] = v;
    }
    __syncthreads();

    // ---- conv1 ----
    f32x4 a1[4][2];
    #pragma unroll
    for (int i=0;i<4;i++){ a1[i][0]=(f32x4)(0.f); a1[i][1]=(f32x4)(0.f); }
    {
        const int py = l15>>2, px = l15&3;
        for (int cc=0; cc<2; ++cc){
            #pragma unroll
            for (int k9=0;k9<9;k9++){
                const int ky = k9/3, kx = k9 - (k9/3)*3;
                bf16x8 A[4], Bv[2];
                #pragma unroll
                for (int mt=0;mt<4;mt++)
                    A[mt] = *(const bf16x8*)&xL[(mt*36 + (py+ky)*6 + (px+kx))*72
                                                + cc*32 + lg*8];
                const int ko = k9*64 + cc*32;
                Bv[0] = *(const bf16x8*)(B1 + (wv*32 +     l15)*576 + ko + lg*8);
                Bv[1] = *(const bf16x8*)(B1 + (wv*32 + 16 + l15)*576 + ko + lg*8);
                #pragma unroll
                for (int mt=0;mt<4;mt++){
                    a1[mt][0] = __builtin_amdgcn_mfma_f32_16x16x32_bf16(A[mt], Bv[0], a1[mt][0],0,0,0);
                    a1[mt][1] = __builtin_amdgcn_mfma_f32_16x16x32_bf16(A[mt], Bv[1], a1[mt][1],0,0,0);
                }
            }
        }
    }
    // epilogue conv1 -> hL (bf16), Tab affine + BN + relu
    #pragma unroll
    for (int mt=0;mt<4;mt++){
        const int pY0 = sPY[mt], pX0 = sPX[mt];
        #pragma unroll
        for (int reg=0;reg<4;reg++){
            const int p = lg*4 + reg;
            const int py = p>>2, px = p&3;
            const int hy = pY0+py, hx = pX0+px;
            const int pyb = (hy==0)?0:((hy==127)?2:1);
            const int pxb = (hx==0)?0:((hx==127)?2:1);
            #pragma unroll
            for (int nt=0;nt<2;nt++){
                const int co = wv*32 + nt*16 + l15;
                const float* t3 = Tab + ((size_t)(pyb*3+pxb)*128 + co)*3;
                float a = a1[mt][nt][reg];
                a += t3[0] + t3[1]*(float)hx + t3[2]*(float)hy;
                float v = fmaxf(a*BN_S, 0.f);
                hL[mt*2192 + p*136 + co] = (short)f2b(v);
            }
        }
    }
    __syncthreads();

    // ---- conv2: M=16 (4kp x 4 corners) ----
    f32x4 a2[2];
    a2[0]=(f32x4)(0.f); a2[1]=(f32x4)(0.f);
    {
        const int ki = l15>>2, c = l15&3, cy = c>>1, cx = c&1;
        const int hbase = ki*2192 + (sCY[ki][cy]*4 + sCX[ki][cx])*136;
        for (int cc=0; cc<4; ++cc){
            #pragma unroll
            for (int k9=0;k9<9;k9++){
                const int ky = k9/3, kx = k9 - (k9/3)*3;
                bf16x8 A = *(const bf16x8*)&hL[hbase + (ky*4+kx)*136 + cc*32 + lg*8];
                const int ko = k9*128 + cc*32;
                bf16x8 Bv0 = *(const bf16x8*)(B2 + (wv*32 +     l15)*1152 + ko + lg*8);
                bf16x8 Bv1 = *(const bf16x8*)(B2 + (wv*32 + 16 + l15)*1152 + ko + lg*8);
                a2[0] = __builtin_amdgcn_mfma_f32_16x16x32_bf16(A, Bv0, a2[0],0,0,0);
                a2[1] = __builtin_amdgcn_mfma_f32_16x16x32_bf16(A, Bv1, a2[1],0,0,0);
            }
        }
    }
    // interp epilogue: Theta = relu(BN_S * conv2) per corner, THEN weight.
    {
        const float* w4 = sWT[lg];
        #pragma unroll
        for (int nt=0;nt<2;nt++){
            float c0 = fmaxf(a2[nt][0]*BN_S, 0.f);
            float c1 = fmaxf(a2[nt][1]*BN_S, 0.f);
            float c2 = fmaxf(a2[nt][2]*BN_S, 0.f);
            float c3 = fmaxf(a2[nt][3]*BN_S, 0.f);
            float r = ((c0*w4[0] + c1*w4[1]) + c2*w4[2]) + c3*w4[3];
            th0g[(size_t)(bid*4+lg)*128 + wv*32 + nt*16 + l15] = r;
        }
    }
}

// ===== ug_fill (merged consts): 4 blocks x 256; each block redundantly
// computes the closed-form 1024-pt min/max (fmin/fmax exact, order-free),
// block 0 writes cbuf, all blocks write identical pgn, each fills its Ug rows.
__global__ __launch_bounds__(256) void ug_fill_k(float* __restrict__ cbuf,
    float* __restrict__ pgn, unsigned short* __restrict__ Ug)
{
    __shared__ float part[4][4];
    __shared__ float res[4];
    __shared__ float sc[64][2];
    const int tid = threadIdx.x;
    const int bid = blockIdx.x;

    float bxv[4], byv[4];
    float mnx=1e30f, mxx=-1e30f, mny=1e30f, mxy=-1e30f;
    #pragma unroll
    for (int t=0;t<4;t++){
        int g = tid + t*256;
        int i = g >> 5, j = g & 31;
        float xs = (j + 0.5f)*(2.0f/32.0f) - 1.0f;
        float ys = (i + 0.5f)*(2.0f/32.0f) - 1.0f;
        float norm = (xs + 1.0f)*0.5f;
        float r_ = 1.0f + norm*31.0f;
        float r_s = (r_ - 1.0f)/31.0f*2.0f*32.0f/512.0f;
        float t_s = (ys + 1.0f)*3.14159265358979323846f;
        float bx = r_s*cosf(t_s);
        float by = r_s*sinf(t_s);
        bxv[t]=bx; byv[t]=by;
        mnx=fminf(mnx,bx); mxx=fmaxf(mxx,bx);
        mny=fminf(mny,by); mxy=fmaxf(mxy,by);
    }
    #pragma unroll
    for (int s=1; s<64; s<<=1){
        mnx = fminf(mnx, __shfl_xor(mnx, s));
        mxx = fmaxf(mxx, __shfl_xor(mxx, s));
        mny = fminf(mny, __shfl_xor(mny, s));
        mxy = fmaxf(mxy, __shfl_xor(mxy, s));
    }
    int wv = tid>>6, ln = tid&63;
    if (ln == 0){ part[wv][0]=mnx; part[wv][1]=mxx; part[wv][2]=mny; part[wv][3]=mxy; }
    __syncthreads();
    if (tid < 4){
        float v = part[0][tid];
        for (int t=1;t<4;t++) v = (tid&1) ? fmaxf(v, part[t][tid]) : fminf(v, part[t][tid]);
        res[tid] = v;
    }
    __syncthreads();
    const float minx=res[0], maxx=res[1], miny=res[2], maxy=res[3];
    const float ptpx = maxx-minx, ptpy = maxy-miny;
    if (bid == 0 && tid == 0){ cbuf[0]=minx; cbuf[1]=miny; cbuf[2]=ptpx; cbuf[3]=ptpy; }

    // pgn for this thread's 4 points (all blocks write identical values)
    #pragma unroll
    for (int t=0;t<4;t++){
        int g = tid + t*256;
        float pgx = (bxv[t] - minx)/(ptpx + 1e-8f)*0.3f + 0.35f;
        float pgy = (byv[t] - miny)/(ptpy + 1e-8f)*0.3f + 0.35f;
        pgn[2*g]   = pgx;
        pgn[2*g+1] = pgy;
    }
    // ctrl points (closed form) -> LDS
    if (tid < 64){
        int g = 128*(tid>>3) + 4*(tid&7);          // i=4*(t/8), j=4*(t%8)
        int i = g >> 5, j = g & 31;
        float xs = (j + 0.5f)*(2.0f/32.0f) - 1.0f;
        float ys = (i + 0.5f)*(2.0f/32.0f) - 1.0f;
        float norm = (xs + 1.0f)*0.5f;
        float r_ = 1.0f + norm*31.0f;
        float r_s = (r_ - 1.0f)/31.0f*2.0f*32.0f/512.0f;
        float t_s = (ys + 1.0f)*3.14159265358979323846f;
        float bx = r_s*cosf(t_s);
        float by = r_s*sinf(t_s);
        sc[tid][0] = (bx - minx)/(ptpx + 1e-8f)*0.3f + 0.35f;
        sc[tid][1] = (by - miny)/(ptpy + 1e-8f)*0.3f + 0.35f;
    }
    __syncthreads();

    // Ug rows for this block's g = bid*256 + tid (bx/by = bxv[bid], byv[bid])
    const float px = (bxv[bid] - minx)/(ptpx + 1e-8f)*0.3f + 0.35f;
    const float py = (byv[bid] - miny)/(ptpy + 1e-8f)*0.3f + 0.35f;
    const int g = bid*256 + tid;
    float gg2 = px*px + py*py;
    unsigned int* dst = (unsigned int*)(Ug + (size_t)g*96);
    #pragma unroll
    for (int t=0;t<64;t+=2){
        float cx0=sc[t][0],   cy0=sc[t][1];
        float cx1=sc[t+1][0], cy1=sc[t+1][1];
        float r20 = fmaxf(gg2 + (cx0*cx0+cy0*cy0) - 2.f*(px*cx0+py*cy0), 0.f);
        float r21 = fmaxf(gg2 + (cx1*cx1+cy1*cy1) - 2.f*(px*cx1+py*cy1), 0.f);
        float u0 = r20*logf(sqrtf(r20+1e-12f)+1e-6f);
        float u1 = r21*logf(sqrtf(r21+1e-12f)+1e-6f);
        dst[t>>1] = (unsigned)f2b(u0) | ((unsigned)f2b(u1)<<16);
    }
    dst[32] = (unsigned)f2b(1.f) | ((unsigned)f2b(px)<<16);
    dst[33] = (unsigned)f2b(py);               // hi half = 0
    #pragma unroll
    for (int t=34;t<48;t++) dst[t] = 0u;
}

// ===== fused MLP+TPS: all linear layers as split-bf16 MFMA GEMMs =====
__global__ __launch_bounds__(256) void mlp_tps_k(const float* __restrict__ th0g,
    const unsigned short* __restrict__ W1h, const unsigned short* __restrict__ W1l,
    const unsigned short* __restrict__ W2h, const unsigned short* __restrict__ W2l,
    const unsigned short* __restrict__ W3h, const unsigned short* __restrict__ W3l,
    const float* __restrict__ l1b, const float* __restrict__ l2b,
    const float* __restrict__ l3b,
    const unsigned short* __restrict__ Ug, float* __restrict__ bxy)
{
    __shared__ unsigned short th0h[16][136], th0l[16][136];
    __shared__ unsigned short th1h[16][264], th1l[16][264];
    __shared__ unsigned short th2h[16][264], th2l[16][264];
    __shared__ float sth[8][132];
    __shared__ __align__(16) unsigned short sW[16][96];
    const int m0 = blockIdx.x*8;
    const int tid = threadIdx.x;
    const int wv = tid>>6, lane = tid&63;
    const int l15 = lane&15, lg = lane>>4;

    for (int e = tid; e < 2048; e += 256){
        int r = e >> 7, k = e & 127;
        float v = (r < 8) ? th0g[(size_t)(m0 + r)*128 + k] : 0.f;
        unsigned short hi = f2b(v);
        th0h[r][k] = hi; th0l[r][k] = f2b(v - b2f(hi));
    }
    __syncthreads();

    // ---- lin1: N=256 (4 frags/wave), K=128 (4 chunks), 3-pass split ----
    {
        f32x4 acc[4];
        #pragma unroll
        for (int nt=0;nt<4;nt++) acc[nt] = (f32x4)(0.f);
        for (int kc=0; kc<4; ++kc){
            bf16x8 Ah = *(const bf16x8*)&th0h[l15][kc*32 + lg*8];
            bf16x8 Al = *(const bf16x8*)&th0l[l15][kc*32 + lg*8];
            #pragma unroll
            for (int nt=0;nt<4;nt++){
                const int o = (wv*4+nt)*16 + l15;
                bf16x8 Bh = *(const bf16x8*)(W1h + (size_t)o*128 + kc*32 + lg*8);
                bf16x8 Bl = *(const bf16x8*)(W1l + (size_t)o*128 + kc*32 + lg*8);
                acc[nt] = __builtin_amdgcn_mfma_f32_16x16x32_bf16(Ah, Bh, acc[nt],0,0,0);
                acc[nt] = __builtin_amdgcn_mfma_f32_16x16x32_bf16(Ah, Bl, acc[nt],0,0,0);
                acc[nt] = __builtin_amdgcn_mfma_f32_16x16x32_bf16(Al, Bh, acc[nt],0,0,0);
            }
        }
        #pragma unroll
        for (int nt=0;nt<4;nt++){
            const int o = (wv*4+nt)*16 + l15;
            float bv = l1b[o];
            #pragma unroll
            for (int reg=0;reg<4;reg++){
                int r = lg*4+reg;
                float v = fmaxf((acc[nt][reg]+bv)*BN_S, 0.f);
                unsigned short hi = f2b(v);
                th1h[r][o] = hi; th1l[r][o] = f2b(v - b2f(hi));
            }
        }
    }
    __syncthreads();

    // ---- lin2: N=256, K=256 (8 chunks) ----
    {
        f32x4 acc[4];
        #pragma unroll
        for (int nt=0;nt<4;nt++) acc[nt] = (f32x4)(0.f);
        for (int kc=0; kc<8; ++kc){
            bf16x8 Ah = *(const bf16x8*)&th1h[l15][kc*32 + lg*8];
            bf16x8 Al = *(const bf16x8*)&th1l[l15][kc*32 + lg*8];
            #pragma unroll
            for (int nt=0;nt<4;nt++){
                const int o = (wv*4+nt)*16 + l15;
                bf16x8 Bh = *(const bf16x8*)(W2h + (size_t)o*256 + kc*32 + lg*8);
                bf16x8 Bl = *(const bf16x8*)(W2l + (size_t)o*256 + kc*32 + lg*8);
                acc[nt] = __builtin_amdgcn_mfma_f32_16x16x32_bf16(Ah, Bh, acc[nt],0,0,0);
                acc[nt] = __builtin_amdgcn_mfma_f32_16x16x32_bf16(Ah, Bl, acc[nt],0,0,0);
                acc[nt] = __builtin_amdgcn_mfma_f32_16x16x32_bf16(Al, Bh, acc[nt],0,0,0);
            }
        }
        #pragma unroll
        for (int nt=0;nt<4;nt++){
            const int o = (wv*4+nt)*16 + l15;
            float bv = l2b[o];
            #pragma unroll
            for (int reg=0;reg<4;reg++){
                int r = lg*4+reg;
                float v = fmaxf(acc[nt][reg]+bv, 0.f);
                unsigned short hi = f2b(v);
                th2h[r][o] = hi; th2l[r][o] = f2b(v - b2f(hi));
            }
        }
    }
    __syncthreads();

    // ---- lin3: N=144 (9 frags: waves {2,2,2,3}), K=256; tanh -> sth ----
    {
        f32x4 acc[3];
        #pragma unroll
        for (int t=0;t<3;t++) acc[t] = (f32x4)(0.f);
        const int nfr = (wv<3) ? 2 : 3;
        for (int kc=0; kc<8; ++kc){
            bf16x8 Ah = *(const bf16x8*)&th2h[l15][kc*32 + lg*8];
            bf16x8 Al = *(const bf16x8*)&th2l[l15][kc*32 + lg*8];
            for (int t=0;t<3;t++){
                if (t >= nfr) break;
                const int fr = (wv<3) ? (wv*2+t) : (6+t);
                const int o = fr*16 + l15;
                bf16x8 Bh = *(const bf16x8*)(W3h + (size_t)o*256 + kc*32 + lg*8);
                bf16x8 Bl = *(const bf16x8*)(W3l + (size_t)o*256 + kc*32 + lg*8);
                acc[t] = __builtin_amdgcn_mfma_f32_16x16x32_bf16(Ah, Bh, acc[t],0,0,0);
                acc[t] = __builtin_amdgcn_mfma_f32_16x16x32_bf16(Ah, Bl, acc[t],0,0,0);
                acc[t] = __builtin_amdgcn_mfma_f32_16x16x32_bf16(Al, Bh, acc[t],0,0,0);
            }
        }
        for (int t=0;t<3;t++){
            if (t >= nfr) break;
            const int fr = (wv<3) ? (wv*2+t) : (6+t);
            const int o = fr*16 + l15;
            if (o < NPAR){
                float bv = l3b[o];
                #pragma unroll
                for (int reg=0;reg<4;reg++){
                    int r = lg*4+reg;
                    if (r < 8) sth[r][o] = tanhf(acc[t][reg]+bv);
                }
            }
        }
    }
    __syncthreads();

    // ---- W+ prep ----
    if (tid < 16){
        int kpi = tid>>1, c = tid&1;
        float s = 0.f;
        for (int p=0;p<63;p++){ float w = sth[kpi][2*p+c]; s += w; sW[tid][1+p] = f2b(w); }
        sW[tid][0]  = f2b(-s);
        sW[tid][64] = f2b(sth[kpi][126+c]);
        sW[tid][65] = f2b(sth[kpi][128+c]);
        sW[tid][66] = f2b(sth[kpi][130+c]);
        for (int p=67;p<96;p++) sW[tid][p] = 0;
    }
    __syncthreads();
    // ---- TPS MFMA: bxy = Ug(1024x96) @ W+(96x16cols) ----
    bf16x8 Bf[3];
    #pragma unroll
    for (int ks=0;ks<3;ks++) Bf[ks] = *(const bf16x8*)&sW[l15][ks*32 + lg*8];
    const int gbase = wv*256;
    const int kpg = m0 + (l15>>1), c = l15&1;
    #pragma unroll
    for (int mf=0; mf<16; ++mf){
        f32x4 acc2 = (f32x4)(0.f);
        const unsigned short* ap = Ug + (size_t)(gbase + mf*16 + l15)*96 + lg*8;
        #pragma unroll
        for (int ks=0;ks<3;ks++){
            bf16x8 Af = *(const bf16x8*)(ap + ks*32);
            acc2 = __builtin_amdgcn_mfma_f32_16x16x32_bf16(Af, Bf[ks], acc2,0,0,0);
        }
        float* dst = bxy + ((size_t)kpg*2 + c)*1024 + gbase + mf*16 + lg*4;
        #pragma unroll
        for (int r=0;r<4;r++) dst[r] = acc2[r];
    }
}

// ===== sample: channels-last imgT gather, 2048 blocks, XCD-swizzled ========
__global__ __launch_bounds__(256) void sample_k(const int* __restrict__ kp,
    const float* __restrict__ bxy, const float* __restrict__ pgn,
    const float* __restrict__ cbuf, const float* __restrict__ imgT,
    float* __restrict__ out)
{
    const int bid = blockIdx.x;
    const int m = ((bid & 7) << 8) | (bid >> 3);   // bijective: 2048 = 8*256
    const int tid = threadIdx.x;
    const int b = m >> 9;
    const float vminx = cbuf[0] + ((float)kp[m*2+0]/512.f*2.f - 1.f);
    const float vminy = cbuf[1] + ((float)kp[m*2+1]/512.f*2.f - 1.f);
    const float ptpx = cbuf[2], ptpy = cbuf[3];
    const int g0 = tid*4;
    f32x4 zbx = *(const f32x4*)&bxy[((size_t)m*2+0)*1024 + g0];
    f32x4 zby = *(const f32x4*)&bxy[((size_t)m*2+1)*1024 + g0];
    f32x4 pga = *(const f32x4*)&pgn[2*g0];
    f32x4 pgb = *(const f32x4*)&pgn[2*g0+4];
    float px[4] = {pga[0], pga[2], pgb[0], pgb[2]};
    float py[4] = {pga[1], pga[3], pgb[1], pgb[3]};
    const float* it_b = imgT + (size_t)b*HOImg*HOImg*4;
    f32x4 o0, o1, o2;
    #pragma unroll
    for (int i=0;i<4;i++){
        float wnx = px[i] + zbx[i];
        float wny = py[i] + zby[i];
        float wxr = (wnx - 0.35f)/0.3f*ptpx + vminx;
        float wyr = (wny - 0.35f)/0.3f*ptpy + vminy;
        float ix = ((wxr + 1.f)*512.f - 1.f)*0.5f;
        float iy = ((wyr + 1.f)*512.f - 1.f)*0.5f;
        float x0f = floorf(ix), y0f = floorf(iy);
        float fx = ix-x0f, fy = iy-y0f;
        float w00=(1.f-fx)*(1.f-fy), w10=fx*(1.f-fy), w01=(1.f-fx)*fy, w11=fx*fy;
        bool vx0 = (x0f>=0.f)&&(x0f<=511.f), vx1 = (x0f+1.f>=0.f)&&(x0f+1.f<=511.f);
        bool vy0 = (y0f>=0.f)&&(y0f<=511.f), vy1 = (y0f+1.f>=0.f)&&(y0f+1.f<=511.f);
        float m00 = (vx0&&vy0)?w00:0.f;
        float m10 = (vx1&&vy0)?w10:0.f;
        float m01 = (vx0&&vy1)?w01:0.f;
        float m11 = (vx1&&vy1)?w11:0.f;
        int X0 = (int)fminf(fmaxf(x0f,0.f),511.f);
        int X1 = (int)fminf(fmaxf(x0f+1.f,0.f),511.f);
        int Y0 = (int)fminf(fmaxf(y0f,0.f),511.f);
        int Y1 = (int)fminf(fmaxf(y0f+1.f,0.f),511.f);
        f32x4 t00 = *(const f32x4*)&it_b[((size_t)Y0*HOImg + X0)*4];
        f32x4 t10 = *(const f32x4*)&it_b[((size_t)Y0*HOImg + X1)*4];
        f32x4 t01 = *(const f32x4*)&it_b[((size_t)Y1*HOImg + X0)*4];
        f32x4 t11 = *(const f32x4*)&it_b[((size_t)Y1*HOImg + X1)*4];
        o0[i] = t00[0]*m00 + t10[0]*m10 + t01[0]*m01 + t11[0]*m11;
        o1[i] = t00[1]*m00 + t10[1]*m10 + t01[1]*m01 + t11[1]*m11;
        o2[i] = t00[2]*m00 + t10[2]*m10 + t01[2]*m01 + t11[2]*m11;
    }
    *(f32x4*)&out[((size_t)(m*3+0))*GG + g0] = o0;
    *(f32x4*)&out[((size_t)(m*3+1))*GG + g0] = o1;
    *(f32x4*)&out[((size_t)(m*3+2))*GG + g0] = o2;
}

// ============================ launcher =======================================
extern "C" void kernel_launch(void* const* d_in, const int* in_sizes, int n_in,
                              void* d_out, int out_size, void* d_ws, size_t ws_size,
                              hipStream_t stream)
{
    const float* x    = (const float*)d_in[0];
    const float* imgs = (const float*)d_in[1];
    const int*   kp   = (const int*)d_in[2];
    const float* c1w  = (const float*)d_in[3];
    const float* c2w  = (const float*)d_in[4];
    const float* l1w  = (const float*)d_in[5];
    const float* l1b  = (const float*)d_in[6];
    const float* l2w  = (const float*)d_in[7];
    const float* l2b  = (const float*)d_in[8];
    const float* l3w  = (const float*)d_in[9];
    const float* l3b  = (const float*)d_in[10];
    float* out = (float*)d_out;

    // ---- workspace layout: ALL DEDICATED, ZERO ALIASING (repacked, 44.5 MB) --
    char* W = (char*)d_ws;
    short* xph  = (short*)(W + 0);                          // 8,652,800
    float* imgT = (float*)(W + 8652800);                    // 16,777,216
    float* th0g = (float*)(W + 25430016);                   // 1,048,576
    short* B1   = (short*)(W + 26478592);                   // 147,456
    short* B2   = (short*)(W + 26626048);                   // 294,912
    float* Tab  = (float*)(W + 26920960);                   // 13,824
    unsigned short* Ug  = (unsigned short*)(W + 26934784);  // 196,608
    float* pgn  = (float*)(W + 27131392);                   // 8,192
    float* cbuf = (float*)(W + 27139584);                   // 256
    unsigned short* W1h = (unsigned short*)(W + 27140352);  // 65,536
    unsigned short* W1l = (unsigned short*)(W + 27205888);  // 65,536
    unsigned short* W2h = (unsigned short*)(W + 27271424);  // 131,072
    unsigned short* W2l = (unsigned short*)(W + 27402496);  // 131,072
    unsigned short* W3h = (unsigned short*)(W + 27533568);  // 73,728
    unsigned short* W3l = (unsigned short*)(W + 27607296);  // 73,728
    float* bxy  = (float*)(W + 27681024);                   // 16,777,216 -> 44,458,240

    hipLaunchKernelGGL(prep_xb_k, dim3(2,130,4), dim3(256), 0, stream, x, xph);
    hipLaunchKernelGGL(prep_img_k, dim3(2,512,4), dim3(256), 0, stream, imgs, imgT);
    hipLaunchKernelGGL(prep_misc_k, dim3(789), dim3(256), 0, stream,
                       c1w, c2w, l1w, l2w, l3w, B1, B2, Tab,
                       W1h, W1l, W2h, W2l, W3h, W3l);
    hipLaunchKernelGGL(ug_fill_k, dim3(4), dim3(256), 0, stream, cbuf, pgn, Ug);

    hipLaunchKernelGGL(spconv_k, dim3(MM/4), dim3(256), 0, stream,
                       xph, B1, B2, Tab, kp, th0g);

    hipLaunchKernelGGL(mlp_tps_k, dim3(MM/8), dim3(256), 0, stream,
                       th0g, W1h, W1l, W2h, W2l, W3h, W3l,
                       l1b, l2b, l3b, Ug, bxy);
    hipLaunchKernelGGL(sample_k, dim3(MM), dim3(256), 0, stream,
                       kp, bxy, pgn, cbuf, imgT, out);
}

// Round 24
// 111.874 us; speedup vs baseline: 1.4344x; 1.0698x over previous
//
#include <hip/hip_runtime.h>
#include <math.h>

// ---------------- problem constants ----------------
#define MM 2048             // B*N keypoints
#define HOImg 512
#define GG 1024             // HG*WG
#define NCTRL 64
#define NPAR 132            // NPARAM*2

#define BN_S 0.9999950000374997f   // 1/sqrt(1+1e-5)

typedef __bf16 bf16x8 __attribute__((ext_vector_type(8)));
typedef float  f32x4  __attribute__((ext_vector_type(4)));

__device__ __forceinline__ unsigned short f2b(float v){
    unsigned u = __float_as_uint(v);
    unsigned r = (u + 0x7FFFu + ((u>>16)&1u)) >> 16;
    return (unsigned short)r;
}
__device__ __forceinline__ float b2f(unsigned short s){
    return __uint_as_float(((unsigned)s)<<16);
}

// ===== prep_xb: x (4,64,128,128) f32 -> xp bf16 [4][130][130][64] =====
__global__ __launch_bounds__(256) void prep_xb_k(const float* __restrict__ x,
    short* __restrict__ XH)
{
    __shared__ float sT[64][65];
    const int xt = blockIdx.x, yo = blockIdx.y, b = blockIdx.z;
    const int tid = threadIdx.x;
    const int x0 = xt*64;

    if (yo == 0 || yo == 129){
        for (int e = tid; e < 4160; e += 256){      // half of 130*64
            int idx = xt*4160 + e;
            size_t o = (((size_t)b*130 + yo)*130 + idx/64)*64 + (idx&63);
            XH[o] = 0;
        }
        return;
    }
    const int ys = yo - 1;
    for (int e = tid; e < 64*64; e += 256) {
        int ci = e >> 6, xl = e & 63;
        sT[ci][xl] = x[(((size_t)b*64 + ci)*128 + ys)*128 + x0 + xl];
    }
    if (tid < 64){
        size_t o = (((size_t)b*130 + yo)*130 + (xt?129:0))*64 + tid;
        XH[o] = 0;
    }
    __syncthreads();
    for (int e = tid; e < 64*64; e += 256) {
        int xl = e >> 6, ci = e & 63;
        size_t o = (((size_t)b*130 + yo)*130 + (x0+xl+1))*64 + ci;
        XH[o] = (short)f2b(sT[ci][xl]);
    }
}

// ===== prep_img: imgs (4,3,512,512) -> imgT [b][y][x][4] f32 (dedicated) =====
__global__ __launch_bounds__(256) void prep_img_k(const float* __restrict__ imgs,
    float* __restrict__ imgT)
{
    const int x = blockIdx.x*256 + threadIdx.x;
    const int y = blockIdx.y, b = blockIdx.z;
    const size_t ib = ((size_t)b*3*HOImg + y)*HOImg + x;
    f32x4 v;
    v[0] = imgs[ib];
    v[1] = imgs[ib + (size_t)HOImg*HOImg];
    v[2] = imgs[ib + (size_t)2*HOImg*HOImg];
    v[3] = 0.f;
    *(f32x4*)&imgT[(((size_t)b*HOImg + y)*HOImg + x)*4] = v;
}

// ===== prep_misc =====
// B1f (bid 0..17):   conv1 B fragment-linearized: frag=(cc*9+k9)*8+wv*2+nt,
//                    idx = frag*512 + lane*8 + j  (one coalesced 1KB frag)
// B2f (bid 18..53):  conv2 B, same scheme (cc in 0..3)
// Tab (54..58), W1 split (59..186), W2 split (187..442), W3 split (443..586)
__global__ __launch_bounds__(256) void prep_misc_k(const float* __restrict__ w1,
    const float* __restrict__ w2, const float* __restrict__ l1w,
    const float* __restrict__ l2w, const float* __restrict__ l3w,
    short* __restrict__ B1H, short* __restrict__ B2H, float* __restrict__ Tab,
    unsigned short* __restrict__ W1h, unsigned short* __restrict__ W1l,
    unsigned short* __restrict__ W2h, unsigned short* __restrict__ W2l,
    unsigned short* __restrict__ W3h, unsigned short* __restrict__ W3l)
{
    int bid = blockIdx.x;
    if (bid < 18){
        const int p = bid, cc = p/9, k9 = p - (p/9)*9;
        const int ky = k9/3, kx = k9 - (k9/3)*3;
        #pragma unroll
        for (int it=0; it<16; ++it){
            int e = threadIdx.x + it*256;           // 0..4095
            int wv = e>>10, nt = (e>>9)&1, lane = (e>>3)&63, j = e&7;
            int l15 = lane&15, lg = lane>>4;
            int co = wv*32 + nt*16 + l15;
            int ci = cc*32 + lg*8 + j;
            float v = w1[((co*66 + ci)*3 + ky)*3 + kx];
            B1H[((p*4 + wv)*2 + nt)*512 + lane*8 + j] = (short)f2b(v);
        }
    } else if (bid < 54){
        const int p = bid-18, cc = p/9, k9 = p - (p/9)*9;
        const int ky = k9/3, kx = k9 - (k9/3)*3;
        #pragma unroll
        for (int it=0; it<16; ++it){
            int e = threadIdx.x + it*256;
            int wv = e>>10, nt = (e>>9)&1, lane = (e>>3)&63, j = e&7;
            int l15 = lane&15, lg = lane>>4;
            int co = wv*32 + nt*16 + l15;
            int ci = cc*32 + lg*8 + j;
            float v = w2[((co*128 + ci)*3 + ky)*3 + kx];
            B2H[((p*4 + wv)*2 + nt)*512 + lane*8 + j] = (short)f2b(v);
        }
    } else if (bid < 59){
        int i = (bid-54)*256 + threadIdx.x;
        if (i < 1152){
            int co = i/9, comb = i - (i/9)*9;
            int py = comb/3, px = comb - py*3;
            float w64[3][3], w65[3][3];
            #pragma unroll
            for (int ky=0;ky<3;ky++)
                #pragma unroll
                for (int kx=0;kx<3;kx++){
                    w64[ky][kx] = w1[((co*66 + 64)*3 + ky)*3 + kx];
                    w65[ky][kx] = w1[((co*66 + 65)*3 + ky)*3 + kx];
                }
            const int ky0 = (py==0)?1:0, ky1 = (py==2)?1:2;
            const int kx0 = (px==0)?1:0, kx1 = (px==2)?1:2;
            const float s = 2.f/127.f;
            float A = 0.f, Bc = 0.f, Cc = 0.f;
            for (int kx=kx0; kx<=kx1; ++kx){
                float wy = 0.f;
                for (int ky=ky0; ky<=ky1; ++ky) wy += w64[ky][kx];
                A  += wy * (-1.f + (float)(kx-1)*s);
                Bc += wy * s;
            }
            for (int ky=ky0; ky<=ky1; ++ky){
                float wx = 0.f;
                for (int kx=kx0; kx<=kx1; ++kx) wx += w65[ky][kx];
                A  += wx * (-1.f + (float)(ky-1)*s);
                Cc += wx * s;
            }
            float* d = Tab + ((size_t)comb*128 + co)*3;
            d[0] = A; d[1] = Bc; d[2] = Cc;
        }
    } else if (bid < 187){
        int e = (bid-59)*256 + threadIdx.x;     // 32768 = 256o x 128k
        float v = l1w[e];
        unsigned short hi = f2b(v);
        W1h[e] = hi; W1l[e] = f2b(v - b2f(hi));
    } else if (bid < 443){
        int e = (bid-187)*256 + threadIdx.x;    // 65536 = 256o x 256k
        float v = l2w[e];
        unsigned short hi = f2b(v);
        W2h[e] = hi; W2l[e] = f2b(v - b2f(hi));
    } else {
        int e = (bid-443)*256 + threadIdx.x;    // 36864 = 144o x 256k
        int o = e >> 8, k = e & 255;
        float v = (o < 132) ? l3w[o*256 + k] : 0.f;
        unsigned short hi = f2b(v);
        W3h[e] = hi; W3l[e] = f2b(v - b2f(hi));
    }
}

// ===== SPARSE conv1+conv2+interp: one block = 4 keypoints =====
// B loads now read fragment-linearized B1f/B2f: one 1KB coalesced read per
// fragment (was: 32 scattered cache lines per load instruction).
__global__ __launch_bounds__(256, 2) void spconv_k(
    const short* __restrict__ B1f_, const short* __restrict__ B2f_,
    const short* __restrict__ XP, const float* __restrict__ Tab,
    const int* __restrict__ kp, float* __restrict__ th0g)
{
    __shared__ __align__(16) short xL[10368];      // 4kp x 36(pos) x 72(ch pad)
    __shared__ __align__(16) short hL[8768];       // 4kp x (16pos x 136 + 16 pad)
    __shared__ int   sPY[4], sPX[4], sCY[4][2], sCX[4][2], sB[4];
    __shared__ float sWT[4][4];
    const int bid = blockIdx.x;
    const int tid = threadIdx.x;
    const int wv = tid>>6, lane = tid&63;
    const int l15 = lane&15, lg = lane>>4;

    if (tid < 4){
        int m = bid*4 + tid;
        sB[tid] = m >> 9;
        float ix = (float)kp[m*2+0]/511.f*125.f;
        float iy = (float)kp[m*2+1]/511.f*125.f;
        float x0f = floorf(ix), y0f = floorf(iy);
        float wx = ix-x0f, wy = iy-y0f;
        int X0 = (int)x0f, Y0 = (int)y0f;
        bool vx1 = (x0f+1.f <= 125.f), vy1 = (y0f+1.f <= 125.f);
        int X1 = vx1 ? X0+1 : 125;
        int Y1 = vy1 ? Y0+1 : 125;
        int pX0 = min(X0,124), pY0 = min(Y0,124);
        sPX[tid]=pX0; sPY[tid]=pY0;
        sCX[tid][0]=X0-pX0; sCX[tid][1]=X1-pX0;
        sCY[tid][0]=Y0-pY0; sCY[tid][1]=Y1-pY0;
        sWT[tid][0] = (1.f-wx)*(1.f-wy);
        sWT[tid][1] = vx1 ? wx*(1.f-wy) : 0.f;
        sWT[tid][2] = vy1 ? (1.f-wx)*wy : 0.f;
        sWT[tid][3] = (vx1&&vy1) ? wx*wy : 0.f;
    }
    __syncthreads();

    // stage 4 xp patches (6x6 pos x 64ch) -> xL, ch padded to 72
    for (int e = tid; e < 1152; e += 256){
        int pair = e >> 3, seg = e & 7;
        int ki = pair/36, rem = pair - ki*36;
        int row = rem/6, col = rem - row*6;
        const short* src = XP + (((size_t)sB[ki]*130 + sPY[ki]+row)*130
                                 + sPX[ki]+col)*64 + seg*8;
        int4 v = *(const int4*)src;
        *(int4*)&xL[(ki*36 + rem)*72 + seg*8] = v;
    }
    __syncthreads();

    // ---- conv1 ----
    f32x4 a1[4][2];
    #pragma unroll
    for (int i=0;i<4;i++){ a1[i][0]=(f32x4)(0.f); a1[i][1]=(f32x4)(0.f); }
    {
        const int py = l15>>2, px = l15&3;
        for (int cc=0; cc<2; ++cc){
            #pragma unroll
            for (int k9=0;k9<9;k9++){
                const int ky = k9/3, kx = k9 - (k9/3)*3;
                bf16x8 A[4], Bv[2];
                #pragma unroll
                for (int mt=0;mt<4;mt++)
                    A[mt] = *(const bf16x8*)&xL[(mt*36 + (py+ky)*6 + (px+kx))*72
                                                + cc*32 + lg*8];
                const int fb = (((cc*9+k9)*4 + wv)*2)*512 + lane*8;
                Bv[0] = *(const bf16x8*)(B1f_ + fb);
                Bv[1] = *(const bf16x8*)(B1f_ + fb + 512);
                #pragma unroll
                for (int mt=0;mt<4;mt++){
                    a1[mt][0] = __builtin_amdgcn_mfma_f32_16x16x32_bf16(A[mt], Bv[0], a1[mt][0],0,0,0);
                    a1[mt][1] = __builtin_amdgcn_mfma_f32_16x16x32_bf16(A[mt], Bv[1], a1[mt][1],0,0,0);
                }
            }
        }
    }
    // epilogue conv1 -> hL (bf16), Tab affine + BN + relu
    #pragma unroll
    for (int mt=0;mt<4;mt++){
        const int pY0 = sPY[mt], pX0 = sPX[mt];
        #pragma unroll
        for (int reg=0;reg<4;reg++){
            const int p = lg*4 + reg;
            const int py = p>>2, px = p&3;
            const int hy = pY0+py, hx = pX0+px;
            const int pyb = (hy==0)?0:((hy==127)?2:1);
            const int pxb = (hx==0)?0:((hx==127)?2:1);
            #pragma unroll
            for (int nt=0;nt<2;nt++){
                const int co = wv*32 + nt*16 + l15;
                const float* t3 = Tab + ((size_t)(pyb*3+pxb)*128 + co)*3;
                float a = a1[mt][nt][reg];
                a += t3[0] + t3[1]*(float)hx + t3[2]*(float)hy;
                float v = fmaxf(a*BN_S, 0.f);
                hL[mt*2192 + p*136 + co] = (short)f2b(v);
            }
        }
    }
    __syncthreads();

    // ---- conv2: M=16 (4kp x 4 corners) ----
    f32x4 a2[2];
    a2[0]=(f32x4)(0.f); a2[1]=(f32x4)(0.f);
    {
        const int ki = l15>>2, c = l15&3, cy = c>>1, cx = c&1;
        const int hbase = ki*2192 + (sCY[ki][cy]*4 + sCX[ki][cx])*136;
        for (int cc=0; cc<4; ++cc){
            #pragma unroll
            for (int k9=0;k9<9;k9++){
                const int ky = k9/3, kx = k9 - (k9/3)*3;
                bf16x8 A = *(const bf16x8*)&hL[hbase + (ky*4+kx)*136 + cc*32 + lg*8];
                const int fb = (((cc*9+k9)*4 + wv)*2)*512 + lane*8;
                bf16x8 Bv0 = *(const bf16x8*)(B2f_ + fb);
                bf16x8 Bv1 = *(const bf16x8*)(B2f_ + fb + 512);
                a2[0] = __builtin_amdgcn_mfma_f32_16x16x32_bf16(A, Bv0, a2[0],0,0,0);
                a2[1] = __builtin_amdgcn_mfma_f32_16x16x32_bf16(A, Bv1, a2[1],0,0,0);
            }
        }
    }
    // interp epilogue: Theta = relu(BN_S * conv2) per corner, THEN weight.
    {
        const float* w4 = sWT[lg];
        #pragma unroll
        for (int nt=0;nt<2;nt++){
            float c0 = fmaxf(a2[nt][0]*BN_S, 0.f);
            float c1 = fmaxf(a2[nt][1]*BN_S, 0.f);
            float c2 = fmaxf(a2[nt][2]*BN_S, 0.f);
            float c3 = fmaxf(a2[nt][3]*BN_S, 0.f);
            float r = ((c0*w4[0] + c1*w4[1]) + c2*w4[2]) + c3*w4[3];
            th0g[(size_t)(bid*4+lg)*128 + wv*32 + nt*16 + l15] = r;
        }
    }
}

// ===== ug_fill (merged consts): 4 blocks x 256 =====
__global__ __launch_bounds__(256) void ug_fill_k(float* __restrict__ cbuf,
    float* __restrict__ pgn, unsigned short* __restrict__ Ug)
{
    __shared__ float part[4][4];
    __shared__ float res[4];
    __shared__ float sc[64][2];
    const int tid = threadIdx.x;
    const int bid = blockIdx.x;

    float bxv[4], byv[4];
    float mnx=1e30f, mxx=-1e30f, mny=1e30f, mxy=-1e30f;
    #pragma unroll
    for (int t=0;t<4;t++){
        int g = tid + t*256;
        int i = g >> 5, j = g & 31;
        float xs = (j + 0.5f)*(2.0f/32.0f) - 1.0f;
        float ys = (i + 0.5f)*(2.0f/32.0f) - 1.0f;
        float norm = (xs + 1.0f)*0.5f;
        float r_ = 1.0f + norm*31.0f;
        float r_s = (r_ - 1.0f)/31.0f*2.0f*32.0f/512.0f;
        float t_s = (ys + 1.0f)*3.14159265358979323846f;
        float bx = r_s*cosf(t_s);
        float by = r_s*sinf(t_s);
        bxv[t]=bx; byv[t]=by;
        mnx=fminf(mnx,bx); mxx=fmaxf(mxx,bx);
        mny=fminf(mny,by); mxy=fmaxf(mxy,by);
    }
    #pragma unroll
    for (int s=1; s<64; s<<=1){
        mnx = fminf(mnx, __shfl_xor(mnx, s));
        mxx = fmaxf(mxx, __shfl_xor(mxx, s));
        mny = fminf(mny, __shfl_xor(mny, s));
        mxy = fmaxf(mxy, __shfl_xor(mxy, s));
    }
    int wv = tid>>6, ln = tid&63;
    if (ln == 0){ part[wv][0]=mnx; part[wv][1]=mxx; part[wv][2]=mny; part[wv][3]=mxy; }
    __syncthreads();
    if (tid < 4){
        float v = part[0][tid];
        for (int t=1;t<4;t++) v = (tid&1) ? fmaxf(v, part[t][tid]) : fminf(v, part[t][tid]);
        res[tid] = v;
    }
    __syncthreads();
    const float minx=res[0], maxx=res[1], miny=res[2], maxy=res[3];
    const float ptpx = maxx-minx, ptpy = maxy-miny;
    if (bid == 0 && tid == 0){ cbuf[0]=minx; cbuf[1]=miny; cbuf[2]=ptpx; cbuf[3]=ptpy; }

    #pragma unroll
    for (int t=0;t<4;t++){
        int g = tid + t*256;
        float pgx = (bxv[t] - minx)/(ptpx + 1e-8f)*0.3f + 0.35f;
        float pgy = (byv[t] - miny)/(ptpy + 1e-8f)*0.3f + 0.35f;
        pgn[2*g]   = pgx;
        pgn[2*g+1] = pgy;
    }
    if (tid < 64){
        int g = 128*(tid>>3) + 4*(tid&7);
        int i = g >> 5, j = g & 31;
        float xs = (j + 0.5f)*(2.0f/32.0f) - 1.0f;
        float ys = (i + 0.5f)*(2.0f/32.0f) - 1.0f;
        float norm = (xs + 1.0f)*0.5f;
        float r_ = 1.0f + norm*31.0f;
        float r_s = (r_ - 1.0f)/31.0f*2.0f*32.0f/512.0f;
        float t_s = (ys + 1.0f)*3.14159265358979323846f;
        float bx = r_s*cosf(t_s);
        float by = r_s*sinf(t_s);
        sc[tid][0] = (bx - minx)/(ptpx + 1e-8f)*0.3f + 0.35f;
        sc[tid][1] = (by - miny)/(ptpy + 1e-8f)*0.3f + 0.35f;
    }
    __syncthreads();

    const float px = (bxv[bid] - minx)/(ptpx + 1e-8f)*0.3f + 0.35f;
    const float py = (byv[bid] - miny)/(ptpy + 1e-8f)*0.3f + 0.35f;
    const int g = bid*256 + tid;
    float gg2 = px*px + py*py;
    unsigned int* dst = (unsigned int*)(Ug + (size_t)g*96);
    #pragma unroll
    for (int t=0;t<64;t+=2){
        float cx0=sc[t][0],   cy0=sc[t][1];
        float cx1=sc[t+1][0], cy1=sc[t+1][1];
        float r20 = fmaxf(gg2 + (cx0*cx0+cy0*cy0) - 2.f*(px*cx0+py*cy0), 0.f);
        float r21 = fmaxf(gg2 + (cx1*cx1+cy1*cy1) - 2.f*(px*cx1+py*cy1), 0.f);
        float u0 = r20*logf(sqrtf(r20+1e-12f)+1e-6f);
        float u1 = r21*logf(sqrtf(r21+1e-12f)+1e-6f);
        dst[t>>1] = (unsigned)f2b(u0) | ((unsigned)f2b(u1)<<16);
    }
    dst[32] = (unsigned)f2b(1.f) | ((unsigned)f2b(px)<<16);
    dst[33] = (unsigned)f2b(py);               // hi half = 0
    #pragma unroll
    for (int t=34;t<48;t++) dst[t] = 0u;
}

// ===== fused MLP+TPS: all linear layers as split-bf16 MFMA GEMMs =====
__global__ __launch_bounds__(256) void mlp_tps_k(const float* __restrict__ th0g,
    const unsigned short* __restrict__ W1h, const unsigned short* __restrict__ W1l,
    const unsigned short* __restrict__ W2h, const unsigned short* __restrict__ W2l,
    const unsigned short* __restrict__ W3h, const unsigned short* __restrict__ W3l,
    const float* __restrict__ l1b, const float* __restrict__ l2b,
    const float* __restrict__ l3b,
    const unsigned short* __restrict__ Ug, float* __restrict__ bxy)
{
    __shared__ unsigned short th0h[16][136], th0l[16][136];
    __shared__ unsigned short th1h[16][264], th1l[16][264];
    __shared__ unsigned short th2h[16][264], th2l[16][264];
    __shared__ float sth[8][132];
    __shared__ __align__(16) unsigned short sW[16][96];
    const int m0 = blockIdx.x*8;
    const int tid = threadIdx.x;
    const int wv = tid>>6, lane = tid&63;
    const int l15 = lane&15, lg = lane>>4;

    for (int e = tid; e < 2048; e += 256){
        int r = e >> 7, k = e & 127;
        float v = (r < 8) ? th0g[(size_t)(m0 + r)*128 + k] : 0.f;
        unsigned short hi = f2b(v);
        th0h[r][k] = hi; th0l[r][k] = f2b(v - b2f(hi));
    }
    __syncthreads();

    // ---- lin1: N=256 (4 frags/wave), K=128 (4 chunks), 3-pass split ----
    {
        f32x4 acc[4];
        #pragma unroll
        for (int nt=0;nt<4;nt++) acc[nt] = (f32x4)(0.f);
        for (int kc=0; kc<4; ++kc){
            bf16x8 Ah = *(const bf16x8*)&th0h[l15][kc*32 + lg*8];
            bf16x8 Al = *(const bf16x8*)&th0l[l15][kc*32 + lg*8];
            #pragma unroll
            for (int nt=0;nt<4;nt++){
                const int o = (wv*4+nt)*16 + l15;
                bf16x8 Bh = *(const bf16x8*)(W1h + (size_t)o*128 + kc*32 + lg*8);
                bf16x8 Bl = *(const bf16x8*)(W1l + (size_t)o*128 + kc*32 + lg*8);
                acc[nt] = __builtin_amdgcn_mfma_f32_16x16x32_bf16(Ah, Bh, acc[nt],0,0,0);
                acc[nt] = __builtin_amdgcn_mfma_f32_16x16x32_bf16(Ah, Bl, acc[nt],0,0,0);
                acc[nt] = __builtin_amdgcn_mfma_f32_16x16x32_bf16(Al, Bh, acc[nt],0,0,0);
            }
        }
        #pragma unroll
        for (int nt=0;nt<4;nt++){
            const int o = (wv*4+nt)*16 + l15;
            float bv = l1b[o];
            #pragma unroll
            for (int reg=0;reg<4;reg++){
                int r = lg*4+reg;
                float v = fmaxf((acc[nt][reg]+bv)*BN_S, 0.f);
                unsigned short hi = f2b(v);
                th1h[r][o] = hi; th1l[r][o] = f2b(v - b2f(hi));
            }
        }
    }
    __syncthreads();

    // ---- lin2: N=256, K=256 (8 chunks) ----
    {
        f32x4 acc[4];
        #pragma unroll
        for (int nt=0;nt<4;nt++) acc[nt] = (f32x4)(0.f);
        for (int kc=0; kc<8; ++kc){
            bf16x8 Ah = *(const bf16x8*)&th1h[l15][kc*32 + lg*8];
            bf16x8 Al = *(const bf16x8*)&th1l[l15][kc*32 + lg*8];
            #pragma unroll
            for (int nt=0;nt<4;nt++){
                const int o = (wv*4+nt)*16 + l15;
                bf16x8 Bh = *(const bf16x8*)(W2h + (size_t)o*256 + kc*32 + lg*8);
                bf16x8 Bl = *(const bf16x8*)(W2l + (size_t)o*256 + kc*32 + lg*8);
                acc[nt] = __builtin_amdgcn_mfma_f32_16x16x32_bf16(Ah, Bh, acc[nt],0,0,0);
                acc[nt] = __builtin_amdgcn_mfma_f32_16x16x32_bf16(Ah, Bl, acc[nt],0,0,0);
                acc[nt] = __builtin_amdgcn_mfma_f32_16x16x32_bf16(Al, Bh, acc[nt],0,0,0);
            }
        }
        #pragma unroll
        for (int nt=0;nt<4;nt++){
            const int o = (wv*4+nt)*16 + l15;
            float bv = l2b[o];
            #pragma unroll
            for (int reg=0;reg<4;reg++){
                int r = lg*4+reg;
                float v = fmaxf(acc[nt][reg]+bv, 0.f);
                unsigned short hi = f2b(v);
                th2h[r][o] = hi; th2l[r][o] = f2b(v - b2f(hi));
            }
        }
    }
    __syncthreads();

    // ---- lin3: N=144 (9 frags: waves {2,2,2,3}), K=256; tanh -> sth ----
    {
        f32x4 acc[3];
        #pragma unroll
        for (int t=0;t<3;t++) acc[t] = (f32x4)(0.f);
        const int nfr = (wv<3) ? 2 : 3;
        for (int kc=0; kc<8; ++kc){
            bf16x8 Ah = *(const bf16x8*)&th2h[l15][kc*32 + lg*8];
            bf16x8 Al = *(const bf16x8*)&th2l[l15][kc*32 + lg*8];
            for (int t=0;t<3;t++){
                if (t >= nfr) break;
                const int fr = (wv<3) ? (wv*2+t) : (6+t);
                const int o = fr*16 + l15;
                bf16x8 Bh = *(const bf16x8*)(W3h + (size_t)o*256 + kc*32 + lg*8);
                bf16x8 Bl = *(const bf16x8*)(W3l + (size_t)o*256 + kc*32 + lg*8);
                acc[t] = __builtin_amdgcn_mfma_f32_16x16x32_bf16(Ah, Bh, acc[t],0,0,0);
                acc[t] = __builtin_amdgcn_mfma_f32_16x16x32_bf16(Ah, Bl, acc[t],0,0,0);
                acc[t] = __builtin_amdgcn_mfma_f32_16x16x32_bf16(Al, Bh, acc[t],0,0,0);
            }
        }
        for (int t=0;t<3;t++){
            if (t >= nfr) break;
            const int fr = (wv<3) ? (wv*2+t) : (6+t);
            const int o = fr*16 + l15;
            if (o < NPAR){
                float bv = l3b[o];
                #pragma unroll
                for (int reg=0;reg<4;reg++){
                    int r = lg*4+reg;
                    if (r < 8) sth[r][o] = tanhf(acc[t][reg]+bv);
                }
            }
        }
    }
    __syncthreads();

    // ---- W+ prep ----
    if (tid < 16){
        int kpi = tid>>1, c = tid&1;
        float s = 0.f;
        for (int p=0;p<63;p++){ float w = sth[kpi][2*p+c]; s += w; sW[tid][1+p] = f2b(w); }
        sW[tid][0]  = f2b(-s);
        sW[tid][64] = f2b(sth[kpi][126+c]);
        sW[tid][65] = f2b(sth[kpi][128+c]);
        sW[tid][66] = f2b(sth[kpi][130+c]);
        for (int p=67;p<96;p++) sW[tid][p] = 0;
    }
    __syncthreads();
    // ---- TPS MFMA: bxy = Ug(1024x96) @ W+(96x16cols) ----
    bf16x8 Bf[3];
    #pragma unroll
    for (int ks=0;ks<3;ks++) Bf[ks] = *(const bf16x8*)&sW[l15][ks*32 + lg*8];
    const int gbase = wv*256;
    const int kpg = m0 + (l15>>1), c = l15&1;
    #pragma unroll
    for (int mf=0; mf<16; ++mf){
        f32x4 acc2 = (f32x4)(0.f);
        const unsigned short* ap = Ug + (size_t)(gbase + mf*16 + l15)*96 + lg*8;
        #pragma unroll
        for (int ks=0;ks<3;ks++){
            bf16x8 Af = *(const bf16x8*)(ap + ks*32);
            acc2 = __builtin_amdgcn_mfma_f32_16x16x32_bf16(Af, Bf[ks], acc2,0,0,0);
        }
        float* dst = bxy + ((size_t)kpg*2 + c)*1024 + gbase + mf*16 + lg*4;
        #pragma unroll
        for (int r=0;r<4;r++) dst[r] = acc2[r];
    }
}

// ===== sample: channels-last imgT gather, 2048 blocks, XCD-swizzled ========
__global__ __launch_bounds__(256) void sample_k(const int* __restrict__ kp,
    const float* __restrict__ bxy, const float* __restrict__ pgn,
    const float* __restrict__ cbuf, const float* __restrict__ imgT,
    float* __restrict__ out)
{
    const int bid = blockIdx.x;
    const int m = ((bid & 7) << 8) | (bid >> 3);   // bijective: 2048 = 8*256
    const int tid = threadIdx.x;
    const int b = m >> 9;
    const float vminx = cbuf[0] + ((float)kp[m*2+0]/512.f*2.f - 1.f);
    const float vminy = cbuf[1] + ((float)kp[m*2+1]/512.f*2.f - 1.f);
    const float ptpx = cbuf[2], ptpy = cbuf[3];
    const int g0 = tid*4;
    f32x4 zbx = *(const f32x4*)&bxy[((size_t)m*2+0)*1024 + g0];
    f32x4 zby = *(const f32x4*)&bxy[((size_t)m*2+1)*1024 + g0];
    f32x4 pga = *(const f32x4*)&pgn[2*g0];
    f32x4 pgb = *(const f32x4*)&pgn[2*g0+4];
    float px[4] = {pga[0], pga[2], pgb[0], pgb[2]};
    float py[4] = {pga[1], pga[3], pgb[1], pgb[3]};
    const float* it_b = imgT + (size_t)b*HOImg*HOImg*4;
    f32x4 o0, o1, o2;
    #pragma unroll
    for (int i=0;i<4;i++){
        float wnx = px[i] + zbx[i];
        float wny = py[i] + zby[i];
        float wxr = (wnx - 0.35f)/0.3f*ptpx + vminx;
        float wyr = (wny - 0.35f)/0.3f*ptpy + vminy;
        float ix = ((wxr + 1.f)*512.f - 1.f)*0.5f;
        float iy = ((wyr + 1.f)*512.f - 1.f)*0.5f;
        float x0f = floorf(ix), y0f = floorf(iy);
        float fx = ix-x0f, fy = iy-y0f;
        float w00=(1.f-fx)*(1.f-fy), w10=fx*(1.f-fy), w01=(1.f-fx)*fy, w11=fx*fy;
        bool vx0 = (x0f>=0.f)&&(x0f<=511.f), vx1 = (x0f+1.f>=0.f)&&(x0f+1.f<=511.f);
        bool vy0 = (y0f>=0.f)&&(y0f<=511.f), vy1 = (y0f+1.f>=0.f)&&(y0f+1.f<=511.f);
        float m00 = (vx0&&vy0)?w00:0.f;
        float m10 = (vx1&&vy0)?w10:0.f;
        float m01 = (vx0&&vy1)?w01:0.f;
        float m11 = (vx1&&vy1)?w11:0.f;
        int X0 = (int)fminf(fmaxf(x0f,0.f),511.f);
        int X1 = (int)fminf(fmaxf(x0f+1.f,0.f),511.f);
        int Y0 = (int)fminf(fmaxf(y0f,0.f),511.f);
        int Y1 = (int)fminf(fmaxf(y0f+1.f,0.f),511.f);
        f32x4 t00 = *(const f32x4*)&it_b[((size_t)Y0*HOImg + X0)*4];
        f32x4 t10 = *(const f32x4*)&it_b[((size_t)Y0*HOImg + X1)*4];
        f32x4 t01 = *(const f32x4*)&it_b[((size_t)Y1*HOImg + X0)*4];
        f32x4 t11 = *(const f32x4*)&it_b[((size_t)Y1*HOImg + X1)*4];
        o0[i] = t00[0]*m00 + t10[0]*m10 + t01[0]*m01 + t11[0]*m11;
        o1[i] = t00[1]*m00 + t10[1]*m10 + t01[1]*m01 + t11[1]*m11;
        o2[i] = t00[2]*m00 + t10[2]*m10 + t01[2]*m01 + t11[2]*m11;
    }
    *(f32x4*)&out[((size_t)(m*3+0))*GG + g0] = o0;
    *(f32x4*)&out[((size_t)(m*3+1))*GG + g0] = o1;
    *(f32x4*)&out[((size_t)(m*3+2))*GG + g0] = o2;
}

// ============================ launcher =======================================
extern "C" void kernel_launch(void* const* d_in, const int* in_sizes, int n_in,
                              void* d_out, int out_size, void* d_ws, size_t ws_size,
                              hipStream_t stream)
{
    const float* x    = (const float*)d_in[0];
    const float* imgs = (const float*)d_in[1];
    const int*   kp   = (const int*)d_in[2];
    const float* c1w  = (const float*)d_in[3];
    const float* c2w  = (const float*)d_in[4];
    const float* l1w  = (const float*)d_in[5];
    const float* l1b  = (const float*)d_in[6];
    const float* l2w  = (const float*)d_in[7];
    const float* l2b  = (const float*)d_in[8];
    const float* l3w  = (const float*)d_in[9];
    const float* l3b  = (const float*)d_in[10];
    float* out = (float*)d_out;

    // ---- workspace layout: ALL DEDICATED, ZERO ALIASING (44.5 MB) ----
    char* W = (char*)d_ws;
    short* xph  = (short*)(W + 0);                          // 8,652,800
    float* imgT = (float*)(W + 8652800);                    // 16,777,216
    float* th0g = (float*)(W + 25430016);                   // 1,048,576
    short* B1   = (short*)(W + 26478592);                   // 147,456 (B1f frags)
    short* B2   = (short*)(W + 26626048);                   // 294,912 (B2f frags)
    float* Tab  = (float*)(W + 26920960);                   // 13,824
    unsigned short* Ug  = (unsigned short*)(W + 26934784);  // 196,608
    float* pgn  = (float*)(W + 27131392);                   // 8,192
    float* cbuf = (float*)(W + 27139584);                   // 256
    unsigned short* W1h = (unsigned short*)(W + 27140352);  // 65,536
    unsigned short* W1l = (unsigned short*)(W + 27205888);  // 65,536
    unsigned short* W2h = (unsigned short*)(W + 27271424);  // 131,072
    unsigned short* W2l = (unsigned short*)(W + 27402496);  // 131,072
    unsigned short* W3h = (unsigned short*)(W + 27533568);  // 73,728
    unsigned short* W3l = (unsigned short*)(W + 27607296);  // 73,728
    float* bxy  = (float*)(W + 27681024);                   // 16,777,216 -> 44,458,240

    hipLaunchKernelGGL(prep_xb_k, dim3(2,130,4), dim3(256), 0, stream, x, xph);
    hipLaunchKernelGGL(prep_img_k, dim3(2,512,4), dim3(256), 0, stream, imgs, imgT);
    hipLaunchKernelGGL(prep_misc_k, dim3(587), dim3(256), 0, stream,
                       c1w, c2w, l1w, l2w, l3w, B1, B2, Tab,
                       W1h, W1l, W2h, W2l, W3h, W3l);
    hipLaunchKernelGGL(ug_fill_k, dim3(4), dim3(256), 0, stream, cbuf, pgn, Ug);

    hipLaunchKernelGGL(spconv_k, dim3(MM/4), dim3(256), 0, stream,
                       B1, B2, xph, Tab, kp, th0g);

    hipLaunchKernelGGL(mlp_tps_k, dim3(MM/8), dim3(256), 0, stream,
                       th0g, W1h, W1l, W2h, W2l, W3h, W3l,
                       l1b, l2b, l3b, Ug, bxy);
    hipLaunchKernelGGL(sample_k, dim3(MM), dim3(256), 0, stream,
                       kp, bxy, pgn, cbuf, imgT, out);
}

// Round 25
// 111.471 us; speedup vs baseline: 1.4396x; 1.0036x over previous
//
#include <hip/hip_runtime.h>
#include <math.h>

// ---------------- problem constants ----------------
#define MM 2048             // B*N keypoints
#define HOImg 512
#define GG 1024             // HG*WG
#define NCTRL 64
#define NPAR 132            // NPARAM*2

#define BN_S 0.9999950000374997f   // 1/sqrt(1+1e-5)

typedef __bf16 bf16x8 __attribute__((ext_vector_type(8)));
typedef float  f32x4  __attribute__((ext_vector_type(4)));

__device__ __forceinline__ unsigned short f2b(float v){
    unsigned u = __float_as_uint(v);
    unsigned r = (u + 0x7FFFu + ((u>>16)&1u)) >> 16;
    return (unsigned short)r;
}
__device__ __forceinline__ float b2f(unsigned short s){
    return __uint_as_float(((unsigned)s)<<16);
}

// ===== prep_xb: x (4,64,128,128) f32 -> xp bf16 [4][130][130][64] =====
__global__ __launch_bounds__(256) void prep_xb_k(const float* __restrict__ x,
    short* __restrict__ XH)
{
    __shared__ float sT[64][65];
    const int xt = blockIdx.x, yo = blockIdx.y, b = blockIdx.z;
    const int tid = threadIdx.x;
    const int x0 = xt*64;

    if (yo == 0 || yo == 129){
        for (int e = tid; e < 4160; e += 256){      // half of 130*64
            int idx = xt*4160 + e;
            size_t o = (((size_t)b*130 + yo)*130 + idx/64)*64 + (idx&63);
            XH[o] = 0;
        }
        return;
    }
    const int ys = yo - 1;
    for (int e = tid; e < 64*64; e += 256) {
        int ci = e >> 6, xl = e & 63;
        sT[ci][xl] = x[(((size_t)b*64 + ci)*128 + ys)*128 + x0 + xl];
    }
    if (tid < 64){
        size_t o = (((size_t)b*130 + yo)*130 + (xt?129:0))*64 + tid;
        XH[o] = 0;
    }
    __syncthreads();
    for (int e = tid; e < 64*64; e += 256) {
        int xl = e >> 6, ci = e & 63;
        size_t o = (((size_t)b*130 + yo)*130 + (x0+xl+1))*64 + ci;
        XH[o] = (short)f2b(sT[ci][xl]);
    }
}

// ===== prep_img: imgs (4,3,512,512) -> imgT [b][y][x][4] f32 (dedicated) =====
__global__ __launch_bounds__(256) void prep_img_k(const float* __restrict__ imgs,
    float* __restrict__ imgT)
{
    const int x = blockIdx.x*256 + threadIdx.x;
    const int y = blockIdx.y, b = blockIdx.z;
    const size_t ib = ((size_t)b*3*HOImg + y)*HOImg + x;
    f32x4 v;
    v[0] = imgs[ib];
    v[1] = imgs[ib + (size_t)HOImg*HOImg];
    v[2] = imgs[ib + (size_t)2*HOImg*HOImg];
    v[3] = 0.f;
    *(f32x4*)&imgT[(((size_t)b*HOImg + y)*HOImg + x)*4] = v;
}

// ===== prep_misc =====
// B1f (bid 0..17):   conv1 B fragment-linearized (frag*512 + lane*8 + j)
// B2f (bid 18..53):  conv2 B, same scheme
// Tab (54..58)
// W1f (59..186):     lin1 B frag-linearized: frag = kc*16 + wvnt (kc<4)
// W2f (187..442):    lin2: frag = kc*16 + wvnt (kc<8)
// W3f (443..586):    lin3: frag = kc*9 + fr (kc<8, fr<9; o>=132 -> 0)
__global__ __launch_bounds__(256) void prep_misc_k(const float* __restrict__ w1,
    const float* __restrict__ w2, const float* __restrict__ l1w,
    const float* __restrict__ l2w, const float* __restrict__ l3w,
    short* __restrict__ B1H, short* __restrict__ B2H, float* __restrict__ Tab,
    unsigned short* __restrict__ W1h, unsigned short* __restrict__ W1l,
    unsigned short* __restrict__ W2h, unsigned short* __restrict__ W2l,
    unsigned short* __restrict__ W3h, unsigned short* __restrict__ W3l)
{
    int bid = blockIdx.x;
    if (bid < 18){
        const int p = bid, cc = p/9, k9 = p - (p/9)*9;
        const int ky = k9/3, kx = k9 - (k9/3)*3;
        #pragma unroll
        for (int it=0; it<16; ++it){
            int e = threadIdx.x + it*256;           // 0..4095
            int wv = e>>10, nt = (e>>9)&1, lane = (e>>3)&63, j = e&7;
            int l15 = lane&15, lg = lane>>4;
            int co = wv*32 + nt*16 + l15;
            int ci = cc*32 + lg*8 + j;
            float v = w1[((co*66 + ci)*3 + ky)*3 + kx];
            B1H[((p*4 + wv)*2 + nt)*512 + lane*8 + j] = (short)f2b(v);
        }
    } else if (bid < 54){
        const int p = bid-18, cc = p/9, k9 = p - (p/9)*9;
        const int ky = k9/3, kx = k9 - (k9/3)*3;
        #pragma unroll
        for (int it=0; it<16; ++it){
            int e = threadIdx.x + it*256;
            int wv = e>>10, nt = (e>>9)&1, lane = (e>>3)&63, j = e&7;
            int l15 = lane&15, lg = lane>>4;
            int co = wv*32 + nt*16 + l15;
            int ci = cc*32 + lg*8 + j;
            float v = w2[((co*128 + ci)*3 + ky)*3 + kx];
            B2H[((p*4 + wv)*2 + nt)*512 + lane*8 + j] = (short)f2b(v);
        }
    } else if (bid < 59){
        int i = (bid-54)*256 + threadIdx.x;
        if (i < 1152){
            int co = i/9, comb = i - (i/9)*9;
            int py = comb/3, px = comb - py*3;
            float w64[3][3], w65[3][3];
            #pragma unroll
            for (int ky=0;ky<3;ky++)
                #pragma unroll
                for (int kx=0;kx<3;kx++){
                    w64[ky][kx] = w1[((co*66 + 64)*3 + ky)*3 + kx];
                    w65[ky][kx] = w1[((co*66 + 65)*3 + ky)*3 + kx];
                }
            const int ky0 = (py==0)?1:0, ky1 = (py==2)?1:2;
            const int kx0 = (px==0)?1:0, kx1 = (px==2)?1:2;
            const float s = 2.f/127.f;
            float A = 0.f, Bc = 0.f, Cc = 0.f;
            for (int kx=kx0; kx<=kx1; ++kx){
                float wy = 0.f;
                for (int ky=ky0; ky<=ky1; ++ky) wy += w64[ky][kx];
                A  += wy * (-1.f + (float)(kx-1)*s);
                Bc += wy * s;
            }
            for (int ky=ky0; ky<=ky1; ++ky){
                float wx = 0.f;
                for (int kx=kx0; kx<=kx1; ++kx) wx += w65[ky][kx];
                A  += wx * (-1.f + (float)(ky-1)*s);
                Cc += wx * s;
            }
            float* d = Tab + ((size_t)comb*128 + co)*3;
            d[0] = A; d[1] = Bc; d[2] = Cc;
        }
    } else if (bid < 187){
        int e = (bid-59)*256 + threadIdx.x;     // 0..32767
        int frag = e >> 9, lane = (e>>3)&63, j = e&7;
        int kc = frag >> 4, wvnt = frag & 15;
        int o = wvnt*16 + (lane&15);
        int k = kc*32 + (lane>>4)*8 + j;
        float v = l1w[o*128 + k];
        unsigned short hi = f2b(v);
        W1h[e] = hi; W1l[e] = f2b(v - b2f(hi));
    } else if (bid < 443){
        int e = (bid-187)*256 + threadIdx.x;    // 0..65535
        int frag = e >> 9, lane = (e>>3)&63, j = e&7;
        int kc = frag >> 4, wvnt = frag & 15;
        int o = wvnt*16 + (lane&15);
        int k = kc*32 + (lane>>4)*8 + j;
        float v = l2w[o*256 + k];
        unsigned short hi = f2b(v);
        W2h[e] = hi; W2l[e] = f2b(v - b2f(hi));
    } else {
        int e = (bid-443)*256 + threadIdx.x;    // 0..36863
        int frag = e >> 9, lane = (e>>3)&63, j = e&7;
        int kc = frag/9, fr = frag - (frag/9)*9;
        int o = fr*16 + (lane&15);
        int k = kc*32 + (lane>>4)*8 + j;
        float v = (o < 132) ? l3w[o*256 + k] : 0.f;
        unsigned short hi = f2b(v);
        W3h[e] = hi; W3l[e] = f2b(v - b2f(hi));
    }
}

// ===== SPARSE conv1+conv2+interp: one block = 4 keypoints =====
__global__ __launch_bounds__(256, 2) void spconv_k(
    const short* __restrict__ B1f_, const short* __restrict__ B2f_,
    const short* __restrict__ XP, const float* __restrict__ Tab,
    const int* __restrict__ kp, float* __restrict__ th0g)
{
    __shared__ __align__(16) short xL[10368];      // 4kp x 36(pos) x 72(ch pad)
    __shared__ __align__(16) short hL[8768];       // 4kp x (16pos x 136 + 16 pad)
    __shared__ int   sPY[4], sPX[4], sCY[4][2], sCX[4][2], sB[4];
    __shared__ float sWT[4][4];
    const int bid = blockIdx.x;
    const int tid = threadIdx.x;
    const int wv = tid>>6, lane = tid&63;
    const int l15 = lane&15, lg = lane>>4;

    if (tid < 4){
        int m = bid*4 + tid;
        sB[tid] = m >> 9;
        float ix = (float)kp[m*2+0]/511.f*125.f;
        float iy = (float)kp[m*2+1]/511.f*125.f;
        float x0f = floorf(ix), y0f = floorf(iy);
        float wx = ix-x0f, wy = iy-y0f;
        int X0 = (int)x0f, Y0 = (int)y0f;
        bool vx1 = (x0f+1.f <= 125.f), vy1 = (y0f+1.f <= 125.f);
        int X1 = vx1 ? X0+1 : 125;
        int Y1 = vy1 ? Y0+1 : 125;
        int pX0 = min(X0,124), pY0 = min(Y0,124);
        sPX[tid]=pX0; sPY[tid]=pY0;
        sCX[tid][0]=X0-pX0; sCX[tid][1]=X1-pX0;
        sCY[tid][0]=Y0-pY0; sCY[tid][1]=Y1-pY0;
        sWT[tid][0] = (1.f-wx)*(1.f-wy);
        sWT[tid][1] = vx1 ? wx*(1.f-wy) : 0.f;
        sWT[tid][2] = vy1 ? (1.f-wx)*wy : 0.f;
        sWT[tid][3] = (vx1&&vy1) ? wx*wy : 0.f;
    }
    __syncthreads();

    // stage 4 xp patches (6x6 pos x 64ch) -> xL, ch padded to 72
    for (int e = tid; e < 1152; e += 256){
        int pair = e >> 3, seg = e & 7;
        int ki = pair/36, rem = pair - ki*36;
        int row = rem/6, col = rem - row*6;
        const short* src = XP + (((size_t)sB[ki]*130 + sPY[ki]+row)*130
                                 + sPX[ki]+col)*64 + seg*8;
        int4 v = *(const int4*)src;
        *(int4*)&xL[(ki*36 + rem)*72 + seg*8] = v;
    }
    __syncthreads();

    // ---- conv1 ----
    f32x4 a1[4][2];
    #pragma unroll
    for (int i=0;i<4;i++){ a1[i][0]=(f32x4)(0.f); a1[i][1]=(f32x4)(0.f); }
    {
        const int py = l15>>2, px = l15&3;
        for (int cc=0; cc<2; ++cc){
            #pragma unroll
            for (int k9=0;k9<9;k9++){
                const int ky = k9/3, kx = k9 - (k9/3)*3;
                bf16x8 A[4], Bv[2];
                #pragma unroll
                for (int mt=0;mt<4;mt++)
                    A[mt] = *(const bf16x8*)&xL[(mt*36 + (py+ky)*6 + (px+kx))*72
                                                + cc*32 + lg*8];
                const int fb = (((cc*9+k9)*4 + wv)*2)*512 + lane*8;
                Bv[0] = *(const bf16x8*)(B1f_ + fb);
                Bv[1] = *(const bf16x8*)(B1f_ + fb + 512);
                #pragma unroll
                for (int mt=0;mt<4;mt++){
                    a1[mt][0] = __builtin_amdgcn_mfma_f32_16x16x32_bf16(A[mt], Bv[0], a1[mt][0],0,0,0);
                    a1[mt][1] = __builtin_amdgcn_mfma_f32_16x16x32_bf16(A[mt], Bv[1], a1[mt][1],0,0,0);
                }
            }
        }
    }
    // epilogue conv1 -> hL (bf16), Tab affine + BN + relu
    #pragma unroll
    for (int mt=0;mt<4;mt++){
        const int pY0 = sPY[mt], pX0 = sPX[mt];
        #pragma unroll
        for (int reg=0;reg<4;reg++){
            const int p = lg*4 + reg;
            const int py = p>>2, px = p&3;
            const int hy = pY0+py, hx = pX0+px;
            const int pyb = (hy==0)?0:((hy==127)?2:1);
            const int pxb = (hx==0)?0:((hx==127)?2:1);
            #pragma unroll
            for (int nt=0;nt<2;nt++){
                const int co = wv*32 + nt*16 + l15;
                const float* t3 = Tab + ((size_t)(pyb*3+pxb)*128 + co)*3;
                float a = a1[mt][nt][reg];
                a += t3[0] + t3[1]*(float)hx + t3[2]*(float)hy;
                float v = fmaxf(a*BN_S, 0.f);
                hL[mt*2192 + p*136 + co] = (short)f2b(v);
            }
        }
    }
    __syncthreads();

    // ---- conv2: M=16 (4kp x 4 corners) ----
    f32x4 a2[2];
    a2[0]=(f32x4)(0.f); a2[1]=(f32x4)(0.f);
    {
        const int ki = l15>>2, c = l15&3, cy = c>>1, cx = c&1;
        const int hbase = ki*2192 + (sCY[ki][cy]*4 + sCX[ki][cx])*136;
        for (int cc=0; cc<4; ++cc){
            #pragma unroll
            for (int k9=0;k9<9;k9++){
                const int ky = k9/3, kx = k9 - (k9/3)*3;
                bf16x8 A = *(const bf16x8*)&hL[hbase + (ky*4+kx)*136 + cc*32 + lg*8];
                const int fb = (((cc*9+k9)*4 + wv)*2)*512 + lane*8;
                bf16x8 Bv0 = *(const bf16x8*)(B2f_ + fb);
                bf16x8 Bv1 = *(const bf16x8*)(B2f_ + fb + 512);
                a2[0] = __builtin_amdgcn_mfma_f32_16x16x32_bf16(A, Bv0, a2[0],0,0,0);
                a2[1] = __builtin_amdgcn_mfma_f32_16x16x32_bf16(A, Bv1, a2[1],0,0,0);
            }
        }
    }
    // interp epilogue: Theta = relu(BN_S * conv2) per corner, THEN weight.
    {
        const float* w4 = sWT[lg];
        #pragma unroll
        for (int nt=0;nt<2;nt++){
            float c0 = fmaxf(a2[nt][0]*BN_S, 0.f);
            float c1 = fmaxf(a2[nt][1]*BN_S, 0.f);
            float c2 = fmaxf(a2[nt][2]*BN_S, 0.f);
            float c3 = fmaxf(a2[nt][3]*BN_S, 0.f);
            float r = ((c0*w4[0] + c1*w4[1]) + c2*w4[2]) + c3*w4[3];
            th0g[(size_t)(bid*4+lg)*128 + wv*32 + nt*16 + l15] = r;
        }
    }
}

// ===== ug_fill (merged consts): 4 blocks x 256 =====
__global__ __launch_bounds__(256) void ug_fill_k(float* __restrict__ cbuf,
    float* __restrict__ pgn, unsigned short* __restrict__ Ug)
{
    __shared__ float part[4][4];
    __shared__ float res[4];
    __shared__ float sc[64][2];
    const int tid = threadIdx.x;
    const int bid = blockIdx.x;

    float bxv[4], byv[4];
    float mnx=1e30f, mxx=-1e30f, mny=1e30f, mxy=-1e30f;
    #pragma unroll
    for (int t=0;t<4;t++){
        int g = tid + t*256;
        int i = g >> 5, j = g & 31;
        float xs = (j + 0.5f)*(2.0f/32.0f) - 1.0f;
        float ys = (i + 0.5f)*(2.0f/32.0f) - 1.0f;
        float norm = (xs + 1.0f)*0.5f;
        float r_ = 1.0f + norm*31.0f;
        float r_s = (r_ - 1.0f)/31.0f*2.0f*32.0f/512.0f;
        float t_s = (ys + 1.0f)*3.14159265358979323846f;
        float bx = r_s*cosf(t_s);
        float by = r_s*sinf(t_s);
        bxv[t]=bx; byv[t]=by;
        mnx=fminf(mnx,bx); mxx=fmaxf(mxx,bx);
        mny=fminf(mny,by); mxy=fmaxf(mxy,by);
    }
    #pragma unroll
    for (int s=1; s<64; s<<=1){
        mnx = fminf(mnx, __shfl_xor(mnx, s));
        mxx = fmaxf(mxx, __shfl_xor(mxx, s));
        mny = fminf(mny, __shfl_xor(mny, s));
        mxy = fmaxf(mxy, __shfl_xor(mxy, s));
    }
    int wv = tid>>6, ln = tid&63;
    if (ln == 0){ part[wv][0]=mnx; part[wv][1]=mxx; part[wv][2]=mny; part[wv][3]=mxy; }
    __syncthreads();
    if (tid < 4){
        float v = part[0][tid];
        for (int t=1;t<4;t++) v = (tid&1) ? fmaxf(v, part[t][tid]) : fminf(v, part[t][tid]);
        res[tid] = v;
    }
    __syncthreads();
    const float minx=res[0], maxx=res[1], miny=res[2], maxy=res[3];
    const float ptpx = maxx-minx, ptpy = maxy-miny;
    if (bid == 0 && tid == 0){ cbuf[0]=minx; cbuf[1]=miny; cbuf[2]=ptpx; cbuf[3]=ptpy; }

    #pragma unroll
    for (int t=0;t<4;t++){
        int g = tid + t*256;
        float pgx = (bxv[t] - minx)/(ptpx + 1e-8f)*0.3f + 0.35f;
        float pgy = (byv[t] - miny)/(ptpy + 1e-8f)*0.3f + 0.35f;
        pgn[2*g]   = pgx;
        pgn[2*g+1] = pgy;
    }
    if (tid < 64){
        int g = 128*(tid>>3) + 4*(tid&7);
        int i = g >> 5, j = g & 31;
        float xs = (j + 0.5f)*(2.0f/32.0f) - 1.0f;
        float ys = (i + 0.5f)*(2.0f/32.0f) - 1.0f;
        float norm = (xs + 1.0f)*0.5f;
        float r_ = 1.0f + norm*31.0f;
        float r_s = (r_ - 1.0f)/31.0f*2.0f*32.0f/512.0f;
        float t_s = (ys + 1.0f)*3.14159265358979323846f;
        float bx = r_s*cosf(t_s);
        float by = r_s*sinf(t_s);
        sc[tid][0] = (bx - minx)/(ptpx + 1e-8f)*0.3f + 0.35f;
        sc[tid][1] = (by - miny)/(ptpy + 1e-8f)*0.3f + 0.35f;
    }
    __syncthreads();

    const float px = (bxv[bid] - minx)/(ptpx + 1e-8f)*0.3f + 0.35f;
    const float py = (byv[bid] - miny)/(ptpy + 1e-8f)*0.3f + 0.35f;
    const int g = bid*256 + tid;
    float gg2 = px*px + py*py;
    unsigned int* dst = (unsigned int*)(Ug + (size_t)g*96);
    #pragma unroll
    for (int t=0;t<64;t+=2){
        float cx0=sc[t][0],   cy0=sc[t][1];
        float cx1=sc[t+1][0], cy1=sc[t+1][1];
        float r20 = fmaxf(gg2 + (cx0*cx0+cy0*cy0) - 2.f*(px*cx0+py*cy0), 0.f);
        float r21 = fmaxf(gg2 + (cx1*cx1+cy1*cy1) - 2.f*(px*cx1+py*cy1), 0.f);
        float u0 = r20*logf(sqrtf(r20+1e-12f)+1e-6f);
        float u1 = r21*logf(sqrtf(r21+1e-12f)+1e-6f);
        dst[t>>1] = (unsigned)f2b(u0) | ((unsigned)f2b(u1)<<16);
    }
    dst[32] = (unsigned)f2b(1.f) | ((unsigned)f2b(px)<<16);
    dst[33] = (unsigned)f2b(py);               // hi half = 0
    #pragma unroll
    for (int t=34;t<48;t++) dst[t] = 0u;
}

// ===== fused MLP+TPS: all linear layers as split-bf16 MFMA GEMMs =====
// Weights fragment-linearized: one coalesced 1KB read per B fragment.
__global__ __launch_bounds__(256) void mlp_tps_k(const float* __restrict__ th0g,
    const unsigned short* __restrict__ W1h, const unsigned short* __restrict__ W1l,
    const unsigned short* __restrict__ W2h, const unsigned short* __restrict__ W2l,
    const unsigned short* __restrict__ W3h, const unsigned short* __restrict__ W3l,
    const float* __restrict__ l1b, const float* __restrict__ l2b,
    const float* __restrict__ l3b,
    const unsigned short* __restrict__ Ug, float* __restrict__ bxy)
{
    __shared__ unsigned short th0h[16][136], th0l[16][136];
    __shared__ unsigned short th1h[16][264], th1l[16][264];
    __shared__ unsigned short th2h[16][264], th2l[16][264];
    __shared__ float sth[8][132];
    __shared__ __align__(16) unsigned short sW[16][96];
    const int m0 = blockIdx.x*8;
    const int tid = threadIdx.x;
    const int wv = tid>>6, lane = tid&63;
    const int l15 = lane&15, lg = lane>>4;

    for (int e = tid; e < 2048; e += 256){
        int r = e >> 7, k = e & 127;
        float v = (r < 8) ? th0g[(size_t)(m0 + r)*128 + k] : 0.f;
        unsigned short hi = f2b(v);
        th0h[r][k] = hi; th0l[r][k] = f2b(v - b2f(hi));
    }
    __syncthreads();

    // ---- lin1: N=256 (4 frags/wave), K=128 (4 chunks), 3-pass split ----
    {
        f32x4 acc[4];
        #pragma unroll
        for (int nt=0;nt<4;nt++) acc[nt] = (f32x4)(0.f);
        for (int kc=0; kc<4; ++kc){
            bf16x8 Ah = *(const bf16x8*)&th0h[l15][kc*32 + lg*8];
            bf16x8 Al = *(const bf16x8*)&th0l[l15][kc*32 + lg*8];
            #pragma unroll
            for (int nt=0;nt<4;nt++){
                const int fb = (kc*16 + wv*4 + nt)*512 + lane*8;
                bf16x8 Bh = *(const bf16x8*)(W1h + fb);
                bf16x8 Bl = *(const bf16x8*)(W1l + fb);
                acc[nt] = __builtin_amdgcn_mfma_f32_16x16x32_bf16(Ah, Bh, acc[nt],0,0,0);
                acc[nt] = __builtin_amdgcn_mfma_f32_16x16x32_bf16(Ah, Bl, acc[nt],0,0,0);
                acc[nt] = __builtin_amdgcn_mfma_f32_16x16x32_bf16(Al, Bh, acc[nt],0,0,0);
            }
        }
        #pragma unroll
        for (int nt=0;nt<4;nt++){
            const int o = (wv*4+nt)*16 + l15;
            float bv = l1b[o];
            #pragma unroll
            for (int reg=0;reg<4;reg++){
                int r = lg*4+reg;
                float v = fmaxf((acc[nt][reg]+bv)*BN_S, 0.f);
                unsigned short hi = f2b(v);
                th1h[r][o] = hi; th1l[r][o] = f2b(v - b2f(hi));
            }
        }
    }
    __syncthreads();

    // ---- lin2: N=256, K=256 (8 chunks) ----
    {
        f32x4 acc[4];
        #pragma unroll
        for (int nt=0;nt<4;nt++) acc[nt] = (f32x4)(0.f);
        for (int kc=0; kc<8; ++kc){
            bf16x8 Ah = *(const bf16x8*)&th1h[l15][kc*32 + lg*8];
            bf16x8 Al = *(const bf16x8*)&th1l[l15][kc*32 + lg*8];
            #pragma unroll
            for (int nt=0;nt<4;nt++){
                const int fb = (kc*16 + wv*4 + nt)*512 + lane*8;
                bf16x8 Bh = *(const bf16x8*)(W2h + fb);
                bf16x8 Bl = *(const bf16x8*)(W2l + fb);
                acc[nt] = __builtin_amdgcn_mfma_f32_16x16x32_bf16(Ah, Bh, acc[nt],0,0,0);
                acc[nt] = __builtin_amdgcn_mfma_f32_16x16x32_bf16(Ah, Bl, acc[nt],0,0,0);
                acc[nt] = __builtin_amdgcn_mfma_f32_16x16x32_bf16(Al, Bh, acc[nt],0,0,0);
            }
        }
        #pragma unroll
        for (int nt=0;nt<4;nt++){
            const int o = (wv*4+nt)*16 + l15;
            float bv = l2b[o];
            #pragma unroll
            for (int reg=0;reg<4;reg++){
                int r = lg*4+reg;
                float v = fmaxf(acc[nt][reg]+bv, 0.f);
                unsigned short hi = f2b(v);
                th2h[r][o] = hi; th2l[r][o] = f2b(v - b2f(hi));
            }
        }
    }
    __syncthreads();

    // ---- lin3: N=144 (9 frags: waves {2,2,2,3}), K=256; tanh -> sth ----
    {
        f32x4 acc[3];
        #pragma unroll
        for (int t=0;t<3;t++) acc[t] = (f32x4)(0.f);
        const int nfr = (wv<3) ? 2 : 3;
        for (int kc=0; kc<8; ++kc){
            bf16x8 Ah = *(const bf16x8*)&th2h[l15][kc*32 + lg*8];
            bf16x8 Al = *(const bf16x8*)&th2l[l15][kc*32 + lg*8];
            for (int t=0;t<3;t++){
                if (t >= nfr) break;
                const int fr = (wv<3) ? (wv*2+t) : (6+t);
                const int fb = (kc*9 + fr)*512 + lane*8;
                bf16x8 Bh = *(const bf16x8*)(W3h + fb);
                bf16x8 Bl = *(const bf16x8*)(W3l + fb);
                acc[t] = __builtin_amdgcn_mfma_f32_16x16x32_bf16(Ah, Bh, acc[t],0,0,0);
                acc[t] = __builtin_amdgcn_mfma_f32_16x16x32_bf16(Ah, Bl, acc[t],0,0,0);
                acc[t] = __builtin_amdgcn_mfma_f32_16x16x32_bf16(Al, Bh, acc[t],0,0,0);
            }
        }
        for (int t=0;t<3;t++){
            if (t >= nfr) break;
            const int fr = (wv<3) ? (wv*2+t) : (6+t);
            const int o = fr*16 + l15;
            if (o < NPAR){
                float bv = l3b[o];
                #pragma unroll
                for (int reg=0;reg<4;reg++){
                    int r = lg*4+reg;
                    if (r < 8) sth[r][o] = tanhf(acc[t][reg]+bv);
                }
            }
        }
    }
    __syncthreads();

    // ---- W+ prep ----
    if (tid < 16){
        int kpi = tid>>1, c = tid&1;
        float s = 0.f;
        for (int p=0;p<63;p++){ float w = sth[kpi][2*p+c]; s += w; sW[tid][1+p] = f2b(w); }
        sW[tid][0]  = f2b(-s);
        sW[tid][64] = f2b(sth[kpi][126+c]);
        sW[tid][65] = f2b(sth[kpi][128+c]);
        sW[tid][66] = f2b(sth[kpi][130+c]);
        for (int p=67;p<96;p++) sW[tid][p] = 0;
    }
    __syncthreads();
    // ---- TPS MFMA: bxy = Ug(1024x96) @ W+(96x16cols) ----
    bf16x8 Bf[3];
    #pragma unroll
    for (int ks=0;ks<3;ks++) Bf[ks] = *(const bf16x8*)&sW[l15][ks*32 + lg*8];
    const int gbase = wv*256;
    const int kpg = m0 + (l15>>1), c = l15&1;
    #pragma unroll
    for (int mf=0; mf<16; ++mf){
        f32x4 acc2 = (f32x4)(0.f);
        const unsigned short* ap = Ug + (size_t)(gbase + mf*16 + l15)*96 + lg*8;
        #pragma unroll
        for (int ks=0;ks<3;ks++){
            bf16x8 Af = *(const bf16x8*)(ap + ks*32);
            acc2 = __builtin_amdgcn_mfma_f32_16x16x32_bf16(Af, Bf[ks], acc2,0,0,0);
        }
        float* dst = bxy + ((size_t)kpg*2 + c)*1024 + gbase + mf*16 + lg*4;
        #pragma unroll
        for (int r=0;r<4;r++) dst[r] = acc2[r];
    }
}

// ===== sample: channels-last imgT gather, 2048 blocks, XCD-swizzled ========
__global__ __launch_bounds__(256) void sample_k(const int* __restrict__ kp,
    const float* __restrict__ bxy, const float* __restrict__ pgn,
    const float* __restrict__ cbuf, const float* __restrict__ imgT,
    float* __restrict__ out)
{
    const int bid = blockIdx.x;
    const int m = ((bid & 7) << 8) | (bid >> 3);   // bijective: 2048 = 8*256
    const int tid = threadIdx.x;
    const int b = m >> 9;
    const float vminx = cbuf[0] + ((float)kp[m*2+0]/512.f*2.f - 1.f);
    const float vminy = cbuf[1] + ((float)kp[m*2+1]/512.f*2.f - 1.f);
    const float ptpx = cbuf[2], ptpy = cbuf[3];
    const int g0 = tid*4;
    f32x4 zbx = *(const f32x4*)&bxy[((size_t)m*2+0)*1024 + g0];
    f32x4 zby = *(const f32x4*)&bxy[((size_t)m*2+1)*1024 + g0];
    f32x4 pga = *(const f32x4*)&pgn[2*g0];
    f32x4 pgb = *(const f32x4*)&pgn[2*g0+4];
    float px[4] = {pga[0], pga[2], pgb[0], pgb[2]};
    float py[4] = {pga[1], pga[3], pgb[1], pgb[3]};
    const float* it_b = imgT + (size_t)b*HOImg*HOImg*4;
    f32x4 o0, o1, o2;
    #pragma unroll
    for (int i=0;i<4;i++){
        float wnx = px[i] + zbx[i];
        float wny = py[i] + zby[i];
        float wxr = (wnx - 0.35f)/0.3f*ptpx + vminx;
        float wyr = (wny - 0.35f)/0.3f*ptpy + vminy;
        float ix = ((wxr + 1.f)*512.f - 1.f)*0.5f;
        float iy = ((wyr + 1.f)*512.f - 1.f)*0.5f;
        float x0f = floorf(ix), y0f = floorf(iy);
        float fx = ix-x0f, fy = iy-y0f;
        float w00=(1.f-fx)*(1.f-fy), w10=fx*(1.f-fy), w01=(1.f-fx)*fy, w11=fx*fy;
        bool vx0 = (x0f>=0.f)&&(x0f<=511.f), vx1 = (x0f+1.f>=0.f)&&(x0f+1.f<=511.f);
        bool vy0 = (y0f>=0.f)&&(y0f<=511.f), vy1 = (y0f+1.f>=0.f)&&(y0f+1.f<=511.f);
        float m00 = (vx0&&vy0)?w00:0.f;
        float m10 = (vx1&&vy0)?w10:0.f;
        float m01 = (vx0&&vy1)?w01:0.f;
        float m11 = (vx1&&vy1)?w11:0.f;
        int X0 = (int)fminf(fmaxf(x0f,0.f),511.f);
        int X1 = (int)fminf(fmaxf(x0f+1.f,0.f),511.f);
        int Y0 = (int)fminf(fmaxf(y0f,0.f),511.f);
        int Y1 = (int)fminf(fmaxf(y0f+1.f,0.f),511.f);
        f32x4 t00 = *(const f32x4*)&it_b[((size_t)Y0*HOImg + X0)*4];
        f32x4 t10 = *(const f32x4*)&it_b[((size_t)Y0*HOImg + X1)*4];
        f32x4 t01 = *(const f32x4*)&it_b[((size_t)Y1*HOImg + X0)*4];
        f32x4 t11 = *(const f32x4*)&it_b[((size_t)Y1*HOImg + X1)*4];
        o0[i] = t00[0]*m00 + t10[0]*m10 + t01[0]*m01 + t11[0]*m11;
        o1[i] = t00[1]*m00 + t10[1]*m10 + t01[1]*m01 + t11[1]*m11;
        o2[i] = t00[2]*m00 + t10[2]*m10 + t01[2]*m01 + t11[2]*m11;
    }
    *(f32x4*)&out[((size_t)(m*3+0))*GG + g0] = o0;
    *(f32x4*)&out[((size_t)(m*3+1))*GG + g0] = o1;
    *(f32x4*)&out[((size_t)(m*3+2))*GG + g0] = o2;
}

// ============================ launcher =======================================
extern "C" void kernel_launch(void* const* d_in, const int* in_sizes, int n_in,
                              void* d_out, int out_size, void* d_ws, size_t ws_size,
                              hipStream_t stream)
{
    const float* x    = (const float*)d_in[0];
    const float* imgs = (const float*)d_in[1];
    const int*   kp   = (const int*)d_in[2];
    const float* c1w  = (const float*)d_in[3];
    const float* c2w  = (const float*)d_in[4];
    const float* l1w  = (const float*)d_in[5];
    const float* l1b  = (const float*)d_in[6];
    const float* l2w  = (const float*)d_in[7];
    const float* l2b  = (const float*)d_in[8];
    const float* l3w  = (const float*)d_in[9];
    const float* l3b  = (const float*)d_in[10];
    float* out = (float*)d_out;

    // ---- workspace layout: ALL DEDICATED, ZERO ALIASING (44.5 MB) ----
    char* W = (char*)d_ws;
    short* xph  = (short*)(W + 0);                          // 8,652,800
    float* imgT = (float*)(W + 8652800);                    // 16,777,216
    float* th0g = (float*)(W + 25430016);                   // 1,048,576
    short* B1   = (short*)(W + 26478592);                   // 147,456 (B1f frags)
    short* B2   = (short*)(W + 26626048);                   // 294,912 (B2f frags)
    float* Tab  = (float*)(W + 26920960);                   // 13,824
    unsigned short* Ug  = (unsigned short*)(W + 26934784);  // 196,608
    float* pgn  = (float*)(W + 27131392);                   // 8,192
    float* cbuf = (float*)(W + 27139584);                   // 256
    unsigned short* W1h = (unsigned short*)(W + 27140352);  // 65,536
    unsigned short* W1l = (unsigned short*)(W + 27205888);  // 65,536
    unsigned short* W2h = (unsigned short*)(W + 27271424);  // 131,072
    unsigned short* W2l = (unsigned short*)(W + 27402496);  // 131,072
    unsigned short* W3h = (unsigned short*)(W + 27533568);  // 73,728
    unsigned short* W3l = (unsigned short*)(W + 27607296);  // 73,728
    float* bxy  = (float*)(W + 27681024);                   // 16,777,216 -> 44,458,240

    hipLaunchKernelGGL(prep_xb_k, dim3(2,130,4), dim3(256), 0, stream, x, xph);
    hipLaunchKernelGGL(prep_img_k, dim3(2,512,4), dim3(256), 0, stream, imgs, imgT);
    hipLaunchKernelGGL(prep_misc_k, dim3(587), dim3(256), 0, stream,
                       c1w, c2w, l1w, l2w, l3w, B1, B2, Tab,
                       W1h, W1l, W2h, W2l, W3h, W3l);
    hipLaunchKernelGGL(ug_fill_k, dim3(4), dim3(256), 0, stream, cbuf, pgn, Ug);

    hipLaunchKernelGGL(spconv_k, dim3(MM/4), dim3(256), 0, stream,
                       B1, B2, xph, Tab, kp, th0g);

    hipLaunchKernelGGL(mlp_tps_k, dim3(MM/8), dim3(256), 0, stream,
                       th0g, W1h, W1l, W2h, W2l, W3h, W3l,
                       l1b, l2b, l3b, Ug, bxy);
    hipLaunchKernelGGL(sample_k, dim3(MM), dim3(256), 0, stream,
                       kp, bxy, pgn, cbuf, imgT, out);
}

// Round 26
// 101.008 us; speedup vs baseline: 1.5887x; 1.1036x over previous
//
#include <hip/hip_runtime.h>
#include <math.h>

// ---------------- problem constants ----------------
#define MM 2048             // B*N keypoints
#define HOImg 512
#define GG 1024             // HG*WG
#define NCTRL 64
#define NPAR 132            // NPARAM*2

#define BN_S 0.9999950000374997f   // 1/sqrt(1+1e-5)

typedef __bf16 bf16x8 __attribute__((ext_vector_type(8)));
typedef float  f32x4  __attribute__((ext_vector_type(4)));

__device__ __forceinline__ unsigned short f2b(float v){
    unsigned u = __float_as_uint(v);
    unsigned r = (u + 0x7FFFu + ((u>>16)&1u)) >> 16;
    return (unsigned short)r;
}
__device__ __forceinline__ float b2f(unsigned short s){
    return __uint_as_float(((unsigned)s)<<16);
}

// ===== prep_all: merged prep_xb (0..1039), prep_img (1040..5135),
//       prep_misc (5136..5722), ug_fill (5723..5726). All sub-parts are the
//       exact prior kernel bodies (bit-identical outputs, disjoint writes).
__global__ __launch_bounds__(256) void prep_all_k(
    const float* __restrict__ x, const float* __restrict__ imgs,
    const float* __restrict__ w1, const float* __restrict__ w2,
    const float* __restrict__ l1w, const float* __restrict__ l2w,
    const float* __restrict__ l3w,
    short* __restrict__ XH, float* __restrict__ imgT,
    short* __restrict__ B1H, short* __restrict__ B2H, float* __restrict__ Tab,
    unsigned short* __restrict__ W1h, unsigned short* __restrict__ W1l,
    unsigned short* __restrict__ W2h, unsigned short* __restrict__ W2l,
    unsigned short* __restrict__ W3h, unsigned short* __restrict__ W3l,
    float* __restrict__ cbuf, float* __restrict__ pgn,
    unsigned short* __restrict__ Ug)
{
    __shared__ float sT[64][65];
    __shared__ float part[4][4];
    __shared__ float res[4];
    __shared__ float sc[64][2];
    const int gbid = blockIdx.x;
    const int tid = threadIdx.x;

    if (gbid < 1040){
        // ---- prep_xb ----
        const int lb = gbid;
        const int xt = lb & 1, yo = (lb>>1)%130, b = lb/260;
        const int x0 = xt*64;
        if (yo == 0 || yo == 129){
            for (int e = tid; e < 4160; e += 256){
                int idx = xt*4160 + e;
                size_t o = (((size_t)b*130 + yo)*130 + idx/64)*64 + (idx&63);
                XH[o] = 0;
            }
            return;
        }
        const int ys = yo - 1;
        for (int e = tid; e < 64*64; e += 256) {
            int ci = e >> 6, xl = e & 63;
            sT[ci][xl] = x[(((size_t)b*64 + ci)*128 + ys)*128 + x0 + xl];
        }
        if (tid < 64){
            size_t o = (((size_t)b*130 + yo)*130 + (xt?129:0))*64 + tid;
            XH[o] = 0;
        }
        __syncthreads();
        for (int e = tid; e < 64*64; e += 256) {
            int xl = e >> 6, ci = e & 63;
            size_t o = (((size_t)b*130 + yo)*130 + (x0+xl+1))*64 + ci;
            XH[o] = (short)f2b(sT[ci][xl]);
        }
    } else if (gbid < 5136){
        // ---- prep_img ----
        const int lb = gbid - 1040;
        const int xt = lb & 1, y = (lb>>1)&511, b = lb>>10;
        const int xx = xt*256 + tid;
        const size_t ib = ((size_t)b*3*HOImg + y)*HOImg + xx;
        f32x4 v;
        v[0] = imgs[ib];
        v[1] = imgs[ib + (size_t)HOImg*HOImg];
        v[2] = imgs[ib + (size_t)2*HOImg*HOImg];
        v[3] = 0.f;
        *(f32x4*)&imgT[(((size_t)b*HOImg + y)*HOImg + xx)*4] = v;
    } else if (gbid < 5723){
        // ---- prep_misc ----
        const int bid = gbid - 5136;
        if (bid < 18){
            const int p = bid, cc = p/9, k9 = p - (p/9)*9;
            const int ky = k9/3, kx = k9 - (k9/3)*3;
            #pragma unroll
            for (int it=0; it<16; ++it){
                int e = tid + it*256;
                int wv = e>>10, nt = (e>>9)&1, lane = (e>>3)&63, j = e&7;
                int l15 = lane&15, lg = lane>>4;
                int co = wv*32 + nt*16 + l15;
                int ci = cc*32 + lg*8 + j;
                float v = w1[((co*66 + ci)*3 + ky)*3 + kx];
                B1H[((p*4 + wv)*2 + nt)*512 + lane*8 + j] = (short)f2b(v);
            }
        } else if (bid < 54){
            const int p = bid-18, cc = p/9, k9 = p - (p/9)*9;
            const int ky = k9/3, kx = k9 - (k9/3)*3;
            #pragma unroll
            for (int it=0; it<16; ++it){
                int e = tid + it*256;
                int wv = e>>10, nt = (e>>9)&1, lane = (e>>3)&63, j = e&7;
                int l15 = lane&15, lg = lane>>4;
                int co = wv*32 + nt*16 + l15;
                int ci = cc*32 + lg*8 + j;
                float v = w2[((co*128 + ci)*3 + ky)*3 + kx];
                B2H[((p*4 + wv)*2 + nt)*512 + lane*8 + j] = (short)f2b(v);
            }
        } else if (bid < 59){
            int i = (bid-54)*256 + tid;
            if (i < 1152){
                int co = i/9, comb = i - (i/9)*9;
                int py = comb/3, px = comb - py*3;
                float w64[3][3], w65[3][3];
                #pragma unroll
                for (int ky=0;ky<3;ky++)
                    #pragma unroll
                    for (int kx=0;kx<3;kx++){
                        w64[ky][kx] = w1[((co*66 + 64)*3 + ky)*3 + kx];
                        w65[ky][kx] = w1[((co*66 + 65)*3 + ky)*3 + kx];
                    }
                const int ky0 = (py==0)?1:0, ky1 = (py==2)?1:2;
                const int kx0 = (px==0)?1:0, kx1 = (px==2)?1:2;
                const float s = 2.f/127.f;
                float A = 0.f, Bc = 0.f, Cc = 0.f;
                for (int kx=kx0; kx<=kx1; ++kx){
                    float wy = 0.f;
                    for (int ky=ky0; ky<=ky1; ++ky) wy += w64[ky][kx];
                    A  += wy * (-1.f + (float)(kx-1)*s);
                    Bc += wy * s;
                }
                for (int ky=ky0; ky<=ky1; ++ky){
                    float wx = 0.f;
                    for (int kx=kx0; kx<=kx1; ++kx) wx += w65[ky][kx];
                    A  += wx * (-1.f + (float)(ky-1)*s);
                    Cc += wx * s;
                }
                float* d = Tab + ((size_t)comb*128 + co)*3;
                d[0] = A; d[1] = Bc; d[2] = Cc;
            }
        } else if (bid < 187){
            int e = (bid-59)*256 + tid;
            int frag = e >> 9, lane = (e>>3)&63, j = e&7;
            int kc = frag >> 4, wvnt = frag & 15;
            int o = wvnt*16 + (lane&15);
            int k = kc*32 + (lane>>4)*8 + j;
            float v = l1w[o*128 + k];
            unsigned short hi = f2b(v);
            W1h[e] = hi; W1l[e] = f2b(v - b2f(hi));
        } else if (bid < 443){
            int e = (bid-187)*256 + tid;
            int frag = e >> 9, lane = (e>>3)&63, j = e&7;
            int kc = frag >> 4, wvnt = frag & 15;
            int o = wvnt*16 + (lane&15);
            int k = kc*32 + (lane>>4)*8 + j;
            float v = l2w[o*256 + k];
            unsigned short hi = f2b(v);
            W2h[e] = hi; W2l[e] = f2b(v - b2f(hi));
        } else {
            int e = (bid-443)*256 + tid;
            int frag = e >> 9, lane = (e>>3)&63, j = e&7;
            int kc = frag/9, fr = frag - (frag/9)*9;
            int o = fr*16 + (lane&15);
            int k = kc*32 + (lane>>4)*8 + j;
            float v = (o < 132) ? l3w[o*256 + k] : 0.f;
            unsigned short hi = f2b(v);
            W3h[e] = hi; W3l[e] = f2b(v - b2f(hi));
        }
    } else {
        // ---- ug_fill (4 blocks) ----
        const int bid = gbid - 5723;
        float bxv[4], byv[4];
        float mnx=1e30f, mxx=-1e30f, mny=1e30f, mxy=-1e30f;
        #pragma unroll
        for (int t=0;t<4;t++){
            int g = tid + t*256;
            int i = g >> 5, j = g & 31;
            float xs = (j + 0.5f)*(2.0f/32.0f) - 1.0f;
            float ys = (i + 0.5f)*(2.0f/32.0f) - 1.0f;
            float norm = (xs + 1.0f)*0.5f;
            float r_ = 1.0f + norm*31.0f;
            float r_s = (r_ - 1.0f)/31.0f*2.0f*32.0f/512.0f;
            float t_s = (ys + 1.0f)*3.14159265358979323846f;
            float bx = r_s*cosf(t_s);
            float by = r_s*sinf(t_s);
            bxv[t]=bx; byv[t]=by;
            mnx=fminf(mnx,bx); mxx=fmaxf(mxx,bx);
            mny=fminf(mny,by); mxy=fmaxf(mxy,by);
        }
        #pragma unroll
        for (int s=1; s<64; s<<=1){
            mnx = fminf(mnx, __shfl_xor(mnx, s));
            mxx = fmaxf(mxx, __shfl_xor(mxx, s));
            mny = fminf(mny, __shfl_xor(mny, s));
            mxy = fmaxf(mxy, __shfl_xor(mxy, s));
        }
        int wv = tid>>6, ln = tid&63;
        if (ln == 0){ part[wv][0]=mnx; part[wv][1]=mxx; part[wv][2]=mny; part[wv][3]=mxy; }
        __syncthreads();
        if (tid < 4){
            float v = part[0][tid];
            for (int t=1;t<4;t++) v = (tid&1) ? fmaxf(v, part[t][tid]) : fminf(v, part[t][tid]);
            res[tid] = v;
        }
        __syncthreads();
        const float minx=res[0], maxx=res[1], miny=res[2], maxy=res[3];
        const float ptpx = maxx-minx, ptpy = maxy-miny;
        if (bid == 0 && tid == 0){ cbuf[0]=minx; cbuf[1]=miny; cbuf[2]=ptpx; cbuf[3]=ptpy; }

        #pragma unroll
        for (int t=0;t<4;t++){
            int g = tid + t*256;
            float pgx = (bxv[t] - minx)/(ptpx + 1e-8f)*0.3f + 0.35f;
            float pgy = (byv[t] - miny)/(ptpy + 1e-8f)*0.3f + 0.35f;
            pgn[2*g]   = pgx;
            pgn[2*g+1] = pgy;
        }
        if (tid < 64){
            int g = 128*(tid>>3) + 4*(tid&7);
            int i = g >> 5, j = g & 31;
            float xs = (j + 0.5f)*(2.0f/32.0f) - 1.0f;
            float ys = (i + 0.5f)*(2.0f/32.0f) - 1.0f;
            float norm = (xs + 1.0f)*0.5f;
            float r_ = 1.0f + norm*31.0f;
            float r_s = (r_ - 1.0f)/31.0f*2.0f*32.0f/512.0f;
            float t_s = (ys + 1.0f)*3.14159265358979323846f;
            float bx = r_s*cosf(t_s);
            float by = r_s*sinf(t_s);
            sc[tid][0] = (bx - minx)/(ptpx + 1e-8f)*0.3f + 0.35f;
            sc[tid][1] = (by - miny)/(ptpy + 1e-8f)*0.3f + 0.35f;
        }
        __syncthreads();

        const float px = (bxv[bid] - minx)/(ptpx + 1e-8f)*0.3f + 0.35f;
        const float py = (byv[bid] - miny)/(ptpy + 1e-8f)*0.3f + 0.35f;
        const int g = bid*256 + tid;
        float gg2 = px*px + py*py;
        unsigned int* dst = (unsigned int*)(Ug + (size_t)g*96);
        #pragma unroll
        for (int t=0;t<64;t+=2){
            float cx0=sc[t][0],   cy0=sc[t][1];
            float cx1=sc[t+1][0], cy1=sc[t+1][1];
            float r20 = fmaxf(gg2 + (cx0*cx0+cy0*cy0) - 2.f*(px*cx0+py*cy0), 0.f);
            float r21 = fmaxf(gg2 + (cx1*cx1+cy1*cy1) - 2.f*(px*cx1+py*cy1), 0.f);
            float u0 = r20*logf(sqrtf(r20+1e-12f)+1e-6f);
            float u1 = r21*logf(sqrtf(r21+1e-12f)+1e-6f);
            dst[t>>1] = (unsigned)f2b(u0) | ((unsigned)f2b(u1)<<16);
        }
        dst[32] = (unsigned)f2b(1.f) | ((unsigned)f2b(px)<<16);
        dst[33] = (unsigned)f2b(py);
        #pragma unroll
        for (int t=34;t<48;t++) dst[t] = 0u;
    }
}

// ===== SPARSE conv1+conv2+interp: one block = 4 keypoints =====
__global__ __launch_bounds__(256, 2) void spconv_k(
    const short* __restrict__ B1f_, const short* __restrict__ B2f_,
    const short* __restrict__ XP, const float* __restrict__ Tab,
    const int* __restrict__ kp, float* __restrict__ th0g)
{
    __shared__ __align__(16) short xL[10368];      // 4kp x 36(pos) x 72(ch pad)
    __shared__ __align__(16) short hL[8768];       // 4kp x (16pos x 136 + 16 pad)
    __shared__ int   sPY[4], sPX[4], sCY[4][2], sCX[4][2], sB[4];
    __shared__ float sWT[4][4];
    const int bid = blockIdx.x;
    const int tid = threadIdx.x;
    const int wv = tid>>6, lane = tid&63;
    const int l15 = lane&15, lg = lane>>4;

    if (tid < 4){
        int m = bid*4 + tid;
        sB[tid] = m >> 9;
        float ix = (float)kp[m*2+0]/511.f*125.f;
        float iy = (float)kp[m*2+1]/511.f*125.f;
        float x0f = floorf(ix), y0f = floorf(iy);
        float wx = ix-x0f, wy = iy-y0f;
        int X0 = (int)x0f, Y0 = (int)y0f;
        bool vx1 = (x0f+1.f <= 125.f), vy1 = (y0f+1.f <= 125.f);
        int X1 = vx1 ? X0+1 : 125;
        int Y1 = vy1 ? Y0+1 : 125;
        int pX0 = min(X0,124), pY0 = min(Y0,124);
        sPX[tid]=pX0; sPY[tid]=pY0;
        sCX[tid][0]=X0-pX0; sCX[tid][1]=X1-pX0;
        sCY[tid][0]=Y0-pY0; sCY[tid][1]=Y1-pY0;
        sWT[tid][0] = (1.f-wx)*(1.f-wy);
        sWT[tid][1] = vx1 ? wx*(1.f-wy) : 0.f;
        sWT[tid][2] = vy1 ? (1.f-wx)*wy : 0.f;
        sWT[tid][3] = (vx1&&vy1) ? wx*wy : 0.f;
    }
    __syncthreads();

    for (int e = tid; e < 1152; e += 256){
        int pair = e >> 3, seg = e & 7;
        int ki = pair/36, rem = pair - ki*36;
        int row = rem/6, col = rem - row*6;
        const short* src = XP + (((size_t)sB[ki]*130 + sPY[ki]+row)*130
                                 + sPX[ki]+col)*64 + seg*8;
        int4 v = *(const int4*)src;
        *(int4*)&xL[(ki*36 + rem)*72 + seg*8] = v;
    }
    __syncthreads();

    // ---- conv1 ----
    f32x4 a1[4][2];
    #pragma unroll
    for (int i=0;i<4;i++){ a1[i][0]=(f32x4)(0.f); a1[i][1]=(f32x4)(0.f); }
    {
        const int py = l15>>2, px = l15&3;
        for (int cc=0; cc<2; ++cc){
            #pragma unroll
            for (int k9=0;k9<9;k9++){
                const int ky = k9/3, kx = k9 - (k9/3)*3;
                bf16x8 A[4], Bv[2];
                #pragma unroll
                for (int mt=0;mt<4;mt++)
                    A[mt] = *(const bf16x8*)&xL[(mt*36 + (py+ky)*6 + (px+kx))*72
                                                + cc*32 + lg*8];
                const int fb = (((cc*9+k9)*4 + wv)*2)*512 + lane*8;
                Bv[0] = *(const bf16x8*)(B1f_ + fb);
                Bv[1] = *(const bf16x8*)(B1f_ + fb + 512);
                #pragma unroll
                for (int mt=0;mt<4;mt++){
                    a1[mt][0] = __builtin_amdgcn_mfma_f32_16x16x32_bf16(A[mt], Bv[0], a1[mt][0],0,0,0);
                    a1[mt][1] = __builtin_amdgcn_mfma_f32_16x16x32_bf16(A[mt], Bv[1], a1[mt][1],0,0,0);
                }
            }
        }
    }
    #pragma unroll
    for (int mt=0;mt<4;mt++){
        const int pY0 = sPY[mt], pX0 = sPX[mt];
        #pragma unroll
        for (int reg=0;reg<4;reg++){
            const int p = lg*4 + reg;
            const int py = p>>2, px = p&3;
            const int hy = pY0+py, hx = pX0+px;
            const int pyb = (hy==0)?0:((hy==127)?2:1);
            const int pxb = (hx==0)?0:((hx==127)?2:1);
            #pragma unroll
            for (int nt=0;nt<2;nt++){
                const int co = wv*32 + nt*16 + l15;
                const float* t3 = Tab + ((size_t)(pyb*3+pxb)*128 + co)*3;
                float a = a1[mt][nt][reg];
                a += t3[0] + t3[1]*(float)hx + t3[2]*(float)hy;
                float v = fmaxf(a*BN_S, 0.f);
                hL[mt*2192 + p*136 + co] = (short)f2b(v);
            }
        }
    }
    __syncthreads();

    // ---- conv2 ----
    f32x4 a2[2];
    a2[0]=(f32x4)(0.f); a2[1]=(f32x4)(0.f);
    {
        const int ki = l15>>2, c = l15&3, cy = c>>1, cx = c&1;
        const int hbase = ki*2192 + (sCY[ki][cy]*4 + sCX[ki][cx])*136;
        for (int cc=0; cc<4; ++cc){
            #pragma unroll
            for (int k9=0;k9<9;k9++){
                const int ky = k9/3, kx = k9 - (k9/3)*3;
                bf16x8 A = *(const bf16x8*)&hL[hbase + (ky*4+kx)*136 + cc*32 + lg*8];
                const int fb = (((cc*9+k9)*4 + wv)*2)*512 + lane*8;
                bf16x8 Bv0 = *(const bf16x8*)(B2f_ + fb);
                bf16x8 Bv1 = *(const bf16x8*)(B2f_ + fb + 512);
                a2[0] = __builtin_amdgcn_mfma_f32_16x16x32_bf16(A, Bv0, a2[0],0,0,0);
                a2[1] = __builtin_amdgcn_mfma_f32_16x16x32_bf16(A, Bv1, a2[1],0,0,0);
            }
        }
    }
    {
        const float* w4 = sWT[lg];
        #pragma unroll
        for (int nt=0;nt<2;nt++){
            float c0 = fmaxf(a2[nt][0]*BN_S, 0.f);
            float c1 = fmaxf(a2[nt][1]*BN_S, 0.f);
            float c2 = fmaxf(a2[nt][2]*BN_S, 0.f);
            float c3 = fmaxf(a2[nt][3]*BN_S, 0.f);
            float r = ((c0*w4[0] + c1*w4[1]) + c2*w4[2]) + c3*w4[3];
            th0g[(size_t)(bid*4+lg)*128 + wv*32 + nt*16 + l15] = r;
        }
    }
}

// ===== fused MLP+TPS: all linear layers as split-bf16 MFMA GEMMs =====
__global__ __launch_bounds__(256) void mlp_tps_k(const float* __restrict__ th0g,
    const unsigned short* __restrict__ W1h, const unsigned short* __restrict__ W1l,
    const unsigned short* __restrict__ W2h, const unsigned short* __restrict__ W2l,
    const unsigned short* __restrict__ W3h, const unsigned short* __restrict__ W3l,
    const float* __restrict__ l1b, const float* __restrict__ l2b,
    const float* __restrict__ l3b,
    const unsigned short* __restrict__ Ug, float* __restrict__ bxy)
{
    __shared__ unsigned short th0h[16][136], th0l[16][136];
    __shared__ unsigned short th1h[16][264], th1l[16][264];
    __shared__ unsigned short th2h[16][264], th2l[16][264];
    __shared__ float sth[8][132];
    __shared__ __align__(16) unsigned short sW[16][96];
    const int m0 = blockIdx.x*8;
    const int tid = threadIdx.x;
    const int wv = tid>>6, lane = tid&63;
    const int l15 = lane&15, lg = lane>>4;

    for (int e = tid; e < 2048; e += 256){
        int r = e >> 7, k = e & 127;
        float v = (r < 8) ? th0g[(size_t)(m0 + r)*128 + k] : 0.f;
        unsigned short hi = f2b(v);
        th0h[r][k] = hi; th0l[r][k] = f2b(v - b2f(hi));
    }
    __syncthreads();

    // ---- lin1 ----
    {
        f32x4 acc[4];
        #pragma unroll
        for (int nt=0;nt<4;nt++) acc[nt] = (f32x4)(0.f);
        for (int kc=0; kc<4; ++kc){
            bf16x8 Ah = *(const bf16x8*)&th0h[l15][kc*32 + lg*8];
            bf16x8 Al = *(const bf16x8*)&th0l[l15][kc*32 + lg*8];
            #pragma unroll
            for (int nt=0;nt<4;nt++){
                const int fb = (kc*16 + wv*4 + nt)*512 + lane*8;
                bf16x8 Bh = *(const bf16x8*)(W1h + fb);
                bf16x8 Bl = *(const bf16x8*)(W1l + fb);
                acc[nt] = __builtin_amdgcn_mfma_f32_16x16x32_bf16(Ah, Bh, acc[nt],0,0,0);
                acc[nt] = __builtin_amdgcn_mfma_f32_16x16x32_bf16(Ah, Bl, acc[nt],0,0,0);
                acc[nt] = __builtin_amdgcn_mfma_f32_16x16x32_bf16(Al, Bh, acc[nt],0,0,0);
            }
        }
        #pragma unroll
        for (int nt=0;nt<4;nt++){
            const int o = (wv*4+nt)*16 + l15;
            float bv = l1b[o];
            #pragma unroll
            for (int reg=0;reg<4;reg++){
                int r = lg*4+reg;
                float v = fmaxf((acc[nt][reg]+bv)*BN_S, 0.f);
                unsigned short hi = f2b(v);
                th1h[r][o] = hi; th1l[r][o] = f2b(v - b2f(hi));
            }
        }
    }
    __syncthreads();

    // ---- lin2 ----
    {
        f32x4 acc[4];
        #pragma unroll
        for (int nt=0;nt<4;nt++) acc[nt] = (f32x4)(0.f);
        for (int kc=0; kc<8; ++kc){
            bf16x8 Ah = *(const bf16x8*)&th1h[l15][kc*32 + lg*8];
            bf16x8 Al = *(const bf16x8*)&th1l[l15][kc*32 + lg*8];
            #pragma unroll
            for (int nt=0;nt<4;nt++){
                const int fb = (kc*16 + wv*4 + nt)*512 + lane*8;
                bf16x8 Bh = *(const bf16x8*)(W2h + fb);
                bf16x8 Bl = *(const bf16x8*)(W2l + fb);
                acc[nt] = __builtin_amdgcn_mfma_f32_16x16x32_bf16(Ah, Bh, acc[nt],0,0,0);
                acc[nt] = __builtin_amdgcn_mfma_f32_16x16x32_bf16(Ah, Bl, acc[nt],0,0,0);
                acc[nt] = __builtin_amdgcn_mfma_f32_16x16x32_bf16(Al, Bh, acc[nt],0,0,0);
            }
        }
        #pragma unroll
        for (int nt=0;nt<4;nt++){
            const int o = (wv*4+nt)*16 + l15;
            float bv = l2b[o];
            #pragma unroll
            for (int reg=0;reg<4;reg++){
                int r = lg*4+reg;
                float v = fmaxf(acc[nt][reg]+bv, 0.f);
                unsigned short hi = f2b(v);
                th2h[r][o] = hi; th2l[r][o] = f2b(v - b2f(hi));
            }
        }
    }
    __syncthreads();

    // ---- lin3 ----
    {
        f32x4 acc[3];
        #pragma unroll
        for (int t=0;t<3;t++) acc[t] = (f32x4)(0.f);
        const int nfr = (wv<3) ? 2 : 3;
        for (int kc=0; kc<8; ++kc){
            bf16x8 Ah = *(const bf16x8*)&th2h[l15][kc*32 + lg*8];
            bf16x8 Al = *(const bf16x8*)&th2l[l15][kc*32 + lg*8];
            for (int t=0;t<3;t++){
                if (t >= nfr) break;
                const int fr = (wv<3) ? (wv*2+t) : (6+t);
                const int fb = (kc*9 + fr)*512 + lane*8;
                bf16x8 Bh = *(const bf16x8*)(W3h + fb);
                bf16x8 Bl = *(const bf16x8*)(W3l + fb);
                acc[t] = __builtin_amdgcn_mfma_f32_16x16x32_bf16(Ah, Bh, acc[t],0,0,0);
                acc[t] = __builtin_amdgcn_mfma_f32_16x16x32_bf16(Ah, Bl, acc[t],0,0,0);
                acc[t] = __builtin_amdgcn_mfma_f32_16x16x32_bf16(Al, Bh, acc[t],0,0,0);
            }
        }
        for (int t=0;t<3;t++){
            if (t >= nfr) break;
            const int fr = (wv<3) ? (wv*2+t) : (6+t);
            const int o = fr*16 + l15;
            if (o < NPAR){
                float bv = l3b[o];
                #pragma unroll
                for (int reg=0;reg<4;reg++){
                    int r = lg*4+reg;
                    if (r < 8) sth[r][o] = tanhf(acc[t][reg]+bv);
                }
            }
        }
    }
    __syncthreads();

    // ---- W+ prep ----
    if (tid < 16){
        int kpi = tid>>1, c = tid&1;
        float s = 0.f;
        for (int p=0;p<63;p++){ float w = sth[kpi][2*p+c]; s += w; sW[tid][1+p] = f2b(w); }
        sW[tid][0]  = f2b(-s);
        sW[tid][64] = f2b(sth[kpi][126+c]);
        sW[tid][65] = f2b(sth[kpi][128+c]);
        sW[tid][66] = f2b(sth[kpi][130+c]);
        for (int p=67;p<96;p++) sW[tid][p] = 0;
    }
    __syncthreads();
    // ---- TPS MFMA ----
    bf16x8 Bf[3];
    #pragma unroll
    for (int ks=0;ks<3;ks++) Bf[ks] = *(const bf16x8*)&sW[l15][ks*32 + lg*8];
    const int gbase = wv*256;
    const int kpg = m0 + (l15>>1), c = l15&1;
    #pragma unroll
    for (int mf=0; mf<16; ++mf){
        f32x4 acc2 = (f32x4)(0.f);
        const unsigned short* ap = Ug + (size_t)(gbase + mf*16 + l15)*96 + lg*8;
        #pragma unroll
        for (int ks=0;ks<3;ks++){
            bf16x8 Af = *(const bf16x8*)(ap + ks*32);
            acc2 = __builtin_amdgcn_mfma_f32_16x16x32_bf16(Af, Bf[ks], acc2,0,0,0);
        }
        float* dst = bxy + ((size_t)kpg*2 + c)*1024 + gbase + mf*16 + lg*4;
        #pragma unroll
        for (int r=0;r<4;r++) dst[r] = acc2[r];
    }
}

// ===== sample: channels-last imgT gather, 2048 blocks, XCD-swizzled ========
__global__ __launch_bounds__(256) void sample_k(const int* __restrict__ kp,
    const float* __restrict__ bxy, const float* __restrict__ pgn,
    const float* __restrict__ cbuf, const float* __restrict__ imgT,
    float* __restrict__ out)
{
    const int bid = blockIdx.x;
    const int m = ((bid & 7) << 8) | (bid >> 3);   // bijective: 2048 = 8*256
    const int tid = threadIdx.x;
    const int b = m >> 9;
    const float vminx = cbuf[0] + ((float)kp[m*2+0]/512.f*2.f - 1.f);
    const float vminy = cbuf[1] + ((float)kp[m*2+1]/512.f*2.f - 1.f);
    const float ptpx = cbuf[2], ptpy = cbuf[3];
    const int g0 = tid*4;
    f32x4 zbx = *(const f32x4*)&bxy[((size_t)m*2+0)*1024 + g0];
    f32x4 zby = *(const f32x4*)&bxy[((size_t)m*2+1)*1024 + g0];
    f32x4 pga = *(const f32x4*)&pgn[2*g0];
    f32x4 pgb = *(const f32x4*)&pgn[2*g0+4];
    float px[4] = {pga[0], pga[2], pgb[0], pgb[2]};
    float py[4] = {pga[1], pga[3], pgb[1], pgb[3]};
    const float* it_b = imgT + (size_t)b*HOImg*HOImg*4;
    f32x4 o0, o1, o2;
    #pragma unroll
    for (int i=0;i<4;i++){
        float wnx = px[i] + zbx[i];
        float wny = py[i] + zby[i];
        float wxr = (wnx - 0.35f)/0.3f*ptpx + vminx;
        float wyr = (wny - 0.35f)/0.3f*ptpy + vminy;
        float ix = ((wxr + 1.f)*512.f - 1.f)*0.5f;
        float iy = ((wyr + 1.f)*512.f - 1.f)*0.5f;
        float x0f = floorf(ix), y0f = floorf(iy);
        float fx = ix-x0f, fy = iy-y0f;
        float w00=(1.f-fx)*(1.f-fy), w10=fx*(1.f-fy), w01=(1.f-fx)*fy, w11=fx*fy;
        bool vx0 = (x0f>=0.f)&&(x0f<=511.f), vx1 = (x0f+1.f>=0.f)&&(x0f+1.f<=511.f);
        bool vy0 = (y0f>=0.f)&&(y0f<=511.f), vy1 = (y0f+1.f>=0.f)&&(y0f+1.f<=511.f);
        float m00 = (vx0&&vy0)?w00:0.f;
        float m10 = (vx1&&vy0)?w10:0.f;
        float m01 = (vx0&&vy1)?w01:0.f;
        float m11 = (vx1&&vy1)?w11:0.f;
        int X0 = (int)fminf(fmaxf(x0f,0.f),511.f);
        int X1 = (int)fminf(fmaxf(x0f+1.f,0.f),511.f);
        int Y0 = (int)fminf(fmaxf(y0f,0.f),511.f);
        int Y1 = (int)fminf(fmaxf(y0f+1.f,0.f),511.f);
        f32x4 t00 = *(const f32x4*)&it_b[((size_t)Y0*HOImg + X0)*4];
        f32x4 t10 = *(const f32x4*)&it_b[((size_t)Y0*HOImg + X1)*4];
        f32x4 t01 = *(const f32x4*)&it_b[((size_t)Y1*HOImg + X0)*4];
        f32x4 t11 = *(const f32x4*)&it_b[((size_t)Y1*HOImg + X1)*4];
        o0[i] = t00[0]*m00 + t10[0]*m10 + t01[0]*m01 + t11[0]*m11;
        o1[i] = t00[1]*m00 + t10[1]*m10 + t01[1]*m01 + t11[1]*m11;
        o2[i] = t00[2]*m00 + t10[2]*m10 + t01[2]*m01 + t11[2]*m11;
    }
    *(f32x4*)&out[((size_t)(m*3+0))*GG + g0] = o0;
    *(f32x4*)&out[((size_t)(m*3+1))*GG + g0] = o1;
    *(f32x4*)&out[((size_t)(m*3+2))*GG + g0] = o2;
}

// ============================ launcher =======================================
extern "C" void kernel_launch(void* const* d_in, const int* in_sizes, int n_in,
                              void* d_out, int out_size, void* d_ws, size_t ws_size,
                              hipStream_t stream)
{
    const float* x    = (const float*)d_in[0];
    const float* imgs = (const float*)d_in[1];
    const int*   kp   = (const int*)d_in[2];
    const float* c1w  = (const float*)d_in[3];
    const float* c2w  = (const float*)d_in[4];
    const float* l1w  = (const float*)d_in[5];
    const float* l1b  = (const float*)d_in[6];
    const float* l2w  = (const float*)d_in[7];
    const float* l2b  = (const float*)d_in[8];
    const float* l3w  = (const float*)d_in[9];
    const float* l3b  = (const float*)d_in[10];
    float* out = (float*)d_out;

    // ---- workspace layout: ALL DEDICATED, ZERO ALIASING (44.5 MB) ----
    char* W = (char*)d_ws;
    short* xph  = (short*)(W + 0);                          // 8,652,800
    float* imgT = (float*)(W + 8652800);                    // 16,777,216
    float* th0g = (float*)(W + 25430016);                   // 1,048,576
    short* B1   = (short*)(W + 26478592);                   // 147,456 (B1f frags)
    short* B2   = (short*)(W + 26626048);                   // 294,912 (B2f frags)
    float* Tab  = (float*)(W + 26920960);                   // 13,824
    unsigned short* Ug  = (unsigned short*)(W + 26934784);  // 196,608
    float* pgn  = (float*)(W + 27131392);                   // 8,192
    float* cbuf = (float*)(W + 27139584);                   // 256
    unsigned short* W1h = (unsigned short*)(W + 27140352);  // 65,536
    unsigned short* W1l = (unsigned short*)(W + 27205888);  // 65,536
    unsigned short* W2h = (unsigned short*)(W + 27271424);  // 131,072
    unsigned short* W2l = (unsigned short*)(W + 27402496);  // 131,072
    unsigned short* W3h = (unsigned short*)(W + 27533568);  // 73,728
    unsigned short* W3l = (unsigned short*)(W + 27607296);  // 73,728
    float* bxy  = (float*)(W + 27681024);                   // 16,777,216 -> 44,458,240

    hipLaunchKernelGGL(prep_all_k, dim3(5727), dim3(256), 0, stream,
                       x, imgs, c1w, c2w, l1w, l2w, l3w,
                       xph, imgT, B1, B2, Tab,
                       W1h, W1l, W2h, W2l, W3h, W3l,
                       cbuf, pgn, Ug);

    hipLaunchKernelGGL(spconv_k, dim3(MM/4), dim3(256), 0, stream,
                       B1, B2, xph, Tab, kp, th0g);

    hipLaunchKernelGGL(mlp_tps_k, dim3(MM/8), dim3(256), 0, stream,
                       th0g, W1h, W1l, W2h, W2l, W3h, W3l,
                       l1b, l2b, l3b, Ug, bxy);
    hipLaunchKernelGGL(sample_k, dim3(MM), dim3(256), 0, stream,
                       kp, bxy, pgn, cbuf, imgT, out);
}